// Round 1
// baseline (1083.621 us; speedup 1.0000x reference)
//
#include <hip/hip_runtime.h>
#include <hip/hip_bf16.h>

#define BDIM 2
#define QLEN 256
#define KLEN 256
#define QDIM 1024
#define HDIM 512
#define H3DIM 1536
#define EPSF 1e-5f

typedef __attribute__((ext_vector_type(8))) short short8;
typedef __attribute__((ext_vector_type(4))) float f32x4;

__device__ inline short f2bf(float f) {
    union { float f; unsigned u; } v; v.f = f;
    unsigned r = v.u + 0x7FFF + ((v.u >> 16) & 1);
    return (short)(r >> 16);
}
__device__ inline float bf2f(short s) {
    union { float f; unsigned u; } v; v.u = ((unsigned)(unsigned short)s) << 16;
    return v.f;
}
__device__ inline unsigned pk2(float a, float b) {
    return ((unsigned)(unsigned short)f2bf(a)) | (((unsigned)(unsigned short)f2bf(b)) << 16);
}
__device__ inline unsigned mulbf2(unsigned a, unsigned b) {
    float a0 = bf2f((short)(a & 0xffff)), a1 = bf2f((short)(a >> 16));
    float b0 = bf2f((short)(b & 0xffff)), b1 = bf2f((short)(b >> 16));
    return pk2(a0 * b0, a1 * b1);
}
__device__ inline void store_bf4(short* p, float4 v) {
    uint2 u; u.x = pk2(v.x, v.y); u.y = pk2(v.z, v.w);
    *(uint2*)p = u;
}

// ---------------- weight prep: W3 (bf16, ln_w-folded), su, tu -----------------
__global__ __launch_bounds__(256) void prep_w(const float* __restrict__ Wm,
                                              const float* __restrict__ lnw,
                                              const float* __restrict__ lnb,
                                              const float* __restrict__ bias,
                                              short* __restrict__ W3bf,
                                              float* __restrict__ svec,
                                              float* __restrict__ tvec) {
    int h = blockIdx.x, tid = threadIdx.x;
    const float* row = Wm + h * H3DIM;
    for (int j = tid; j < HDIM; j += 256)
        W3bf[h * HDIM + j] = f2bf(lnw[2 * HDIM + j] * row[2 * HDIM + j]);
    float s = 0.f, t = 0.f;
    for (int c = tid; c < H3DIM; c += 256) {
        float w = row[c];
        s += lnw[c] * w;
        t += lnb[c] * w;
    }
    for (int m = 1; m < 64; m <<= 1) { s += __shfl_xor(s, m, 64); t += __shfl_xor(t, m, 64); }
    __shared__ float rs[4], rt[4];
    if ((tid & 63) == 0) { rs[tid >> 6] = s; rt[tid >> 6] = t; }
    __syncthreads();
    if (tid == 0) {
        svec[h] = rs[0] + rs[1] + rs[2] + rs[3];
        tvec[h] = rt[0] + rt[1] + rt[2] + rt[3] + bias[h];
    }
}

// ------------- generic Out[i][h] = sum_j In[i][j]*scale[j]*W[h*ws+woff+j] -----
__global__ __launch_bounds__(256) void gemm_tn(const float* __restrict__ In,
                                               const float* __restrict__ W,
                                               const float* __restrict__ scale,
                                               float* __restrict__ Out,
                                               int K, int wstride, int woff) {
    __shared__ float a_l[64][33], b_l[64][33];
    int tid = threadIdx.x;
    int i0 = blockIdx.x * 64, h0 = blockIdx.y * 64;
    int ty = tid >> 4, tx = tid & 15;
    float acc[4][4] = {};
    for (int kc = 0; kc < K; kc += 32) {
        for (int t = 0; t < 2; ++t) {
            int id = tid + t * 256;
            int r = id >> 3, c = (id & 7) << 2;
            float4 av = *(const float4*)&In[(size_t)(i0 + r) * K + kc + c];
            if (scale) {
                av.x *= scale[kc + c]; av.y *= scale[kc + c + 1];
                av.z *= scale[kc + c + 2]; av.w *= scale[kc + c + 3];
            }
            a_l[r][c] = av.x; a_l[r][c + 1] = av.y; a_l[r][c + 2] = av.z; a_l[r][c + 3] = av.w;
            float4 bv = *(const float4*)&W[(size_t)(h0 + r) * wstride + woff + kc + c];
            b_l[r][c] = bv.x; b_l[r][c + 1] = bv.y; b_l[r][c + 2] = bv.z; b_l[r][c + 3] = bv.w;
        }
        __syncthreads();
#pragma unroll
        for (int dd = 0; dd < 32; ++dd) {
            float af_[4], bf_[4];
#pragma unroll
            for (int a = 0; a < 4; ++a) af_[a] = a_l[ty * 4 + a][dd];
#pragma unroll
            for (int b = 0; b < 4; ++b) bf_[b] = b_l[tx * 4 + b][dd];
#pragma unroll
            for (int a = 0; a < 4; ++a)
#pragma unroll
                for (int b = 0; b < 4; ++b) acc[a][b] += af_[a] * bf_[b];
        }
        __syncthreads();
    }
    for (int a = 0; a < 4; ++a)
        for (int b = 0; b < 4; ++b)
            Out[(size_t)(i0 + ty * 4 + a) * HDIM + h0 + tx * 4 + b] = acc[a][b];
}

// ------------- per-row bf16 cast + sum / sumsq --------------------------------
__global__ __launch_bounds__(256) void rowstats(const float* __restrict__ X,
                                                unsigned* __restrict__ Xbf,
                                                float* __restrict__ s1,
                                                float* __restrict__ s2) {
    int row = blockIdx.x, tid = threadIdx.x;
    float2 v = *(const float2*)&X[(size_t)row * HDIM + tid * 2];
    Xbf[row * 256 + tid] = pk2(v.x, v.y);
    float s = v.x + v.y, q = v.x * v.x + v.y * v.y;
    for (int m = 1; m < 64; m <<= 1) { s += __shfl_xor(s, m, 64); q += __shfl_xor(q, m, 64); }
    __shared__ float rs[4], rq[4];
    if ((tid & 63) == 0) { rs[tid >> 6] = s; rq[tid >> 6] = q; }
    __syncthreads();
    if (tid == 0) {
        s1[row] = rs[0] + rs[1] + rs[2] + rs[3];
        s2[row] = rq[0] + rq[1] + rq[2] + rq[3];
    }
}

// ------------- per-pair mu / rinv ---------------------------------------------
__global__ __launch_bounds__(256) void pairstats(const float* __restrict__ qf,
                                                 const float* __restrict__ kf,
                                                 const float* __restrict__ sq,
                                                 const float* __restrict__ ssq,
                                                 const float* __restrict__ sk,
                                                 const float* __restrict__ ssk,
                                                 float* __restrict__ muA,
                                                 float* __restrict__ riA) {
    __shared__ float qt_l[16][132], kt_l[16][132];
    int b = blockIdx.z, qt = blockIdx.y, kt = blockIdx.x, tid = threadIdx.x;
    int qr = tid >> 4, kr = tid & 15;
    float d1 = 0.f, d2 = 0.f;
    for (int jc = 0; jc < HDIM; jc += 128) {
        for (int t = 0; t < 2; ++t) {
            int id = tid + t * 256;
            int r = id >> 5, c = (id & 31) << 2;
            *(float4*)&qt_l[r][c] = *(const float4*)&qf[(size_t)(b * QLEN + qt * 16 + r) * HDIM + jc + c];
            *(float4*)&kt_l[r][c] = *(const float4*)&kf[(size_t)(b * KLEN + kt * 16 + r) * HDIM + jc + c];
        }
        __syncthreads();
#pragma unroll 16
        for (int j = 0; j < 128; ++j) {
            float a = qt_l[qr][j], c = kt_l[kr][j];
            d1 += a * c;
            d2 += (a * a) * (c * c);
        }
        __syncthreads();
    }
    int qi = qt * 16 + qr, ki = kt * 16 + kr;
    float mu = (sq[b * QLEN + qi] + sk[b * KLEN + ki] + d1) * (1.0f / H3DIM);
    float ex2 = (ssq[b * QLEN + qi] + ssk[b * KLEN + ki] + d2) * (1.0f / H3DIM);
    float var = ex2 - mu * mu;
    float ri = rsqrtf(var + EPSF);
    size_t idx = (size_t)(b * QLEN + qi) * KLEN + ki;
    muA[idx] = mu; riA[idx] = ri;
}

// ------------- main fused pair kernel -----------------------------------------
__global__ __launch_bounds__(256) void main_pair(const short* __restrict__ qbf,
                                                 const short* __restrict__ kbf,
                                                 const float* __restrict__ Au,
                                                 const float* __restrict__ Bu,
                                                 const float* __restrict__ Av,
                                                 const float* __restrict__ Bv,
                                                 const short* __restrict__ W3u,
                                                 const short* __restrict__ W3v,
                                                 const float* __restrict__ su,
                                                 const float* __restrict__ tu,
                                                 const float* __restrict__ sv,
                                                 const float* __restrict__ tv,
                                                 const float* __restrict__ Wo,
                                                 const float* __restrict__ bo,
                                                 const float* __restrict__ muA,
                                                 const float* __restrict__ riA,
                                                 float* __restrict__ out) {
    __shared__ short p_lds[64 * 512];                       // 64KB, XOR-swizzled rows
    __shared__ short au_l[8 * 512], bu_l[8 * 512], av_l[8 * 512], bv_l[8 * 512];
    __shared__ float su_l[512], tu_l[512], sv_l[512], tv_l[512], wo_l[512];
    __shared__ float sred[2][64];

    int tid = threadIdx.x;
    int b = blockIdx.z, qt = blockIdx.y, kt = blockIdx.x;
    int qbase = qt * 8, kbase = kt * 8;

    // stage A/B LN-linear tiles as bf16
    for (int i = tid; i < 1024; i += 256) {
        int r = i >> 7, c = (i & 127) << 2;
        size_t qo = (size_t)(b * QLEN + qbase + r) * HDIM + c;
        size_t ko = (size_t)(b * KLEN + kbase + r) * HDIM + c;
        store_bf4(au_l + r * 512 + c, *(const float4*)&Au[qo]);
        store_bf4(bu_l + r * 512 + c, *(const float4*)&Bu[ko]);
        store_bf4(av_l + r * 512 + c, *(const float4*)&Av[qo]);
        store_bf4(bv_l + r * 512 + c, *(const float4*)&Bv[ko]);
    }
    for (int i = tid; i < 512; i += 256) {
        su_l[i] = su[i]; tu_l[i] = tu[i]; sv_l[i] = sv[i]; tv_l[i] = tv[i]; wo_l[i] = Wo[i];
    }
    // form p = q .* k  (bf16, swizzled)
    for (int cch = tid; cch < 4096; cch += 256) {
        int row = cch >> 6, j0 = (cch & 63) << 3;
        int qi = row >> 3, ki = row & 7;
        uint4 qv = *(const uint4*)&qbf[(size_t)(b * QLEN + qbase + qi) * HDIM + j0];
        uint4 kv = *(const uint4*)&kbf[(size_t)(b * KLEN + kbase + ki) * HDIM + j0];
        uint4 pv;
        pv.x = mulbf2(qv.x, kv.x); pv.y = mulbf2(qv.y, kv.y);
        pv.z = mulbf2(qv.z, kv.z); pv.w = mulbf2(qv.w, kv.w);
        unsigned off = row * 1024 + ((j0 * 2) ^ ((row & 7) << 4));
        *(uint4*)((char*)p_lds + off) = pv;
    }
    __syncthreads();

    int lane = tid & 63, wv = tid >> 6;
    int wm = wv >> 1, wn = wv & 1;
    int l15 = lane & 15, lg = lane >> 4;

    // per-pair scalars
    float rinv8[8], rmu8[8];
#pragma unroll
    for (int mi = 0; mi < 2; ++mi)
#pragma unroll
        for (int r = 0; r < 4; ++r) {
            int pr = wm * 32 + mi * 16 + lg * 4 + r;
            int qi = qbase + (pr >> 3), ki = kbase + (pr & 7);
            size_t idx = (size_t)(b * QLEN + qi) * KLEN + ki;
            float mu = muA[idx], ri = riA[idx];
            rinv8[mi * 4 + r] = ri;
            rmu8[mi * 4 + r] = ri * mu;
        }

    float sacc[8];
#pragma unroll
    for (int i = 0; i < 8; ++i) sacc[i] = 0.f;

    for (int hc = 0; hc < 8; ++hc) {
        int hb = hc * 64 + wn * 32;
        f32x4 aU[2][2], aV[2][2];
#pragma unroll
        for (int mi = 0; mi < 2; ++mi)
#pragma unroll
            for (int nj = 0; nj < 2; ++nj) {
                aU[mi][nj] = (f32x4){0.f, 0.f, 0.f, 0.f};
                aV[mi][nj] = (f32x4){0.f, 0.f, 0.f, 0.f};
            }
#pragma unroll 4
        for (int kk = 0; kk < 512; kk += 32) {
            short8 af[2];
#pragma unroll
            for (int mi = 0; mi < 2; ++mi) {
                int row = wm * 32 + mi * 16 + l15;
                unsigned off = row * 1024 + ((((unsigned)(kk + lg * 8)) * 2) ^ ((row & 7) << 4));
                af[mi] = *(const short8*)((const char*)p_lds + off);
            }
            short8 bfu[2], bfv[2];
#pragma unroll
            for (int nj = 0; nj < 2; ++nj) {
                int h = hb + nj * 16 + l15;
                bfu[nj] = *(const short8*)&W3u[(size_t)h * HDIM + kk + lg * 8];
                bfv[nj] = *(const short8*)&W3v[(size_t)h * HDIM + kk + lg * 8];
            }
#pragma unroll
            for (int mi = 0; mi < 2; ++mi)
#pragma unroll
                for (int nj = 0; nj < 2; ++nj) {
                    aU[mi][nj] = __builtin_amdgcn_mfma_f32_16x16x32_bf16(af[mi], bfu[nj], aU[mi][nj], 0, 0, 0);
                    aV[mi][nj] = __builtin_amdgcn_mfma_f32_16x16x32_bf16(af[mi], bfv[nj], aV[mi][nj], 0, 0, 0);
                }
        }
        // fused epilogue for this h-chunk
#pragma unroll
        for (int nj = 0; nj < 2; ++nj) {
            int h = hb + nj * 16 + l15;
            float suh = su_l[h], tuh = tu_l[h], svh = sv_l[h], tvh = tv_l[h], woh = wo_l[h];
#pragma unroll
            for (int mi = 0; mi < 2; ++mi) {
#pragma unroll
                for (int r = 0; r < 4; ++r) {
                    int pr = wm * 32 + mi * 16 + lg * 4 + r;
                    int qi = pr >> 3, ki = pr & 7;
                    float gu = bf2f(au_l[qi * 512 + h]) + bf2f(bu_l[ki * 512 + h]) + aU[mi][nj][r];
                    float u = rinv8[mi * 4 + r] * gu - rmu8[mi * 4 + r] * suh + tuh;
                    float gv = bf2f(av_l[qi * 512 + h]) + bf2f(bv_l[ki * 512 + h]) + aV[mi][nj][r];
                    float vv = rinv8[mi * 4 + r] * gv - rmu8[mi * 4 + r] * svh + tvh;
                    float ge = 0.5f * vv * (1.0f + erff(vv * 0.70710678118654752f));
                    sacc[mi * 4 + r] += u * ge * woh;
                }
            }
        }
    }

    // reduce over the 16 lanes that share a pair (they hold disjoint h)
#pragma unroll
    for (int i = 0; i < 8; ++i) {
        float v = sacc[i];
        v += __shfl_xor(v, 1, 64);
        v += __shfl_xor(v, 2, 64);
        v += __shfl_xor(v, 4, 64);
        v += __shfl_xor(v, 8, 64);
        sacc[i] = v;
    }
    if (l15 == 0) {
#pragma unroll
        for (int i = 0; i < 8; ++i) {
            int pr = wm * 32 + (i >> 2) * 16 + lg * 4 + (i & 3);
            sred[wn][pr] = sacc[i];
        }
    }
    __syncthreads();
    if (tid < 64) {
        int pr = tid;
        int qi = qbase + (pr >> 3), ki = kbase + (pr & 7);
        out[(size_t)(b * QLEN + qi) * KLEN + ki] = sred[0][pr] + sred[1][pr] + bo[0];
    }
}

extern "C" void kernel_launch(void* const* d_in, const int* in_sizes, int n_in,
                              void* d_out, int out_size, void* d_ws, size_t ws_size,
                              hipStream_t stream) {
    const float* Q   = (const float*)d_in[0];
    const float* Kin = (const float*)d_in[1];
    const float* Wq  = (const float*)d_in[2];
    const float* Wk  = (const float*)d_in[3];
    const float* lnw = (const float*)d_in[4];
    const float* lnb = (const float*)d_in[5];
    const float* Wu  = (const float*)d_in[6];
    const float* bu  = (const float*)d_in[7];
    const float* Wv  = (const float*)d_in[8];
    const float* bv  = (const float*)d_in[9];
    const float* Wo  = (const float*)d_in[10];
    const float* bo  = (const float*)d_in[11];
    float* out = (float*)d_out;

    char* ws = (char*)d_ws;
    size_t off = 0;
    auto alloc = [&](size_t bytes) -> void* {
        void* p = ws + off;
        off += (bytes + 255) & ~(size_t)255;
        return p;
    };
    const int ROWS = BDIM * QLEN; // 512
    float* qf  = (float*)alloc((size_t)ROWS * HDIM * 4);
    float* kf  = (float*)alloc((size_t)ROWS * HDIM * 4);
    float* Au  = (float*)alloc((size_t)ROWS * HDIM * 4);
    float* Bu  = (float*)alloc((size_t)ROWS * HDIM * 4);
    float* Av  = (float*)alloc((size_t)ROWS * HDIM * 4);
    float* Bv  = (float*)alloc((size_t)ROWS * HDIM * 4);
    short* qbf = (short*)alloc((size_t)ROWS * HDIM * 2);
    short* kbf = (short*)alloc((size_t)ROWS * HDIM * 2);
    short* W3u = (short*)alloc((size_t)HDIM * HDIM * 2);
    short* W3v = (short*)alloc((size_t)HDIM * HDIM * 2);
    float* su  = (float*)alloc(HDIM * 4);
    float* tu  = (float*)alloc(HDIM * 4);
    float* sv  = (float*)alloc(HDIM * 4);
    float* tv  = (float*)alloc(HDIM * 4);
    float* sq  = (float*)alloc(ROWS * 4);
    float* ssq = (float*)alloc(ROWS * 4);
    float* sk  = (float*)alloc(ROWS * 4);
    float* ssk = (float*)alloc(ROWS * 4);
    float* muA = (float*)alloc((size_t)BDIM * QLEN * KLEN * 4);
    float* riA = (float*)alloc((size_t)BDIM * QLEN * KLEN * 4);

    prep_w<<<HDIM, 256, 0, stream>>>(Wu, lnw, lnb, bu, W3u, su, tu);
    prep_w<<<HDIM, 256, 0, stream>>>(Wv, lnw, lnb, bv, W3v, sv, tv);

    gemm_tn<<<dim3(8, 8), 256, 0, stream>>>(Q,   Wq, nullptr, qf, QDIM, QDIM, 0);
    gemm_tn<<<dim3(8, 8), 256, 0, stream>>>(Kin, Wk, nullptr, kf, QDIM, QDIM, 0);

    rowstats<<<ROWS, 256, 0, stream>>>(qf, (unsigned*)qbf, sq, ssq);
    rowstats<<<ROWS, 256, 0, stream>>>(kf, (unsigned*)kbf, sk, ssk);

    pairstats<<<dim3(16, 16, 2), 256, 0, stream>>>(qf, kf, sq, ssq, sk, ssk, muA, riA);

    gemm_tn<<<dim3(8, 8), 256, 0, stream>>>(qf, Wu, lnw,        Au, HDIM, H3DIM, 0);
    gemm_tn<<<dim3(8, 8), 256, 0, stream>>>(kf, Wu, lnw + HDIM, Bu, HDIM, H3DIM, HDIM);
    gemm_tn<<<dim3(8, 8), 256, 0, stream>>>(qf, Wv, lnw,        Av, HDIM, H3DIM, 0);
    gemm_tn<<<dim3(8, 8), 256, 0, stream>>>(kf, Wv, lnw + HDIM, Bv, HDIM, H3DIM, HDIM);

    main_pair<<<dim3(KLEN / 8, QLEN / 8, BDIM), 256, 0, stream>>>(
        qbf, kbf, Au, Bu, Av, Bv, W3u, W3v, su, tu, sv, tv, Wo, bo, muA, riA, out);
}

// Round 2
// 1022.404 us; speedup vs baseline: 1.0599x; 1.0599x over previous
//
#include <hip/hip_runtime.h>
#include <hip/hip_bf16.h>

#define QLEN 256
#define QD 1024
#define HD 512
#define H3 1536
#define EPSF 1e-5f

typedef __attribute__((ext_vector_type(8))) short short8;
typedef __attribute__((ext_vector_type(4))) float f32x4;

__device__ inline short f2bf(float f) {
    union { float f; unsigned u; } v; v.f = f;
    unsigned r = v.u + 0x7FFF + ((v.u >> 16) & 1);
    return (short)(r >> 16);
}
__device__ inline float bf2f(short s) {
    union { float f; unsigned u; } v; v.u = ((unsigned)(unsigned short)s) << 16;
    return v.f;
}
__device__ inline unsigned pk2(float a, float b) {
    return ((unsigned)(unsigned short)f2bf(a)) | (((unsigned)(unsigned short)f2bf(b)) << 16);
}
__device__ inline unsigned mulbf2(unsigned a, unsigned b) {
    float a0 = bf2f((short)(a & 0xffff)), a1 = bf2f((short)(a >> 16));
    float b0 = bf2f((short)(b & 0xffff)), b1 = bf2f((short)(b >> 16));
    return pk2(a0 * b0, a1 * b1);
}

// ---------- weight prep: fold ln_w into all three K-thirds (bf16) + su/tu ----
__global__ __launch_bounds__(256) void prep_w(const float* __restrict__ Wm,
                                              const float* __restrict__ lnw,
                                              const float* __restrict__ lnb,
                                              const float* __restrict__ bias,
                                              short* __restrict__ W1,
                                              short* __restrict__ W2,
                                              short* __restrict__ W3,
                                              float* __restrict__ svec,
                                              float* __restrict__ tvec) {
    int h = blockIdx.x, tid = threadIdx.x;
    const float* row = Wm + h * H3;
    for (int j = tid; j < HD; j += 256) {
        W1[h * HD + j] = f2bf(lnw[j] * row[j]);
        W2[h * HD + j] = f2bf(lnw[HD + j] * row[HD + j]);
        W3[h * HD + j] = f2bf(lnw[2 * HD + j] * row[2 * HD + j]);
    }
    float s = 0.f, t = 0.f;
    for (int c = tid; c < H3; c += 256) {
        float w = row[c];
        s += lnw[c] * w;
        t += lnb[c] * w;
    }
    for (int m = 1; m < 64; m <<= 1) { s += __shfl_xor(s, m, 64); t += __shfl_xor(t, m, 64); }
    __shared__ float rs[4], rt[4];
    if ((tid & 63) == 0) { rs[tid >> 6] = s; rt[tid >> 6] = t; }
    __syncthreads();
    if (tid == 0) {
        svec[h] = rs[0] + rs[1] + rs[2] + rs[3];
        tvec[h] = rt[0] + rt[1] + rt[2] + rt[3] + bias[h];
    }
}

// ---------- row sums over bf16 rows (s1 = sum, s2 = sum of squares) ----------
__global__ __launch_bounds__(256) void rowstats(const unsigned* __restrict__ Xbf,
                                                float* __restrict__ s1,
                                                float* __restrict__ s2) {
    int row = blockIdx.x, tid = threadIdx.x;
    unsigned u = Xbf[row * 256 + tid];
    float a = bf2f((short)(u & 0xffff)), b = bf2f((short)(u >> 16));
    float s = a + b, q = a * a + b * b;
    for (int m = 1; m < 64; m <<= 1) { s += __shfl_xor(s, m, 64); q += __shfl_xor(q, m, 64); }
    __shared__ float rs[4], rq[4];
    if ((tid & 63) == 0) { rs[tid >> 6] = s; rq[tid >> 6] = q; }
    __syncthreads();
    if (tid == 0) {
        s1[row] = rs[0] + rs[1] + rs[2] + rs[3];
        s2[row] = rq[0] + rq[1] + rq[2] + rq[3];
    }
}

// ---------- generic bf16 MFMA GEMM: C[M,N] = A[M,K] * B[N,K]^T ---------------
// MODE 0: f32 out [row][col]   MODE 1: f32 out transposed [col][row]
// MODE 2: f32 inputs, bf16 out + bf16 square out
// MODE 3: dual GEMM (d1 = A*B^T, d2 = A2*B2^T) -> fused mu/ri stats
template<int MODE>
__global__ __launch_bounds__(256) void mm_k(const void* __restrict__ Ap,
                                            const void* __restrict__ Bp,
                                            const void* __restrict__ A2p,
                                            const void* __restrict__ B2p,
                                            float* __restrict__ OutF,
                                            short* __restrict__ OutB,
                                            short* __restrict__ OutB2,
                                            const float* __restrict__ s1q,
                                            const float* __restrict__ s2q,
                                            const float* __restrict__ s1k,
                                            const float* __restrict__ s2k,
                                            float* __restrict__ muA,
                                            float* __restrict__ riA,
                                            int K) {
    constexpr bool F32IN = (MODE == 2);
    constexpr bool ST = (MODE == 3);
    __shared__ short a_l[64][72], b_l[64][72];
    __shared__ short a2_l[ST ? 64 : 1][72], b2_l[ST ? 64 : 1][72];
    int t = threadIdx.x;
    int i0 = blockIdx.y * 64, n0 = blockIdx.x * 64, bz = blockIdx.z;
    int lane = t & 63, wv = t >> 6, wm = wv >> 1, wn = wv & 1;
    int l15 = lane & 15, lg = lane >> 4;
    f32x4 acc[2][2] = {};
    f32x4 acc2[ST ? 2 : 1][ST ? 2 : 1] = {};
    int sr = t >> 4, sc = (t & 15) * 4;
    size_t roff = ST ? (size_t)bz * QLEN : 0;

    for (int kc = 0; kc < K; kc += 64) {
#pragma unroll
        for (int rep = 0; rep < 4; ++rep) {
            int row = sr + rep * 16;
            if (F32IN) {
                const float* A = (const float*)Ap;
                const float* B = (const float*)Bp;
                float4 av = *(const float4*)&A[(size_t)(i0 + row) * K + kc + sc];
                float4 bv = *(const float4*)&B[(size_t)(n0 + row) * K + kc + sc];
                *(uint2*)&a_l[row][sc] = (uint2){pk2(av.x, av.y), pk2(av.z, av.w)};
                *(uint2*)&b_l[row][sc] = (uint2){pk2(bv.x, bv.y), pk2(bv.z, bv.w)};
            } else {
                const short* A = (const short*)Ap;
                const short* B = (const short*)Bp;
                *(uint2*)&a_l[row][sc] = *(const uint2*)&A[(roff + i0 + row) * K + kc + sc];
                *(uint2*)&b_l[row][sc] = *(const uint2*)&B[(roff + n0 + row) * K + kc + sc];
                if (ST) {
                    const short* A2 = (const short*)A2p;
                    const short* B2 = (const short*)B2p;
                    *(uint2*)&a2_l[row][sc] = *(const uint2*)&A2[(roff + i0 + row) * K + kc + sc];
                    *(uint2*)&b2_l[row][sc] = *(const uint2*)&B2[(roff + n0 + row) * K + kc + sc];
                }
            }
        }
        __syncthreads();
#pragma unroll
        for (int kk = 0; kk < 2; ++kk) {
            short8 af[2], bf_[2];
#pragma unroll
            for (int mi = 0; mi < 2; ++mi)
                af[mi] = *(const short8*)&a_l[wm * 32 + mi * 16 + l15][kk * 32 + lg * 8];
#pragma unroll
            for (int nj = 0; nj < 2; ++nj)
                bf_[nj] = *(const short8*)&b_l[wn * 32 + nj * 16 + l15][kk * 32 + lg * 8];
#pragma unroll
            for (int mi = 0; mi < 2; ++mi)
#pragma unroll
                for (int nj = 0; nj < 2; ++nj)
                    acc[mi][nj] = __builtin_amdgcn_mfma_f32_16x16x32_bf16(af[mi], bf_[nj], acc[mi][nj], 0, 0, 0);
            if (ST) {
                short8 af2[2], bf2_[2];
#pragma unroll
                for (int mi = 0; mi < 2; ++mi)
                    af2[mi] = *(const short8*)&a2_l[wm * 32 + mi * 16 + l15][kk * 32 + lg * 8];
#pragma unroll
                for (int nj = 0; nj < 2; ++nj)
                    bf2_[nj] = *(const short8*)&b2_l[wn * 32 + nj * 16 + l15][kk * 32 + lg * 8];
#pragma unroll
                for (int mi = 0; mi < 2; ++mi)
#pragma unroll
                    for (int nj = 0; nj < 2; ++nj)
                        acc2[mi][nj] = __builtin_amdgcn_mfma_f32_16x16x32_bf16(af2[mi], bf2_[nj], acc2[mi][nj], 0, 0, 0);
            }
        }
        __syncthreads();
    }

#pragma unroll
    for (int mi = 0; mi < 2; ++mi)
#pragma unroll
        for (int nj = 0; nj < 2; ++nj)
#pragma unroll
            for (int r = 0; r < 4; ++r) {
                int row = i0 + wm * 32 + mi * 16 + lg * 4 + r;
                int col = n0 + wn * 32 + nj * 16 + l15;
                float v = acc[mi][nj][r];
                if (MODE == 0) {
                    OutF[(size_t)row * HD + col] = v;
                } else if (MODE == 1) {
                    OutF[(size_t)col * HD + row] = v;
                } else if (MODE == 2) {
                    short qb = f2bf(v);
                    OutB[(size_t)row * HD + col] = qb;
                    float q = bf2f(qb);
                    OutB2[(size_t)row * HD + col] = f2bf(q * q);
                } else {
                    float d2 = acc2[mi][nj][r];
                    float mu = (s1q[bz * QLEN + row] + s1k[bz * QLEN + col] + v) * (1.f / H3);
                    float ex2 = (s2q[bz * QLEN + row] + s2k[bz * QLEN + col] + d2) * (1.f / H3);
                    float ri = rsqrtf(ex2 - mu * mu + EPSF);
                    size_t ix = ((size_t)bz * QLEN + row) * QLEN + col;
                    muA[ix] = mu;
                    riA[ix] = ri;
                }
            }
}

// ---------- main fused pair kernel (8 waves, 64 pairs, h split by wave) ------
__global__ __launch_bounds__(512, 3) void main_pair(const short* __restrict__ qbf,
                                                    const short* __restrict__ kbf,
                                                    const float* __restrict__ Au,
                                                    const float* __restrict__ Av,
                                                    const float* __restrict__ BuT,
                                                    const float* __restrict__ BvT,
                                                    const short* __restrict__ W3u,
                                                    const short* __restrict__ W3v,
                                                    const float* __restrict__ su,
                                                    const float* __restrict__ tu,
                                                    const float* __restrict__ sv,
                                                    const float* __restrict__ tv,
                                                    const float* __restrict__ Wo,
                                                    const float* __restrict__ bo,
                                                    const float* __restrict__ muA,
                                                    const float* __restrict__ riA,
                                                    float* __restrict__ out) {
    __shared__ short p_lds[64 * 512];   // 64 KB, XOR-swizzled rows
    __shared__ float sred[8][64];

    int tid = threadIdx.x;
    int b = blockIdx.z, qt = blockIdx.y, kt = blockIdx.x;
    int qbase = qt * 8, kbase = kt * 8;

    // p = q .* k  (bf16, swizzled rows: pair-major [64][512])
    for (int i = tid; i < 4096; i += 512) {
        int row = i >> 6, j0 = (i & 63) << 3;
        int qi = row >> 3, ki = row & 7;
        uint4 qv = *(const uint4*)&qbf[(size_t)(b * QLEN + qbase + qi) * HD + j0];
        uint4 kv = *(const uint4*)&kbf[(size_t)(b * QLEN + kbase + ki) * HD + j0];
        uint4 pv;
        pv.x = mulbf2(qv.x, kv.x); pv.y = mulbf2(qv.y, kv.y);
        pv.z = mulbf2(qv.z, kv.z); pv.w = mulbf2(qv.w, kv.w);
        unsigned off = row * 1024 + ((j0 * 2) ^ ((row & 7) << 4));
        *(uint4*)((char*)p_lds + off) = pv;
    }
    __syncthreads();

    int lane = tid & 63, wv = tid >> 6;
    int l15 = lane & 15, lg = lane >> 4;
    int qi_l = (lg >> 1), ki0 = (lg & 1) * 4;   // within-pair-tile decomposition

    float sacc[16];
#pragma unroll
    for (int i = 0; i < 16; ++i) sacc[i] = 0.f;

    for (int outer = 0; outer < 2; ++outer) {
        int hb = wv * 64 + outer * 32;
        // acc init = Au[qi,h] + Bu[ki,h]  (C-in of the MFMA)
        f32x4 aU[4][2], aV[4][2];
#pragma unroll
        for (int mi = 0; mi < 4; ++mi) {
            int qrow = b * QLEN + qbase + mi * 2 + qi_l;
            int krow4 = b * QLEN + kbase + ki0;
#pragma unroll
            for (int nj = 0; nj < 2; ++nj) {
                int h = hb + nj * 16 + l15;
                float au = Au[(size_t)qrow * HD + h];
                float av = Av[(size_t)qrow * HD + h];
                f32x4 bu4 = *(const f32x4*)&BuT[(size_t)h * 512 + krow4];
                f32x4 bv4 = *(const f32x4*)&BvT[(size_t)h * 512 + krow4];
#pragma unroll
                for (int r = 0; r < 4; ++r) {
                    aU[mi][nj][r] = au + bu4[r];
                    aV[mi][nj][r] = av + bv4[r];
                }
            }
        }
        // K loop over p (LDS) x W3 (global/L2)
        for (int kk = 0; kk < 512; kk += 32) {
            short8 bu_f[2], bv_f[2], a_f[4];
#pragma unroll
            for (int nj = 0; nj < 2; ++nj) {
                int h = hb + nj * 16 + l15;
                bu_f[nj] = *(const short8*)&W3u[(size_t)h * HD + kk + lg * 8];
                bv_f[nj] = *(const short8*)&W3v[(size_t)h * HD + kk + lg * 8];
            }
#pragma unroll
            for (int mi = 0; mi < 4; ++mi) {
                int row = mi * 16 + l15;
                unsigned off = row * 1024 + (((kk + lg * 8) * 2) ^ ((row & 7) << 4));
                a_f[mi] = *(const short8*)((const char*)p_lds + off);
            }
#pragma unroll
            for (int mi = 0; mi < 4; ++mi)
#pragma unroll
                for (int nj = 0; nj < 2; ++nj) {
                    aU[mi][nj] = __builtin_amdgcn_mfma_f32_16x16x32_bf16(a_f[mi], bu_f[nj], aU[mi][nj], 0, 0, 0);
                    aV[mi][nj] = __builtin_amdgcn_mfma_f32_16x16x32_bf16(a_f[mi], bv_f[nj], aV[mi][nj], 0, 0, 0);
                }
        }
        // fused epilogue: LN-linear + gelu(tanh) + Wo reduction
#pragma unroll
        for (int nj = 0; nj < 2; ++nj) {
            int h = hb + nj * 16 + l15;
            float suh = su[h], tuh = tu[h], svh = sv[h], tvh = tv[h], woh = Wo[h];
#pragma unroll
            for (int mi = 0; mi < 4; ++mi) {
                size_t pbase = (size_t)(b * QLEN + qbase + mi * 2 + qi_l) * QLEN + kbase + ki0;
#pragma unroll
                for (int r = 0; r < 4; ++r) {
                    float ri = riA[pbase + r];
                    float rmu = ri * muA[pbase + r];
                    float u = fmaf(ri, aU[mi][nj][r], tuh) - rmu * suh;
                    float vx = fmaf(ri, aV[mi][nj][r], tvh) - rmu * svh;
                    float x2 = vx * vx;
                    float tt = vx * fmaf(0.0356774081f, x2, 0.7978845608f);
                    float e2 = exp2f(tt * 2.885390082f);
                    float sig = 1.0f / (e2 + 1.0f);
                    float ge = vx - vx * sig;          // v * sigmoid(2t), inf-safe
                    sacc[mi * 4 + r] = fmaf(u * ge, woh, sacc[mi * 4 + r]);
                }
            }
        }
    }

    // reduce over 16 h-lanes, then across waves via LDS
#pragma unroll
    for (int i = 0; i < 16; ++i) {
        float v = sacc[i];
        v += __shfl_xor(v, 1, 64);
        v += __shfl_xor(v, 2, 64);
        v += __shfl_xor(v, 4, 64);
        v += __shfl_xor(v, 8, 64);
        sacc[i] = v;
    }
    if (l15 == 0) {
#pragma unroll
        for (int mi = 0; mi < 4; ++mi)
#pragma unroll
            for (int r = 0; r < 4; ++r)
                sred[wv][mi * 16 + lg * 4 + r] = sacc[mi * 4 + r];
    }
    __syncthreads();
    if (tid < 64) {
        float s = bo[0];
#pragma unroll
        for (int w = 0; w < 8; ++w) s += sred[w][tid];
        int qi = tid >> 3, ki = tid & 7;
        out[(size_t)(b * QLEN + qbase + qi) * QLEN + kbase + ki] = s;
    }
}

extern "C" void kernel_launch(void* const* d_in, const int* in_sizes, int n_in,
                              void* d_out, int out_size, void* d_ws, size_t ws_size,
                              hipStream_t stream) {
    const float* Q   = (const float*)d_in[0];
    const float* Kin = (const float*)d_in[1];
    const float* Wq  = (const float*)d_in[2];
    const float* Wk  = (const float*)d_in[3];
    const float* lnw = (const float*)d_in[4];
    const float* lnb = (const float*)d_in[5];
    const float* Wu  = (const float*)d_in[6];
    const float* bu  = (const float*)d_in[7];
    const float* Wv  = (const float*)d_in[8];
    const float* bv  = (const float*)d_in[9];
    const float* Wo  = (const float*)d_in[10];
    const float* bo  = (const float*)d_in[11];
    float* out = (float*)d_out;

    char* ws = (char*)d_ws;
    size_t off = 0;
    auto alloc = [&](size_t bytes) -> void* {
        void* p = ws + off;
        off += (bytes + 255) & ~(size_t)255;
        return p;
    };
    const size_t WB = (size_t)HD * HD * 2;  // 512 KB bf16 weight third
    short* W1u = (short*)alloc(WB); short* W2u = (short*)alloc(WB); short* W3u = (short*)alloc(WB);
    short* W1v = (short*)alloc(WB); short* W2v = (short*)alloc(WB); short* W3v = (short*)alloc(WB);
    short* qbf  = (short*)alloc(WB); short* q2bf = (short*)alloc(WB);
    short* kbf  = (short*)alloc(WB); short* k2bf = (short*)alloc(WB);
    float* su = (float*)alloc(HD * 4); float* tu = (float*)alloc(HD * 4);
    float* sv = (float*)alloc(HD * 4); float* tv = (float*)alloc(HD * 4);
    float* s1q = (float*)alloc(512 * 4); float* s2q = (float*)alloc(512 * 4);
    float* s1k = (float*)alloc(512 * 4); float* s2k = (float*)alloc(512 * 4);
    float* Au  = (float*)alloc((size_t)512 * HD * 4);
    float* Av  = (float*)alloc((size_t)512 * HD * 4);
    float* BuT = (float*)alloc((size_t)512 * HD * 4);
    float* BvT = (float*)alloc((size_t)512 * HD * 4);
    float* muA = (float*)alloc((size_t)2 * QLEN * QLEN * 4);
    float* riA = (float*)alloc((size_t)2 * QLEN * QLEN * 4);

    prep_w<<<HD, 256, 0, stream>>>(Wu, lnw, lnb, bu, W1u, W2u, W3u, su, tu);
    prep_w<<<HD, 256, 0, stream>>>(Wv, lnw, lnb, bv, W1v, W2v, W3v, sv, tv);

    // q/k projections (f32 in, bf16 + bf16^2 out), K=1024
    mm_k<2><<<dim3(8, 8, 1), 256, 0, stream>>>(Q, Wq, nullptr, nullptr, nullptr, qbf, q2bf,
                                               nullptr, nullptr, nullptr, nullptr, nullptr, nullptr, QD);
    mm_k<2><<<dim3(8, 8, 1), 256, 0, stream>>>(Kin, Wk, nullptr, nullptr, nullptr, kbf, k2bf,
                                               nullptr, nullptr, nullptr, nullptr, nullptr, nullptr, QD);

    rowstats<<<512, 256, 0, stream>>>((const unsigned*)qbf, s1q, s2q);
    rowstats<<<512, 256, 0, stream>>>((const unsigned*)kbf, s1k, s2k);

    // fused per-pair mu/ri (dual GEMM: qk dot + q2k2 dot)
    mm_k<3><<<dim3(4, 4, 2), 256, 0, stream>>>(qbf, kbf, q2bf, k2bf, nullptr, nullptr, nullptr,
                                               s1q, s2q, s1k, s2k, muA, riA, HD);

    // LN-linear per-row terms: Au/Av natural, Bu/Bv transposed
    mm_k<0><<<dim3(8, 8, 1), 256, 0, stream>>>(qbf, W1u, nullptr, nullptr, Au, nullptr, nullptr,
                                               nullptr, nullptr, nullptr, nullptr, nullptr, nullptr, HD);
    mm_k<0><<<dim3(8, 8, 1), 256, 0, stream>>>(qbf, W1v, nullptr, nullptr, Av, nullptr, nullptr,
                                               nullptr, nullptr, nullptr, nullptr, nullptr, nullptr, HD);
    mm_k<1><<<dim3(8, 8, 1), 256, 0, stream>>>(kbf, W2u, nullptr, nullptr, BuT, nullptr, nullptr,
                                               nullptr, nullptr, nullptr, nullptr, nullptr, nullptr, HD);
    mm_k<1><<<dim3(8, 8, 1), 256, 0, stream>>>(kbf, W2v, nullptr, nullptr, BvT, nullptr, nullptr,
                                               nullptr, nullptr, nullptr, nullptr, nullptr, nullptr, HD);

    main_pair<<<dim3(QLEN / 8, QLEN / 8, 2), 512, 0, stream>>>(
        qbf, kbf, Au, Av, BuT, BvT, W3u, W3v, su, tu, sv, tv, Wo, bo, muA, riA, out);
}

// Round 3
// 868.610 us; speedup vs baseline: 1.2475x; 1.1771x over previous
//
#include <hip/hip_runtime.h>
#include <hip/hip_bf16.h>

#define QLEN 256
#define QD 1024
#define HD 512
#define H3 1536
#define EPSF 1e-5f

typedef __attribute__((ext_vector_type(8))) short short8;
typedef __attribute__((ext_vector_type(4))) float f32x4;

__device__ inline short f2bf(float f) {
    union { float f; unsigned u; } v; v.f = f;
    unsigned r = v.u + 0x7FFF + ((v.u >> 16) & 1);
    return (short)(r >> 16);
}
__device__ inline float bf2f(short s) {
    union { float f; unsigned u; } v; v.u = ((unsigned)(unsigned short)s) << 16;
    return v.f;
}
__device__ inline unsigned pk2(float a, float b) {
    return ((unsigned)(unsigned short)f2bf(a)) | (((unsigned)(unsigned short)f2bf(b)) << 16);
}
__device__ inline unsigned mulbf2(unsigned a, unsigned b) {
    float a0 = bf2f((short)(a & 0xffff)), a1 = bf2f((short)(a >> 16));
    float b0 = bf2f((short)(b & 0xffff)), b1 = bf2f((short)(b >> 16));
    return pk2(a0 * b0, a1 * b1);
}

// ---------- weight prep: fold ln_w into all three K-thirds (bf16) + su/tu ----
__global__ __launch_bounds__(256) void prep_w(const float* __restrict__ Wm,
                                              const float* __restrict__ lnw,
                                              const float* __restrict__ lnb,
                                              const float* __restrict__ bias,
                                              short* __restrict__ W1,
                                              short* __restrict__ W2,
                                              short* __restrict__ W3,
                                              float* __restrict__ svec,
                                              float* __restrict__ tvec) {
    int h = blockIdx.x, tid = threadIdx.x;
    const float* row = Wm + h * H3;
    for (int j = tid; j < HD; j += 256) {
        W1[h * HD + j] = f2bf(lnw[j] * row[j]);
        W2[h * HD + j] = f2bf(lnw[HD + j] * row[HD + j]);
        W3[h * HD + j] = f2bf(lnw[2 * HD + j] * row[2 * HD + j]);
    }
    float s = 0.f, t = 0.f;
    for (int c = tid; c < H3; c += 256) {
        float w = row[c];
        s += lnw[c] * w;
        t += lnb[c] * w;
    }
    for (int m = 1; m < 64; m <<= 1) { s += __shfl_xor(s, m, 64); t += __shfl_xor(t, m, 64); }
    __shared__ float rs[4], rt[4];
    if ((tid & 63) == 0) { rs[tid >> 6] = s; rt[tid >> 6] = t; }
    __syncthreads();
    if (tid == 0) {
        svec[h] = rs[0] + rs[1] + rs[2] + rs[3];
        tvec[h] = rt[0] + rt[1] + rt[2] + rt[3] + bias[h];
    }
}

// ---------- row sums over bf16 rows (s1 = sum, s2 = sum of squares) ----------
__global__ __launch_bounds__(256) void rowstats(const unsigned* __restrict__ Xbf,
                                                float* __restrict__ s1,
                                                float* __restrict__ s2) {
    int row = blockIdx.x, tid = threadIdx.x;
    unsigned u = Xbf[row * 256 + tid];
    float a = bf2f((short)(u & 0xffff)), b = bf2f((short)(u >> 16));
    float s = a + b, q = a * a + b * b;
    for (int m = 1; m < 64; m <<= 1) { s += __shfl_xor(s, m, 64); q += __shfl_xor(q, m, 64); }
    __shared__ float rs[4], rq[4];
    if ((tid & 63) == 0) { rs[tid >> 6] = s; rq[tid >> 6] = q; }
    __syncthreads();
    if (tid == 0) {
        s1[row] = rs[0] + rs[1] + rs[2] + rs[3];
        s2[row] = rq[0] + rq[1] + rq[2] + rq[3];
    }
}

// ---------- generic bf16 MFMA GEMM: C[M,N] = A[M,K] * B[N,K]^T ---------------
// MODE 0: f32 out [row][col]   MODE 1: f32 out transposed [col][row]
// MODE 2: f32 inputs, bf16 out + bf16 square out
// MODE 3: dual GEMM (d1 = A*B^T, d2 = A2*B2^T) -> fused mu/ri stats
template<int MODE>
__global__ __launch_bounds__(256) void mm_k(const void* __restrict__ Ap,
                                            const void* __restrict__ Bp,
                                            const void* __restrict__ A2p,
                                            const void* __restrict__ B2p,
                                            float* __restrict__ OutF,
                                            short* __restrict__ OutB,
                                            short* __restrict__ OutB2,
                                            const float* __restrict__ s1q,
                                            const float* __restrict__ s2q,
                                            const float* __restrict__ s1k,
                                            const float* __restrict__ s2k,
                                            float* __restrict__ muA,
                                            float* __restrict__ riA,
                                            int K) {
    constexpr bool F32IN = (MODE == 2);
    constexpr bool ST = (MODE == 3);
    __shared__ short a_l[64][72], b_l[64][72];
    __shared__ short a2_l[ST ? 64 : 1][72], b2_l[ST ? 64 : 1][72];
    int t = threadIdx.x;
    int i0 = blockIdx.y * 64, n0 = blockIdx.x * 64, bz = blockIdx.z;
    int lane = t & 63, wv = t >> 6, wm = wv >> 1, wn = wv & 1;
    int l15 = lane & 15, lg = lane >> 4;
    f32x4 acc[2][2] = {};
    f32x4 acc2[ST ? 2 : 1][ST ? 2 : 1] = {};
    int sr = t >> 4, sc = (t & 15) * 4;
    size_t roff = ST ? (size_t)bz * QLEN : 0;

    for (int kc = 0; kc < K; kc += 64) {
#pragma unroll
        for (int rep = 0; rep < 4; ++rep) {
            int row = sr + rep * 16;
            if (F32IN) {
                const float* A = (const float*)Ap;
                const float* B = (const float*)Bp;
                float4 av = *(const float4*)&A[(size_t)(i0 + row) * K + kc + sc];
                float4 bv = *(const float4*)&B[(size_t)(n0 + row) * K + kc + sc];
                *(uint2*)&a_l[row][sc] = (uint2){pk2(av.x, av.y), pk2(av.z, av.w)};
                *(uint2*)&b_l[row][sc] = (uint2){pk2(bv.x, bv.y), pk2(bv.z, bv.w)};
            } else {
                const short* A = (const short*)Ap;
                const short* B = (const short*)Bp;
                *(uint2*)&a_l[row][sc] = *(const uint2*)&A[(roff + i0 + row) * K + kc + sc];
                *(uint2*)&b_l[row][sc] = *(const uint2*)&B[(roff + n0 + row) * K + kc + sc];
                if (ST) {
                    const short* A2 = (const short*)A2p;
                    const short* B2 = (const short*)B2p;
                    *(uint2*)&a2_l[row][sc] = *(const uint2*)&A2[(roff + i0 + row) * K + kc + sc];
                    *(uint2*)&b2_l[row][sc] = *(const uint2*)&B2[(roff + n0 + row) * K + kc + sc];
                }
            }
        }
        __syncthreads();
#pragma unroll
        for (int kk = 0; kk < 2; ++kk) {
            short8 af[2], bf_[2];
#pragma unroll
            for (int mi = 0; mi < 2; ++mi)
                af[mi] = *(const short8*)&a_l[wm * 32 + mi * 16 + l15][kk * 32 + lg * 8];
#pragma unroll
            for (int nj = 0; nj < 2; ++nj)
                bf_[nj] = *(const short8*)&b_l[wn * 32 + nj * 16 + l15][kk * 32 + lg * 8];
#pragma unroll
            for (int mi = 0; mi < 2; ++mi)
#pragma unroll
                for (int nj = 0; nj < 2; ++nj)
                    acc[mi][nj] = __builtin_amdgcn_mfma_f32_16x16x32_bf16(af[mi], bf_[nj], acc[mi][nj], 0, 0, 0);
            if (ST) {
                short8 af2[2], bf2_[2];
#pragma unroll
                for (int mi = 0; mi < 2; ++mi)
                    af2[mi] = *(const short8*)&a2_l[wm * 32 + mi * 16 + l15][kk * 32 + lg * 8];
#pragma unroll
                for (int nj = 0; nj < 2; ++nj)
                    bf2_[nj] = *(const short8*)&b2_l[wn * 32 + nj * 16 + l15][kk * 32 + lg * 8];
#pragma unroll
                for (int mi = 0; mi < 2; ++mi)
#pragma unroll
                    for (int nj = 0; nj < 2; ++nj)
                        acc2[mi][nj] = __builtin_amdgcn_mfma_f32_16x16x32_bf16(af2[mi], bf2_[nj], acc2[mi][nj], 0, 0, 0);
            }
        }
        __syncthreads();
    }

#pragma unroll
    for (int mi = 0; mi < 2; ++mi)
#pragma unroll
        for (int nj = 0; nj < 2; ++nj)
#pragma unroll
            for (int r = 0; r < 4; ++r) {
                int row = i0 + wm * 32 + mi * 16 + lg * 4 + r;
                int col = n0 + wn * 32 + nj * 16 + l15;
                float v = acc[mi][nj][r];
                if (MODE == 0) {
                    OutF[(size_t)row * HD + col] = v;
                } else if (MODE == 1) {
                    OutF[(size_t)col * HD + row] = v;
                } else if (MODE == 2) {
                    short qb = f2bf(v);
                    OutB[(size_t)row * HD + col] = qb;
                    float q = bf2f(qb);
                    OutB2[(size_t)row * HD + col] = f2bf(q * q);
                } else {
                    float d2 = acc2[mi][nj][r];
                    float mu = (s1q[bz * QLEN + row] + s1k[bz * QLEN + col] + v) * (1.f / H3);
                    float ex2 = (s2q[bz * QLEN + row] + s2k[bz * QLEN + col] + d2) * (1.f / H3);
                    float ri = rsqrtf(ex2 - mu * mu + EPSF);
                    size_t ix = ((size_t)bz * QLEN + row) * QLEN + col;
                    muA[ix] = mu;
                    riA[ix] = ri;
                }
            }
}

// ---------- main fused pair kernel (8 waves, 64 pairs, h split by wave) ------
__global__ __launch_bounds__(512) void main_pair(const short* __restrict__ qbf,
                                                 const short* __restrict__ kbf,
                                                 const float* __restrict__ Au,
                                                 const float* __restrict__ Av,
                                                 const float* __restrict__ BuT,
                                                 const float* __restrict__ BvT,
                                                 const short* __restrict__ W3u,
                                                 const short* __restrict__ W3v,
                                                 const float* __restrict__ su,
                                                 const float* __restrict__ tu,
                                                 const float* __restrict__ sv,
                                                 const float* __restrict__ tv,
                                                 const float* __restrict__ Wo,
                                                 const float* __restrict__ bo,
                                                 const float* __restrict__ muA,
                                                 const float* __restrict__ riA,
                                                 float* __restrict__ out) {
    __shared__ short p_lds[64 * 512];   // 64 KB, XOR-swizzled rows
    __shared__ float sred[8][64];

    int tid = threadIdx.x;
    int b = blockIdx.z, qt = blockIdx.y, kt = blockIdx.x;
    int qbase = qt * 8, kbase = kt * 8;

    // p = q .* k  (bf16, swizzled rows: pair-major [64][512])
    for (int i = tid; i < 4096; i += 512) {
        int row = i >> 6, j0 = (i & 63) << 3;
        int qi = row >> 3, ki = row & 7;
        uint4 qv = *(const uint4*)&qbf[(size_t)(b * QLEN + qbase + qi) * HD + j0];
        uint4 kv = *(const uint4*)&kbf[(size_t)(b * QLEN + kbase + ki) * HD + j0];
        uint4 pv;
        pv.x = mulbf2(qv.x, kv.x); pv.y = mulbf2(qv.y, kv.y);
        pv.z = mulbf2(qv.z, kv.z); pv.w = mulbf2(qv.w, kv.w);
        unsigned off = row * 1024 + ((j0 * 2) ^ ((row & 7) << 4));
        *(uint4*)((char*)p_lds + off) = pv;
    }
    __syncthreads();

    int lane = tid & 63, wv = tid >> 6;
    int l15 = lane & 15, lg = lane >> 4;
    int qi_l = (lg >> 1), ki0 = (lg & 1) * 4;   // within-pair-tile decomposition

    float sacc[16];
#pragma unroll
    for (int i = 0; i < 16; ++i) sacc[i] = 0.f;

    for (int outer = 0; outer < 2; ++outer) {
        int hb = wv * 64 + outer * 32;
        // acc init = Au[qi,h] + Bu[ki,h]  (C-in of the MFMA)
        f32x4 aU[4][2], aV[4][2];
#pragma unroll
        for (int mi = 0; mi < 4; ++mi) {
            int qrow = b * QLEN + qbase + mi * 2 + qi_l;
            int krow4 = b * QLEN + kbase + ki0;
#pragma unroll
            for (int nj = 0; nj < 2; ++nj) {
                int h = hb + nj * 16 + l15;
                float au = Au[(size_t)qrow * HD + h];
                float av = Av[(size_t)qrow * HD + h];
                f32x4 bu4 = *(const f32x4*)&BuT[(size_t)h * 512 + krow4];
                f32x4 bv4 = *(const f32x4*)&BvT[(size_t)h * 512 + krow4];
#pragma unroll
                for (int r = 0; r < 4; ++r) {
                    aU[mi][nj][r] = au + bu4[r];
                    aV[mi][nj][r] = av + bv4[r];
                }
            }
        }
        // K loop over p (LDS) x W3 (global/L2)
        for (int kk = 0; kk < 512; kk += 32) {
            short8 bu_f[2], bv_f[2], a_f[4];
#pragma unroll
            for (int nj = 0; nj < 2; ++nj) {
                int h = hb + nj * 16 + l15;
                bu_f[nj] = *(const short8*)&W3u[(size_t)h * HD + kk + lg * 8];
                bv_f[nj] = *(const short8*)&W3v[(size_t)h * HD + kk + lg * 8];
            }
#pragma unroll
            for (int mi = 0; mi < 4; ++mi) {
                int row = mi * 16 + l15;
                unsigned off = row * 1024 + (((kk + lg * 8) * 2) ^ ((row & 7) << 4));
                a_f[mi] = *(const short8*)((const char*)p_lds + off);
            }
#pragma unroll
            for (int mi = 0; mi < 4; ++mi)
#pragma unroll
                for (int nj = 0; nj < 2; ++nj) {
                    aU[mi][nj] = __builtin_amdgcn_mfma_f32_16x16x32_bf16(a_f[mi], bu_f[nj], aU[mi][nj], 0, 0, 0);
                    aV[mi][nj] = __builtin_amdgcn_mfma_f32_16x16x32_bf16(a_f[mi], bv_f[nj], aV[mi][nj], 0, 0, 0);
                }
        }
        // fused epilogue: LN-linear + gelu(tanh) + Wo reduction
#pragma unroll
        for (int nj = 0; nj < 2; ++nj) {
            int h = hb + nj * 16 + l15;
            float suh = su[h], tuh = tu[h], svh = sv[h], tvh = tv[h], woh = Wo[h];
#pragma unroll
            for (int mi = 0; mi < 4; ++mi) {
                size_t pbase = (size_t)(b * QLEN + qbase + mi * 2 + qi_l) * QLEN + kbase + ki0;
#pragma unroll
                for (int r = 0; r < 4; ++r) {
                    float ri = riA[pbase + r];
                    float rmu = ri * muA[pbase + r];
                    float u = fmaf(ri, aU[mi][nj][r], tuh) - rmu * suh;
                    float vx = fmaf(ri, aV[mi][nj][r], tvh) - rmu * svh;
                    float x2 = vx * vx;
                    float tt = vx * fmaf(0.0356774081f, x2, 0.7978845608f);
                    float e2 = exp2f(tt * 2.885390082f);
                    float sig = 1.0f / (e2 + 1.0f);
                    float ge = vx - vx * sig;          // v * sigmoid(2t), inf-safe
                    sacc[mi * 4 + r] = fmaf(u * ge, woh, sacc[mi * 4 + r]);
                }
            }
        }
    }

    // reduce over 16 h-lanes, then across waves via LDS
#pragma unroll
    for (int i = 0; i < 16; ++i) {
        float v = sacc[i];
        v += __shfl_xor(v, 1, 64);
        v += __shfl_xor(v, 2, 64);
        v += __shfl_xor(v, 4, 64);
        v += __shfl_xor(v, 8, 64);
        sacc[i] = v;
    }
    if (l15 == 0) {
#pragma unroll
        for (int mi = 0; mi < 4; ++mi)
#pragma unroll
            for (int r = 0; r < 4; ++r)
                sred[wv][mi * 16 + lg * 4 + r] = sacc[mi * 4 + r];
    }
    __syncthreads();
    if (tid < 64) {
        float s = bo[0];
#pragma unroll
        for (int w = 0; w < 8; ++w) s += sred[w][tid];
        int qi = tid >> 3, ki = tid & 7;
        out[(size_t)(b * QLEN + qbase + qi) * QLEN + kbase + ki] = s;
    }
}

extern "C" void kernel_launch(void* const* d_in, const int* in_sizes, int n_in,
                              void* d_out, int out_size, void* d_ws, size_t ws_size,
                              hipStream_t stream) {
    const float* Q   = (const float*)d_in[0];
    const float* Kin = (const float*)d_in[1];
    const float* Wq  = (const float*)d_in[2];
    const float* Wk  = (const float*)d_in[3];
    const float* lnw = (const float*)d_in[4];
    const float* lnb = (const float*)d_in[5];
    const float* Wu  = (const float*)d_in[6];
    const float* bu  = (const float*)d_in[7];
    const float* Wv  = (const float*)d_in[8];
    const float* bv  = (const float*)d_in[9];
    const float* Wo  = (const float*)d_in[10];
    const float* bo  = (const float*)d_in[11];
    float* out = (float*)d_out;

    char* ws = (char*)d_ws;
    size_t off = 0;
    auto alloc = [&](size_t bytes) -> void* {
        void* p = ws + off;
        off += (bytes + 255) & ~(size_t)255;
        return p;
    };
    const size_t WB = (size_t)HD * HD * 2;  // 512 KB bf16 weight third
    short* W1u = (short*)alloc(WB); short* W2u = (short*)alloc(WB); short* W3u = (short*)alloc(WB);
    short* W1v = (short*)alloc(WB); short* W2v = (short*)alloc(WB); short* W3v = (short*)alloc(WB);
    short* qbf  = (short*)alloc(WB); short* q2bf = (short*)alloc(WB);
    short* kbf  = (short*)alloc(WB); short* k2bf = (short*)alloc(WB);
    float* su = (float*)alloc(HD * 4); float* tu = (float*)alloc(HD * 4);
    float* sv = (float*)alloc(HD * 4); float* tv = (float*)alloc(HD * 4);
    float* s1q = (float*)alloc(512 * 4); float* s2q = (float*)alloc(512 * 4);
    float* s1k = (float*)alloc(512 * 4); float* s2k = (float*)alloc(512 * 4);
    float* Au  = (float*)alloc((size_t)512 * HD * 4);
    float* Av  = (float*)alloc((size_t)512 * HD * 4);
    float* BuT = (float*)alloc((size_t)512 * HD * 4);
    float* BvT = (float*)alloc((size_t)512 * HD * 4);
    float* muA = (float*)alloc((size_t)2 * QLEN * QLEN * 4);
    float* riA = (float*)alloc((size_t)2 * QLEN * QLEN * 4);

    prep_w<<<HD, 256, 0, stream>>>(Wu, lnw, lnb, bu, W1u, W2u, W3u, su, tu);
    prep_w<<<HD, 256, 0, stream>>>(Wv, lnw, lnb, bv, W1v, W2v, W3v, sv, tv);

    // q/k projections (f32 in, bf16 + bf16^2 out), K=1024
    mm_k<2><<<dim3(8, 8, 1), 256, 0, stream>>>(Q, Wq, nullptr, nullptr, nullptr, qbf, q2bf,
                                               nullptr, nullptr, nullptr, nullptr, nullptr, nullptr, QD);
    mm_k<2><<<dim3(8, 8, 1), 256, 0, stream>>>(Kin, Wk, nullptr, nullptr, nullptr, kbf, k2bf,
                                               nullptr, nullptr, nullptr, nullptr, nullptr, nullptr, QD);

    rowstats<<<512, 256, 0, stream>>>((const unsigned*)qbf, s1q, s2q);
    rowstats<<<512, 256, 0, stream>>>((const unsigned*)kbf, s1k, s2k);

    // fused per-pair mu/ri (dual GEMM: qk dot + q2k2 dot)
    mm_k<3><<<dim3(4, 4, 2), 256, 0, stream>>>(qbf, kbf, q2bf, k2bf, nullptr, nullptr, nullptr,
                                               s1q, s2q, s1k, s2k, muA, riA, HD);

    // LN-linear per-row terms: Au/Av natural, Bu/Bv transposed
    mm_k<0><<<dim3(8, 8, 1), 256, 0, stream>>>(qbf, W1u, nullptr, nullptr, Au, nullptr, nullptr,
                                               nullptr, nullptr, nullptr, nullptr, nullptr, nullptr, HD);
    mm_k<0><<<dim3(8, 8, 1), 256, 0, stream>>>(qbf, W1v, nullptr, nullptr, Av, nullptr, nullptr,
                                               nullptr, nullptr, nullptr, nullptr, nullptr, nullptr, HD);
    mm_k<1><<<dim3(8, 8, 1), 256, 0, stream>>>(kbf, W2u, nullptr, nullptr, BuT, nullptr, nullptr,
                                               nullptr, nullptr, nullptr, nullptr, nullptr, nullptr, HD);
    mm_k<1><<<dim3(8, 8, 1), 256, 0, stream>>>(kbf, W2v, nullptr, nullptr, BvT, nullptr, nullptr,
                                               nullptr, nullptr, nullptr, nullptr, nullptr, nullptr, HD);

    main_pair<<<dim3(QLEN / 8, QLEN / 8, 2), 512, 0, stream>>>(
        qbf, kbf, Au, Av, BuT, BvT, W3u, W3v, su, tu, sv, tv, Wo, bo, muA, riA, out);
}

// Round 4
// 857.559 us; speedup vs baseline: 1.2636x; 1.0129x over previous
//
#include <hip/hip_runtime.h>
#include <hip/hip_bf16.h>

#define QLEN 256
#define QD 1024
#define HD 512
#define H3 1536
#define EPSF 1e-5f

typedef __attribute__((ext_vector_type(8))) short short8;
typedef __attribute__((ext_vector_type(4))) float f32x4;

__device__ inline short f2bf(float f) {
    union { float f; unsigned u; } v; v.f = f;
    unsigned r = v.u + 0x7FFF + ((v.u >> 16) & 1);
    return (short)(r >> 16);
}
__device__ inline float bf2f(short s) {
    union { float f; unsigned u; } v; v.u = ((unsigned)(unsigned short)s) << 16;
    return v.f;
}
__device__ inline unsigned pk2(float a, float b) {
    return ((unsigned)(unsigned short)f2bf(a)) | (((unsigned)(unsigned short)f2bf(b)) << 16);
}
__device__ inline unsigned mulbf2(unsigned a, unsigned b) {
    float a0 = bf2f((short)(a & 0xffff)), a1 = bf2f((short)(a >> 16));
    float b0 = bf2f((short)(b & 0xffff)), b1 = bf2f((short)(b >> 16));
    return pk2(a0 * b0, a1 * b1);
}

// ---------- weight prep: fold ln_w into all three K-thirds (bf16) + su/tu ----
__global__ __launch_bounds__(256) void prep_w(const float* __restrict__ Wm,
                                              const float* __restrict__ lnw,
                                              const float* __restrict__ lnb,
                                              const float* __restrict__ bias,
                                              short* __restrict__ W1,
                                              short* __restrict__ W2,
                                              short* __restrict__ W3,
                                              float* __restrict__ svec,
                                              float* __restrict__ tvec) {
    int h = blockIdx.x, tid = threadIdx.x;
    const float* row = Wm + h * H3;
    for (int j = tid; j < HD; j += 256) {
        W1[h * HD + j] = f2bf(lnw[j] * row[j]);
        W2[h * HD + j] = f2bf(lnw[HD + j] * row[HD + j]);
        W3[h * HD + j] = f2bf(lnw[2 * HD + j] * row[2 * HD + j]);
    }
    float s = 0.f, t = 0.f;
    for (int c = tid; c < H3; c += 256) {
        float w = row[c];
        s += lnw[c] * w;
        t += lnb[c] * w;
    }
    for (int m = 1; m < 64; m <<= 1) { s += __shfl_xor(s, m, 64); t += __shfl_xor(t, m, 64); }
    __shared__ float rs[4], rt[4];
    if ((tid & 63) == 0) { rs[tid >> 6] = s; rt[tid >> 6] = t; }
    __syncthreads();
    if (tid == 0) {
        svec[h] = rs[0] + rs[1] + rs[2] + rs[3];
        tvec[h] = rt[0] + rt[1] + rt[2] + rt[3] + bias[h];
    }
}

// ---------- row sums over bf16 rows (s1 = sum, s2 = sum of squares) ----------
__global__ __launch_bounds__(256) void rowstats(const unsigned* __restrict__ Xbf,
                                                float* __restrict__ s1,
                                                float* __restrict__ s2) {
    int row = blockIdx.x, tid = threadIdx.x;
    unsigned u = Xbf[row * 256 + tid];
    float a = bf2f((short)(u & 0xffff)), b = bf2f((short)(u >> 16));
    float s = a + b, q = a * a + b * b;
    for (int m = 1; m < 64; m <<= 1) { s += __shfl_xor(s, m, 64); q += __shfl_xor(q, m, 64); }
    __shared__ float rs[4], rq[4];
    if ((tid & 63) == 0) { rs[tid >> 6] = s; rq[tid >> 6] = q; }
    __syncthreads();
    if (tid == 0) {
        s1[row] = rs[0] + rs[1] + rs[2] + rs[3];
        s2[row] = rq[0] + rq[1] + rq[2] + rq[3];
    }
}

// ---------- generic bf16 MFMA GEMM: C[M,N] = A[M,K] * B[N,K]^T ---------------
// MODE 0: f32 out [row][col]   MODE 1: f32 out transposed [col][row]
// MODE 2: f32 inputs, bf16 out + bf16 square out
// MODE 3: dual GEMM (d1 = A*B^T, d2 = A2*B2^T) -> fused mu/ri stats
template<int MODE>
__global__ __launch_bounds__(256) void mm_k(const void* __restrict__ Ap,
                                            const void* __restrict__ Bp,
                                            const void* __restrict__ A2p,
                                            const void* __restrict__ B2p,
                                            float* __restrict__ OutF,
                                            short* __restrict__ OutB,
                                            short* __restrict__ OutB2,
                                            const float* __restrict__ s1q,
                                            const float* __restrict__ s2q,
                                            const float* __restrict__ s1k,
                                            const float* __restrict__ s2k,
                                            float* __restrict__ muA,
                                            float* __restrict__ riA,
                                            int K) {
    constexpr bool F32IN = (MODE == 2);
    constexpr bool ST = (MODE == 3);
    __shared__ short a_l[64][72], b_l[64][72];
    __shared__ short a2_l[ST ? 64 : 1][72], b2_l[ST ? 64 : 1][72];
    int t = threadIdx.x;
    int i0 = blockIdx.y * 64, n0 = blockIdx.x * 64, bz = blockIdx.z;
    int lane = t & 63, wv = t >> 6, wm = wv >> 1, wn = wv & 1;
    int l15 = lane & 15, lg = lane >> 4;
    f32x4 acc[2][2] = {};
    f32x4 acc2[ST ? 2 : 1][ST ? 2 : 1] = {};
    int sr = t >> 4, sc = (t & 15) * 4;
    size_t roff = ST ? (size_t)bz * QLEN : 0;

    for (int kc = 0; kc < K; kc += 64) {
#pragma unroll
        for (int rep = 0; rep < 4; ++rep) {
            int row = sr + rep * 16;
            if (F32IN) {
                const float* A = (const float*)Ap;
                const float* B = (const float*)Bp;
                float4 av = *(const float4*)&A[(size_t)(i0 + row) * K + kc + sc];
                float4 bv = *(const float4*)&B[(size_t)(n0 + row) * K + kc + sc];
                *(uint2*)&a_l[row][sc] = (uint2){pk2(av.x, av.y), pk2(av.z, av.w)};
                *(uint2*)&b_l[row][sc] = (uint2){pk2(bv.x, bv.y), pk2(bv.z, bv.w)};
            } else {
                const short* A = (const short*)Ap;
                const short* B = (const short*)Bp;
                *(uint2*)&a_l[row][sc] = *(const uint2*)&A[(roff + i0 + row) * K + kc + sc];
                *(uint2*)&b_l[row][sc] = *(const uint2*)&B[(roff + n0 + row) * K + kc + sc];
                if (ST) {
                    const short* A2 = (const short*)A2p;
                    const short* B2 = (const short*)B2p;
                    *(uint2*)&a2_l[row][sc] = *(const uint2*)&A2[(roff + i0 + row) * K + kc + sc];
                    *(uint2*)&b2_l[row][sc] = *(const uint2*)&B2[(roff + n0 + row) * K + kc + sc];
                }
            }
        }
        __syncthreads();
#pragma unroll
        for (int kk = 0; kk < 2; ++kk) {
            short8 af[2], bf_[2];
#pragma unroll
            for (int mi = 0; mi < 2; ++mi)
                af[mi] = *(const short8*)&a_l[wm * 32 + mi * 16 + l15][kk * 32 + lg * 8];
#pragma unroll
            for (int nj = 0; nj < 2; ++nj)
                bf_[nj] = *(const short8*)&b_l[wn * 32 + nj * 16 + l15][kk * 32 + lg * 8];
#pragma unroll
            for (int mi = 0; mi < 2; ++mi)
#pragma unroll
                for (int nj = 0; nj < 2; ++nj)
                    acc[mi][nj] = __builtin_amdgcn_mfma_f32_16x16x32_bf16(af[mi], bf_[nj], acc[mi][nj], 0, 0, 0);
            if (ST) {
                short8 af2[2], bf2_[2];
#pragma unroll
                for (int mi = 0; mi < 2; ++mi)
                    af2[mi] = *(const short8*)&a2_l[wm * 32 + mi * 16 + l15][kk * 32 + lg * 8];
#pragma unroll
                for (int nj = 0; nj < 2; ++nj)
                    bf2_[nj] = *(const short8*)&b2_l[wn * 32 + nj * 16 + l15][kk * 32 + lg * 8];
#pragma unroll
                for (int mi = 0; mi < 2; ++mi)
#pragma unroll
                    for (int nj = 0; nj < 2; ++nj)
                        acc2[mi][nj] = __builtin_amdgcn_mfma_f32_16x16x32_bf16(af2[mi], bf2_[nj], acc2[mi][nj], 0, 0, 0);
            }
        }
        __syncthreads();
    }

#pragma unroll
    for (int mi = 0; mi < 2; ++mi)
#pragma unroll
        for (int nj = 0; nj < 2; ++nj)
#pragma unroll
            for (int r = 0; r < 4; ++r) {
                int row = i0 + wm * 32 + mi * 16 + lg * 4 + r;
                int col = n0 + wn * 32 + nj * 16 + l15;
                float v = acc[mi][nj][r];
                if (MODE == 0) {
                    OutF[(size_t)row * HD + col] = v;
                } else if (MODE == 1) {
                    OutF[(size_t)col * HD + row] = v;
                } else if (MODE == 2) {
                    short qb = f2bf(v);
                    OutB[(size_t)row * HD + col] = qb;
                    float q = bf2f(qb);
                    OutB2[(size_t)row * HD + col] = f2bf(q * q);
                } else {
                    float d2 = acc2[mi][nj][r];
                    float mu = (s1q[bz * QLEN + row] + s1k[bz * QLEN + col] + v) * (1.f / H3);
                    float ex2 = (s2q[bz * QLEN + row] + s2k[bz * QLEN + col] + d2) * (1.f / H3);
                    float ri = rsqrtf(ex2 - mu * mu + EPSF);
                    size_t ix = ((size_t)bz * QLEN + row) * QLEN + col;
                    muA[ix] = mu;
                    riA[ix] = ri;
                }
            }
}

// ---------- main fused pair kernel (8 waves, 64 pairs, h split by wave) ------
// __launch_bounds__(512, 2): min 2 waves/EU = 8 waves/CU -> VGPR cap 256.
// At cap 128 (2 blocks/CU) the MFMA accumulators spill: R3 showed 762 MB
// scratch WRITE_SIZE. 1 block/CU with zero spill wins.
__global__ __launch_bounds__(512, 2) void main_pair(const short* __restrict__ qbf,
                                                    const short* __restrict__ kbf,
                                                    const float* __restrict__ Au,
                                                    const float* __restrict__ Av,
                                                    const float* __restrict__ BuT,
                                                    const float* __restrict__ BvT,
                                                    const short* __restrict__ W3u,
                                                    const short* __restrict__ W3v,
                                                    const float* __restrict__ su,
                                                    const float* __restrict__ tu,
                                                    const float* __restrict__ sv,
                                                    const float* __restrict__ tv,
                                                    const float* __restrict__ Wo,
                                                    const float* __restrict__ bo,
                                                    const float* __restrict__ muA,
                                                    const float* __restrict__ riA,
                                                    float* __restrict__ out) {
    __shared__ short p_lds[64 * 512];   // 64 KB, XOR-swizzled rows
    __shared__ float sred[8][64];

    int tid = threadIdx.x;
    int b = blockIdx.z, qt = blockIdx.y, kt = blockIdx.x;
    int qbase = qt * 8, kbase = kt * 8;

    // p = q .* k  (bf16, swizzled rows: pair-major [64][512])
    for (int i = tid; i < 4096; i += 512) {
        int row = i >> 6, j0 = (i & 63) << 3;
        int qi = row >> 3, ki = row & 7;
        uint4 qv = *(const uint4*)&qbf[(size_t)(b * QLEN + qbase + qi) * HD + j0];
        uint4 kv = *(const uint4*)&kbf[(size_t)(b * QLEN + kbase + ki) * HD + j0];
        uint4 pv;
        pv.x = mulbf2(qv.x, kv.x); pv.y = mulbf2(qv.y, kv.y);
        pv.z = mulbf2(qv.z, kv.z); pv.w = mulbf2(qv.w, kv.w);
        unsigned off = row * 1024 + ((j0 * 2) ^ ((row & 7) << 4));
        *(uint4*)((char*)p_lds + off) = pv;
    }
    __syncthreads();

    int lane = tid & 63, wv = tid >> 6;
    int l15 = lane & 15, lg = lane >> 4;
    int qi_l = (lg >> 1), ki0 = (lg & 1) * 4;   // within-pair-tile decomposition

    float sacc[16];
#pragma unroll
    for (int i = 0; i < 16; ++i) sacc[i] = 0.f;

    for (int outer = 0; outer < 2; ++outer) {
        int hb = wv * 64 + outer * 32;
        // acc init = Au[qi,h] + Bu[ki,h]  (C-in of the MFMA)
        f32x4 aU[4][2], aV[4][2];
#pragma unroll
        for (int mi = 0; mi < 4; ++mi) {
            int qrow = b * QLEN + qbase + mi * 2 + qi_l;
            int krow4 = b * QLEN + kbase + ki0;
#pragma unroll
            for (int nj = 0; nj < 2; ++nj) {
                int h = hb + nj * 16 + l15;
                float au = Au[(size_t)qrow * HD + h];
                float av = Av[(size_t)qrow * HD + h];
                f32x4 bu4 = *(const f32x4*)&BuT[(size_t)h * 512 + krow4];
                f32x4 bv4 = *(const f32x4*)&BvT[(size_t)h * 512 + krow4];
#pragma unroll
                for (int r = 0; r < 4; ++r) {
                    aU[mi][nj][r] = au + bu4[r];
                    aV[mi][nj][r] = av + bv4[r];
                }
            }
        }
        // K loop over p (LDS) x W3 (global/L2)
        for (int kk = 0; kk < 512; kk += 32) {
            short8 bu_f[2], bv_f[2], a_f[4];
#pragma unroll
            for (int nj = 0; nj < 2; ++nj) {
                int h = hb + nj * 16 + l15;
                bu_f[nj] = *(const short8*)&W3u[(size_t)h * HD + kk + lg * 8];
                bv_f[nj] = *(const short8*)&W3v[(size_t)h * HD + kk + lg * 8];
            }
#pragma unroll
            for (int mi = 0; mi < 4; ++mi) {
                int row = mi * 16 + l15;
                unsigned off = row * 1024 + (((kk + lg * 8) * 2) ^ ((row & 7) << 4));
                a_f[mi] = *(const short8*)((const char*)p_lds + off);
            }
#pragma unroll
            for (int mi = 0; mi < 4; ++mi)
#pragma unroll
                for (int nj = 0; nj < 2; ++nj) {
                    aU[mi][nj] = __builtin_amdgcn_mfma_f32_16x16x32_bf16(a_f[mi], bu_f[nj], aU[mi][nj], 0, 0, 0);
                    aV[mi][nj] = __builtin_amdgcn_mfma_f32_16x16x32_bf16(a_f[mi], bv_f[nj], aV[mi][nj], 0, 0, 0);
                }
        }
        // fused epilogue: LN-linear + gelu(tanh) + Wo reduction
#pragma unroll
        for (int nj = 0; nj < 2; ++nj) {
            int h = hb + nj * 16 + l15;
            float suh = su[h], tuh = tu[h], svh = sv[h], tvh = tv[h], woh = Wo[h];
#pragma unroll
            for (int mi = 0; mi < 4; ++mi) {
                size_t pbase = (size_t)(b * QLEN + qbase + mi * 2 + qi_l) * QLEN + kbase + ki0;
#pragma unroll
                for (int r = 0; r < 4; ++r) {
                    float ri = riA[pbase + r];
                    float rmu = ri * muA[pbase + r];
                    float u = fmaf(ri, aU[mi][nj][r], tuh) - rmu * suh;
                    float vx = fmaf(ri, aV[mi][nj][r], tvh) - rmu * svh;
                    float x2 = vx * vx;
                    float tt = vx * fmaf(0.0356774081f, x2, 0.7978845608f);
                    float e2 = exp2f(tt * 2.885390082f);
                    float sig = 1.0f / (e2 + 1.0f);
                    float ge = vx - vx * sig;          // v * sigmoid(2t), inf-safe
                    sacc[mi * 4 + r] = fmaf(u * ge, woh, sacc[mi * 4 + r]);
                }
            }
        }
    }

    // reduce over 16 h-lanes, then across waves via LDS
#pragma unroll
    for (int i = 0; i < 16; ++i) {
        float v = sacc[i];
        v += __shfl_xor(v, 1, 64);
        v += __shfl_xor(v, 2, 64);
        v += __shfl_xor(v, 4, 64);
        v += __shfl_xor(v, 8, 64);
        sacc[i] = v;
    }
    if (l15 == 0) {
#pragma unroll
        for (int mi = 0; mi < 4; ++mi)
#pragma unroll
            for (int r = 0; r < 4; ++r)
                sred[wv][mi * 16 + lg * 4 + r] = sacc[mi * 4 + r];
    }
    __syncthreads();
    if (tid < 64) {
        float s = bo[0];
#pragma unroll
        for (int w = 0; w < 8; ++w) s += sred[w][tid];
        int qi = tid >> 3, ki = tid & 7;
        out[(size_t)(b * QLEN + qbase + qi) * QLEN + kbase + ki] = s;
    }
}

extern "C" void kernel_launch(void* const* d_in, const int* in_sizes, int n_in,
                              void* d_out, int out_size, void* d_ws, size_t ws_size,
                              hipStream_t stream) {
    const float* Q   = (const float*)d_in[0];
    const float* Kin = (const float*)d_in[1];
    const float* Wq  = (const float*)d_in[2];
    const float* Wk  = (const float*)d_in[3];
    const float* lnw = (const float*)d_in[4];
    const float* lnb = (const float*)d_in[5];
    const float* Wu  = (const float*)d_in[6];
    const float* bu  = (const float*)d_in[7];
    const float* Wv  = (const float*)d_in[8];
    const float* bv  = (const float*)d_in[9];
    const float* Wo  = (const float*)d_in[10];
    const float* bo  = (const float*)d_in[11];
    float* out = (float*)d_out;

    char* ws = (char*)d_ws;
    size_t off = 0;
    auto alloc = [&](size_t bytes) -> void* {
        void* p = ws + off;
        off += (bytes + 255) & ~(size_t)255;
        return p;
    };
    const size_t WB = (size_t)HD * HD * 2;  // 512 KB bf16 weight third
    short* W1u = (short*)alloc(WB); short* W2u = (short*)alloc(WB); short* W3u = (short*)alloc(WB);
    short* W1v = (short*)alloc(WB); short* W2v = (short*)alloc(WB); short* W3v = (short*)alloc(WB);
    short* qbf  = (short*)alloc(WB); short* q2bf = (short*)alloc(WB);
    short* kbf  = (short*)alloc(WB); short* k2bf = (short*)alloc(WB);
    float* su = (float*)alloc(HD * 4); float* tu = (float*)alloc(HD * 4);
    float* sv = (float*)alloc(HD * 4); float* tv = (float*)alloc(HD * 4);
    float* s1q = (float*)alloc(512 * 4); float* s2q = (float*)alloc(512 * 4);
    float* s1k = (float*)alloc(512 * 4); float* s2k = (float*)alloc(512 * 4);
    float* Au  = (float*)alloc((size_t)512 * HD * 4);
    float* Av  = (float*)alloc((size_t)512 * HD * 4);
    float* BuT = (float*)alloc((size_t)512 * HD * 4);
    float* BvT = (float*)alloc((size_t)512 * HD * 4);
    float* muA = (float*)alloc((size_t)2 * QLEN * QLEN * 4);
    float* riA = (float*)alloc((size_t)2 * QLEN * QLEN * 4);

    prep_w<<<HD, 256, 0, stream>>>(Wu, lnw, lnb, bu, W1u, W2u, W3u, su, tu);
    prep_w<<<HD, 256, 0, stream>>>(Wv, lnw, lnb, bv, W1v, W2v, W3v, sv, tv);

    // q/k projections (f32 in, bf16 + bf16^2 out), K=1024
    mm_k<2><<<dim3(8, 8, 1), 256, 0, stream>>>(Q, Wq, nullptr, nullptr, nullptr, qbf, q2bf,
                                               nullptr, nullptr, nullptr, nullptr, nullptr, nullptr, QD);
    mm_k<2><<<dim3(8, 8, 1), 256, 0, stream>>>(Kin, Wk, nullptr, nullptr, nullptr, kbf, k2bf,
                                               nullptr, nullptr, nullptr, nullptr, nullptr, nullptr, QD);

    rowstats<<<512, 256, 0, stream>>>((const unsigned*)qbf, s1q, s2q);
    rowstats<<<512, 256, 0, stream>>>((const unsigned*)kbf, s1k, s2k);

    // fused per-pair mu/ri (dual GEMM: qk dot + q2k2 dot)
    mm_k<3><<<dim3(4, 4, 2), 256, 0, stream>>>(qbf, kbf, q2bf, k2bf, nullptr, nullptr, nullptr,
                                               s1q, s2q, s1k, s2k, muA, riA, HD);

    // LN-linear per-row terms: Au/Av natural, Bu/Bv transposed
    mm_k<0><<<dim3(8, 8, 1), 256, 0, stream>>>(qbf, W1u, nullptr, nullptr, Au, nullptr, nullptr,
                                               nullptr, nullptr, nullptr, nullptr, nullptr, nullptr, HD);
    mm_k<0><<<dim3(8, 8, 1), 256, 0, stream>>>(qbf, W1v, nullptr, nullptr, Av, nullptr, nullptr,
                                               nullptr, nullptr, nullptr, nullptr, nullptr, nullptr, HD);
    mm_k<1><<<dim3(8, 8, 1), 256, 0, stream>>>(kbf, W2u, nullptr, nullptr, BuT, nullptr, nullptr,
                                               nullptr, nullptr, nullptr, nullptr, nullptr, nullptr, HD);
    mm_k<1><<<dim3(8, 8, 1), 256, 0, stream>>>(kbf, W2v, nullptr, nullptr, BvT, nullptr, nullptr,
                                               nullptr, nullptr, nullptr, nullptr, nullptr, nullptr, HD);

    main_pair<<<dim3(QLEN / 8, QLEN / 8, 2), 512, 0, stream>>>(
        qbf, kbf, Au, Av, BuT, BvT, W3u, W3v, su, tu, sv, tv, Wo, bo, muA, riA, out);
}

// Round 5
// 670.399 us; speedup vs baseline: 1.6164x; 1.2792x over previous
//
#include <hip/hip_runtime.h>
#include <hip/hip_bf16.h>

#define QLEN 256
#define QD 1024
#define HD 512
#define H3 1536
#define EPSF 1e-5f

typedef __attribute__((ext_vector_type(8))) short short8;
typedef __attribute__((ext_vector_type(4))) float f32x4;

__device__ inline short f2bf(float f) {
    union { float f; unsigned u; } v; v.f = f;
    unsigned r = v.u + 0x7FFF + ((v.u >> 16) & 1);
    return (short)(r >> 16);
}
__device__ inline float bf2f(short s) {
    union { float f; unsigned u; } v; v.u = ((unsigned)(unsigned short)s) << 16;
    return v.f;
}
__device__ inline unsigned pk2(float a, float b) {
    return ((unsigned)(unsigned short)f2bf(a)) | (((unsigned)(unsigned short)f2bf(b)) << 16);
}
__device__ inline unsigned mulbf2(unsigned a, unsigned b) {
    float a0 = bf2f((short)(a & 0xffff)), a1 = bf2f((short)(a >> 16));
    float b0 = bf2f((short)(b & 0xffff)), b1 = bf2f((short)(b >> 16));
    return pk2(a0 * b0, a1 * b1);
}

// ---------- weight prep (both U and V via blockIdx.y) ------------------------
__global__ __launch_bounds__(256) void prep_w2(const float* __restrict__ Wu_, const float* __restrict__ Wv_,
                                               const float* __restrict__ lnw, const float* __restrict__ lnb,
                                               const float* __restrict__ bu_, const float* __restrict__ bv_,
                                               short* __restrict__ W1u, short* __restrict__ W2u, short* __restrict__ W3u,
                                               short* __restrict__ W1v, short* __restrict__ W2v, short* __restrict__ W3v,
                                               float* __restrict__ su, float* __restrict__ tu,
                                               float* __restrict__ sv, float* __restrict__ tv) {
    int h = blockIdx.x, z = blockIdx.y, tid = threadIdx.x;
    const float* row = (z ? Wv_ : Wu_) + (size_t)h * H3;
    const float* bias = z ? bv_ : bu_;
    short* W1 = z ? W1v : W1u; short* W2 = z ? W2v : W2u; short* W3 = z ? W3v : W3u;
    float* svec = z ? sv : su; float* tvec = z ? tv : tu;
    for (int j = tid; j < HD; j += 256) {
        W1[h * HD + j] = f2bf(lnw[j] * row[j]);
        W2[h * HD + j] = f2bf(lnw[HD + j] * row[HD + j]);
        W3[h * HD + j] = f2bf(lnw[2 * HD + j] * row[2 * HD + j]);
    }
    float s = 0.f, t = 0.f;
    for (int c = tid; c < H3; c += 256) {
        float w = row[c];
        s += lnw[c] * w;
        t += lnb[c] * w;
    }
    for (int m = 1; m < 64; m <<= 1) { s += __shfl_xor(s, m, 64); t += __shfl_xor(t, m, 64); }
    __shared__ float rs[4], rt[4];
    if ((tid & 63) == 0) { rs[tid >> 6] = s; rt[tid >> 6] = t; }
    __syncthreads();
    if (tid == 0) {
        svec[h] = rs[0] + rs[1] + rs[2] + rs[3];
        tvec[h] = rt[0] + rt[1] + rt[2] + rt[3] + bias[h];
    }
}

// ---------- q/k projection, f32 in -> bf16 + bf16^2 out (z-fused) ------------
__global__ __launch_bounds__(256) void proj2(const float* __restrict__ Q_, const float* __restrict__ K_,
                                             const float* __restrict__ Wq_, const float* __restrict__ Wk_,
                                             short* __restrict__ qbf, short* __restrict__ q2bf,
                                             short* __restrict__ kbf, short* __restrict__ k2bf) {
    int z = blockIdx.z;
    const float* In = z ? K_ : Q_;
    const float* W = z ? Wk_ : Wq_;
    short* OutB = z ? kbf : qbf;
    short* OutB2 = z ? k2bf : q2bf;
    __shared__ short a_l[64][72], b_l[64][72];
    int t = threadIdx.x;
    int i0 = blockIdx.y * 64, n0 = blockIdx.x * 64;
    int lane = t & 63, wv = t >> 6, wm = wv >> 1, wn = wv & 1;
    int l15 = lane & 15, lg = lane >> 4;
    f32x4 acc[2][2] = {};
    int sr = t >> 4, sc = (t & 15) * 4;
    for (int kc = 0; kc < QD; kc += 64) {
#pragma unroll
        for (int rep = 0; rep < 4; ++rep) {
            int row = sr + rep * 16;
            float4 av = *(const float4*)&In[(size_t)(i0 + row) * QD + kc + sc];
            float4 bv = *(const float4*)&W[(size_t)(n0 + row) * QD + kc + sc];
            *(uint2*)&a_l[row][sc] = (uint2){pk2(av.x, av.y), pk2(av.z, av.w)};
            *(uint2*)&b_l[row][sc] = (uint2){pk2(bv.x, bv.y), pk2(bv.z, bv.w)};
        }
        __syncthreads();
#pragma unroll
        for (int kk = 0; kk < 2; ++kk) {
            short8 af[2], bf_[2];
#pragma unroll
            for (int mi = 0; mi < 2; ++mi)
                af[mi] = *(const short8*)&a_l[wm * 32 + mi * 16 + l15][kk * 32 + lg * 8];
#pragma unroll
            for (int nj = 0; nj < 2; ++nj)
                bf_[nj] = *(const short8*)&b_l[wn * 32 + nj * 16 + l15][kk * 32 + lg * 8];
#pragma unroll
            for (int mi = 0; mi < 2; ++mi)
#pragma unroll
                for (int nj = 0; nj < 2; ++nj)
                    acc[mi][nj] = __builtin_amdgcn_mfma_f32_16x16x32_bf16(af[mi], bf_[nj], acc[mi][nj], 0, 0, 0);
        }
        __syncthreads();
    }
#pragma unroll
    for (int mi = 0; mi < 2; ++mi)
#pragma unroll
        for (int nj = 0; nj < 2; ++nj)
#pragma unroll
            for (int r = 0; r < 4; ++r) {
                int row = i0 + wm * 32 + mi * 16 + lg * 4 + r;
                int col = n0 + wn * 32 + nj * 16 + l15;
                short qb = f2bf(acc[mi][nj][r]);
                OutB[(size_t)row * HD + col] = qb;
                float q = bf2f(qb);
                OutB2[(size_t)row * HD + col] = f2bf(q * q);
            }
}

// ---------- row sums (z-fused) -----------------------------------------------
__global__ __launch_bounds__(256) void rowstats2(const unsigned* __restrict__ qbf, const unsigned* __restrict__ kbf,
                                                 float* __restrict__ s1q, float* __restrict__ s2q,
                                                 float* __restrict__ s1k, float* __restrict__ s2k) {
    int row = blockIdx.x, z = blockIdx.y, tid = threadIdx.x;
    const unsigned* Xbf = z ? kbf : qbf;
    float* s1 = z ? s1k : s1q;
    float* s2 = z ? s2k : s2q;
    unsigned u = Xbf[row * 256 + tid];
    float a = bf2f((short)(u & 0xffff)), b = bf2f((short)(u >> 16));
    float s = a + b, q = a * a + b * b;
    for (int m = 1; m < 64; m <<= 1) { s += __shfl_xor(s, m, 64); q += __shfl_xor(q, m, 64); }
    __shared__ float rs[4], rq[4];
    if ((tid & 63) == 0) { rs[tid >> 6] = s; rq[tid >> 6] = q; }
    __syncthreads();
    if (tid == 0) {
        s1[row] = rs[0] + rs[1] + rs[2] + rs[3];
        s2[row] = rq[0] + rq[1] + rq[2] + rq[3];
    }
}

// ---------- per-pair mu/ri: dual GEMM (qk, q2k2) + stats ---------------------
__global__ __launch_bounds__(256) void pairstat(const short* __restrict__ qbf, const short* __restrict__ kbf,
                                                const short* __restrict__ q2bf, const short* __restrict__ k2bf,
                                                const float* __restrict__ s1q, const float* __restrict__ s2q,
                                                const float* __restrict__ s1k, const float* __restrict__ s2k,
                                                float* __restrict__ muA, float* __restrict__ riA) {
    __shared__ short a_l[64][72], b_l[64][72], a2_l[64][72], b2_l[64][72];
    int t = threadIdx.x;
    int i0 = blockIdx.y * 64, n0 = blockIdx.x * 64, bz = blockIdx.z;
    int lane = t & 63, wv = t >> 6, wm = wv >> 1, wn = wv & 1;
    int l15 = lane & 15, lg = lane >> 4;
    f32x4 acc[2][2] = {}, acc2[2][2] = {};
    int sr = t >> 4, sc = (t & 15) * 4;
    size_t roff = (size_t)bz * QLEN;
    for (int kc = 0; kc < HD; kc += 64) {
#pragma unroll
        for (int rep = 0; rep < 4; ++rep) {
            int row = sr + rep * 16;
            *(uint2*)&a_l[row][sc] = *(const uint2*)&qbf[(roff + i0 + row) * HD + kc + sc];
            *(uint2*)&b_l[row][sc] = *(const uint2*)&kbf[(roff + n0 + row) * HD + kc + sc];
            *(uint2*)&a2_l[row][sc] = *(const uint2*)&q2bf[(roff + i0 + row) * HD + kc + sc];
            *(uint2*)&b2_l[row][sc] = *(const uint2*)&k2bf[(roff + n0 + row) * HD + kc + sc];
        }
        __syncthreads();
#pragma unroll
        for (int kk = 0; kk < 2; ++kk) {
            short8 af[2], bf_[2], af2[2], bf2_[2];
#pragma unroll
            for (int mi = 0; mi < 2; ++mi) {
                af[mi] = *(const short8*)&a_l[wm * 32 + mi * 16 + l15][kk * 32 + lg * 8];
                af2[mi] = *(const short8*)&a2_l[wm * 32 + mi * 16 + l15][kk * 32 + lg * 8];
            }
#pragma unroll
            for (int nj = 0; nj < 2; ++nj) {
                bf_[nj] = *(const short8*)&b_l[wn * 32 + nj * 16 + l15][kk * 32 + lg * 8];
                bf2_[nj] = *(const short8*)&b2_l[wn * 32 + nj * 16 + l15][kk * 32 + lg * 8];
            }
#pragma unroll
            for (int mi = 0; mi < 2; ++mi)
#pragma unroll
                for (int nj = 0; nj < 2; ++nj) {
                    acc[mi][nj] = __builtin_amdgcn_mfma_f32_16x16x32_bf16(af[mi], bf_[nj], acc[mi][nj], 0, 0, 0);
                    acc2[mi][nj] = __builtin_amdgcn_mfma_f32_16x16x32_bf16(af2[mi], bf2_[nj], acc2[mi][nj], 0, 0, 0);
                }
        }
        __syncthreads();
    }
#pragma unroll
    for (int mi = 0; mi < 2; ++mi)
#pragma unroll
        for (int nj = 0; nj < 2; ++nj)
#pragma unroll
            for (int r = 0; r < 4; ++r) {
                int row = i0 + wm * 32 + mi * 16 + lg * 4 + r;
                int col = n0 + wn * 32 + nj * 16 + l15;
                float mu = (s1q[bz * QLEN + row] + s1k[bz * QLEN + col] + acc[mi][nj][r]) * (1.f / H3);
                float ex2 = (s2q[bz * QLEN + row] + s2k[bz * QLEN + col] + acc2[mi][nj][r]) * (1.f / H3);
                float ri = rsqrtf(ex2 - mu * mu + EPSF);
                size_t ix = ((size_t)bz * QLEN + row) * QLEN + col;
                muA[ix] = mu;
                riA[ix] = ri;
            }
}

// ---------- LN-linear row terms: 4 GEMMs z-fused (Au, Av, BuT, BvT) ----------
__global__ __launch_bounds__(256) void lnlin4(const short* __restrict__ qbf, const short* __restrict__ kbf,
                                              const short* __restrict__ W1u, const short* __restrict__ W1v,
                                              const short* __restrict__ W2u, const short* __restrict__ W2v,
                                              float* __restrict__ Au, float* __restrict__ Av,
                                              float* __restrict__ BuT, float* __restrict__ BvT) {
    int z = blockIdx.z;
    const short* A = (z < 2) ? qbf : kbf;
    const short* W = (z == 0) ? W1u : (z == 1) ? W1v : (z == 2) ? W2u : W2v;
    float* Out = (z == 0) ? Au : (z == 1) ? Av : (z == 2) ? BuT : BvT;
    bool tr = z >= 2;
    __shared__ short a_l[64][72], b_l[64][72];
    int t = threadIdx.x;
    int i0 = blockIdx.y * 64, n0 = blockIdx.x * 64;
    int lane = t & 63, wv = t >> 6, wm = wv >> 1, wn = wv & 1;
    int l15 = lane & 15, lg = lane >> 4;
    f32x4 acc[2][2] = {};
    int sr = t >> 4, sc = (t & 15) * 4;
    for (int kc = 0; kc < HD; kc += 64) {
#pragma unroll
        for (int rep = 0; rep < 4; ++rep) {
            int row = sr + rep * 16;
            *(uint2*)&a_l[row][sc] = *(const uint2*)&A[(size_t)(i0 + row) * HD + kc + sc];
            *(uint2*)&b_l[row][sc] = *(const uint2*)&W[(size_t)(n0 + row) * HD + kc + sc];
        }
        __syncthreads();
#pragma unroll
        for (int kk = 0; kk < 2; ++kk) {
            short8 af[2], bf_[2];
#pragma unroll
            for (int mi = 0; mi < 2; ++mi)
                af[mi] = *(const short8*)&a_l[wm * 32 + mi * 16 + l15][kk * 32 + lg * 8];
#pragma unroll
            for (int nj = 0; nj < 2; ++nj)
                bf_[nj] = *(const short8*)&b_l[wn * 32 + nj * 16 + l15][kk * 32 + lg * 8];
#pragma unroll
            for (int mi = 0; mi < 2; ++mi)
#pragma unroll
                for (int nj = 0; nj < 2; ++nj)
                    acc[mi][nj] = __builtin_amdgcn_mfma_f32_16x16x32_bf16(af[mi], bf_[nj], acc[mi][nj], 0, 0, 0);
        }
        __syncthreads();
    }
#pragma unroll
    for (int mi = 0; mi < 2; ++mi)
#pragma unroll
        for (int nj = 0; nj < 2; ++nj)
#pragma unroll
            for (int r = 0; r < 4; ++r) {
                int row = i0 + wm * 32 + mi * 16 + lg * 4 + r;
                int col = n0 + wn * 32 + nj * 16 + l15;
                if (tr) Out[(size_t)col * HD + row] = acc[mi][nj][r];
                else    Out[(size_t)row * HD + col] = acc[mi][nj][r];
            }
}

// ---------- main fused pair kernel -------------------------------------------
// 8 waves: wm=wv&1 owns 32 of 64 pairs, wh=wv>>1 owns 128 of 512 h.
// Accumulators per wave: 2x2x2 f32x4 = 32 VGPR -> fits the 128-reg budget
// at 2 blocks/CU with zero spill (R3/R4: 64-reg acc spilled 762 MB scratch).
__global__ __launch_bounds__(512) void main_pair(const short* __restrict__ qbf,
                                                 const short* __restrict__ kbf,
                                                 const float* __restrict__ Au,
                                                 const float* __restrict__ Av,
                                                 const float* __restrict__ BuT,
                                                 const float* __restrict__ BvT,
                                                 const short* __restrict__ W3u,
                                                 const short* __restrict__ W3v,
                                                 const float* __restrict__ su,
                                                 const float* __restrict__ tu,
                                                 const float* __restrict__ sv,
                                                 const float* __restrict__ tv,
                                                 const float* __restrict__ Wo,
                                                 const float* __restrict__ bo,
                                                 const float* __restrict__ muA,
                                                 const float* __restrict__ riA,
                                                 float* __restrict__ out) {
    __shared__ short p_lds[64 * 512];   // 64 KB, XOR-swizzled rows
    __shared__ float sred[8][32];

    int tid = threadIdx.x;
    int b = blockIdx.z, qt = blockIdx.y, kt = blockIdx.x;
    int qbase = qt * 8, kbase = kt * 8;

    // p = q .* k  (bf16, swizzled rows: pair-major [64][512])
    for (int i = tid; i < 4096; i += 512) {
        int row = i >> 6, j0 = (i & 63) << 3;
        int qi = row >> 3, ki = row & 7;
        uint4 qv = *(const uint4*)&qbf[(size_t)(b * QLEN + qbase + qi) * HD + j0];
        uint4 kv = *(const uint4*)&kbf[(size_t)(b * QLEN + kbase + ki) * HD + j0];
        uint4 pv;
        pv.x = mulbf2(qv.x, kv.x); pv.y = mulbf2(qv.y, kv.y);
        pv.z = mulbf2(qv.z, kv.z); pv.w = mulbf2(qv.w, kv.w);
        unsigned off = row * 1024 + ((j0 * 2) ^ ((row & 7) << 4));
        *(uint4*)((char*)p_lds + off) = pv;
    }
    __syncthreads();

    int lane = tid & 63, wv = tid >> 6;
    int wm = wv & 1, wh = wv >> 1;
    int l15 = lane & 15, lg = lane >> 4;
    int qi_l = lg >> 1, ki0 = (lg & 1) * 4;

    float sacc[8];
#pragma unroll
    for (int i = 0; i < 8; ++i) sacc[i] = 0.f;

    for (int oc = 0; oc < 4; ++oc) {
        int hb = wh * 128 + oc * 32;
        f32x4 aU[2][2], aV[2][2];
#pragma unroll
        for (int mi = 0; mi < 2; ++mi) {
            int qrow = b * QLEN + qbase + wm * 4 + mi * 2 + qi_l;
            int krow4 = b * QLEN + kbase + ki0;
#pragma unroll
            for (int nj = 0; nj < 2; ++nj) {
                int h = hb + nj * 16 + l15;
                float au = Au[(size_t)qrow * HD + h];
                float av = Av[(size_t)qrow * HD + h];
                f32x4 bu4 = *(const f32x4*)&BuT[(size_t)h * 512 + krow4];
                f32x4 bv4 = *(const f32x4*)&BvT[(size_t)h * 512 + krow4];
#pragma unroll
                for (int r = 0; r < 4; ++r) {
                    aU[mi][nj][r] = au + bu4[r];
                    aV[mi][nj][r] = av + bv4[r];
                }
            }
        }
#pragma unroll 4
        for (int kk = 0; kk < 512; kk += 32) {
            short8 a_f[2], bu_f[2], bv_f[2];
#pragma unroll
            for (int nj = 0; nj < 2; ++nj) {
                int h = hb + nj * 16 + l15;
                bu_f[nj] = *(const short8*)&W3u[(size_t)h * HD + kk + lg * 8];
                bv_f[nj] = *(const short8*)&W3v[(size_t)h * HD + kk + lg * 8];
            }
#pragma unroll
            for (int mi = 0; mi < 2; ++mi) {
                int row = wm * 32 + mi * 16 + l15;
                unsigned off = row * 1024 + (((kk + lg * 8) * 2) ^ ((row & 7) << 4));
                a_f[mi] = *(const short8*)((const char*)p_lds + off);
            }
#pragma unroll
            for (int mi = 0; mi < 2; ++mi)
#pragma unroll
                for (int nj = 0; nj < 2; ++nj) {
                    aU[mi][nj] = __builtin_amdgcn_mfma_f32_16x16x32_bf16(a_f[mi], bu_f[nj], aU[mi][nj], 0, 0, 0);
                    aV[mi][nj] = __builtin_amdgcn_mfma_f32_16x16x32_bf16(a_f[mi], bv_f[nj], aV[mi][nj], 0, 0, 0);
                }
        }
        // fused epilogue: LN-linear + gelu(tanh) + Wo reduction
#pragma unroll
        for (int nj = 0; nj < 2; ++nj) {
            int h = hb + nj * 16 + l15;
            float suh = su[h], tuh = tu[h], svh = sv[h], tvh = tv[h], woh = Wo[h];
#pragma unroll
            for (int mi = 0; mi < 2; ++mi) {
                size_t pbase = (size_t)(b * QLEN + qbase + wm * 4 + mi * 2 + qi_l) * QLEN + kbase + ki0;
#pragma unroll
                for (int r = 0; r < 4; ++r) {
                    float ri = riA[pbase + r];
                    float rmu = ri * muA[pbase + r];
                    float u = fmaf(ri, aU[mi][nj][r], tuh) - rmu * suh;
                    float vx = fmaf(ri, aV[mi][nj][r], tvh) - rmu * svh;
                    float x2 = vx * vx;
                    float tt = vx * fmaf(0.0356774081f, x2, 0.7978845608f);
                    float e2 = exp2f(tt * 2.885390082f);
                    float ge = vx - vx / (e2 + 1.0f);   // v*sigmoid(2t), inf-safe
                    sacc[mi * 4 + r] = fmaf(u * ge, woh, sacc[mi * 4 + r]);
                }
            }
        }
    }

    // reduce over the 16 h-lanes, then across the 4 h-waves via LDS
#pragma unroll
    for (int i = 0; i < 8; ++i) {
        float v = sacc[i];
        v += __shfl_xor(v, 1, 64);
        v += __shfl_xor(v, 2, 64);
        v += __shfl_xor(v, 4, 64);
        v += __shfl_xor(v, 8, 64);
        sacc[i] = v;
    }
    if (l15 == 0) {
#pragma unroll
        for (int mi = 0; mi < 2; ++mi)
#pragma unroll
            for (int r = 0; r < 4; ++r)
                sred[wv][mi * 16 + lg * 4 + r] = sacc[mi * 4 + r];
    }
    __syncthreads();
    if (tid < 64) {
        int pr = tid, wmO = pr >> 5, loc = pr & 31;
        float s = bo[0];
#pragma unroll
        for (int whO = 0; whO < 4; ++whO) s += sred[whO * 2 + wmO][loc];
        int qi = pr >> 3, ki = pr & 7;
        out[(size_t)(b * QLEN + qbase + qi) * QLEN + kbase + ki] = s;
    }
}

extern "C" void kernel_launch(void* const* d_in, const int* in_sizes, int n_in,
                              void* d_out, int out_size, void* d_ws, size_t ws_size,
                              hipStream_t stream) {
    const float* Q   = (const float*)d_in[0];
    const float* Kin = (const float*)d_in[1];
    const float* Wq  = (const float*)d_in[2];
    const float* Wk  = (const float*)d_in[3];
    const float* lnw = (const float*)d_in[4];
    const float* lnb = (const float*)d_in[5];
    const float* Wu  = (const float*)d_in[6];
    const float* bu  = (const float*)d_in[7];
    const float* Wv  = (const float*)d_in[8];
    const float* bv  = (const float*)d_in[9];
    const float* Wo  = (const float*)d_in[10];
    const float* bo  = (const float*)d_in[11];
    float* out = (float*)d_out;

    char* ws = (char*)d_ws;
    size_t off = 0;
    auto alloc = [&](size_t bytes) -> void* {
        void* p = ws + off;
        off += (bytes + 255) & ~(size_t)255;
        return p;
    };
    const size_t WB = (size_t)HD * HD * 2;  // 512 KB bf16 matrix
    short* W1u = (short*)alloc(WB); short* W2u = (short*)alloc(WB); short* W3u = (short*)alloc(WB);
    short* W1v = (short*)alloc(WB); short* W2v = (short*)alloc(WB); short* W3v = (short*)alloc(WB);
    short* qbf  = (short*)alloc(WB); short* q2bf = (short*)alloc(WB);
    short* kbf  = (short*)alloc(WB); short* k2bf = (short*)alloc(WB);
    float* su = (float*)alloc(HD * 4); float* tu = (float*)alloc(HD * 4);
    float* sv = (float*)alloc(HD * 4); float* tv = (float*)alloc(HD * 4);
    float* s1q = (float*)alloc(512 * 4); float* s2q = (float*)alloc(512 * 4);
    float* s1k = (float*)alloc(512 * 4); float* s2k = (float*)alloc(512 * 4);
    float* Au  = (float*)alloc((size_t)512 * HD * 4);
    float* Av  = (float*)alloc((size_t)512 * HD * 4);
    float* BuT = (float*)alloc((size_t)512 * HD * 4);
    float* BvT = (float*)alloc((size_t)512 * HD * 4);
    float* muA = (float*)alloc((size_t)2 * QLEN * QLEN * 4);
    float* riA = (float*)alloc((size_t)2 * QLEN * QLEN * 4);

    prep_w2<<<dim3(HD, 2), 256, 0, stream>>>(Wu, Wv, lnw, lnb, bu, bv,
                                             W1u, W2u, W3u, W1v, W2v, W3v, su, tu, sv, tv);

    proj2<<<dim3(8, 8, 2), 256, 0, stream>>>(Q, Kin, Wq, Wk, qbf, q2bf, kbf, k2bf);

    rowstats2<<<dim3(512, 2), 256, 0, stream>>>((const unsigned*)qbf, (const unsigned*)kbf,
                                                s1q, s2q, s1k, s2k);

    pairstat<<<dim3(4, 4, 2), 256, 0, stream>>>(qbf, kbf, q2bf, k2bf,
                                                s1q, s2q, s1k, s2k, muA, riA);

    lnlin4<<<dim3(8, 8, 4), 256, 0, stream>>>(qbf, kbf, W1u, W1v, W2u, W2v, Au, Av, BuT, BvT);

    main_pair<<<dim3(QLEN / 8, QLEN / 8, 2), 512, 0, stream>>>(
        qbf, kbf, Au, Av, BuT, BvT, W3u, W3v, su, tu, sv, tv, Wo, bo, muA, riA, out);
}

// Round 6
// 508.898 us; speedup vs baseline: 2.1293x; 1.3174x over previous
//
#include <hip/hip_runtime.h>
#include <hip/hip_bf16.h>

#define QLEN 256
#define QD 1024
#define HD 512
#define H3 1536
#define EPSF 1e-5f

typedef __attribute__((ext_vector_type(8))) short short8;
typedef __attribute__((ext_vector_type(4))) float f32x4;

__device__ inline short f2bf(float f) {
    union { float f; unsigned u; } v; v.f = f;
    unsigned r = v.u + 0x7FFF + ((v.u >> 16) & 1);
    return (short)(r >> 16);
}
__device__ inline float bf2f(short s) {
    union { float f; unsigned u; } v; v.u = ((unsigned)(unsigned short)s) << 16;
    return v.f;
}
__device__ inline unsigned pk2(float a, float b) {
    return ((unsigned)(unsigned short)f2bf(a)) | (((unsigned)(unsigned short)f2bf(b)) << 16);
}
__device__ inline float asf(unsigned u) { union { unsigned u; float f; } v; v.u = u; return v.f; }
// packed bf16 convert (RNE), 1 instruction: D[15:0]=S0, D[31:16]=S1
__device__ inline unsigned cvtpk(float lo, float hi) {
    unsigned r;
    asm("v_cvt_pk_bf16_f32 %0, %1, %2" : "=v"(r) : "v"(lo), "v"(hi));
    return r;
}

// ---------- weight prep (both U and V via blockIdx.y) ------------------------
__global__ __launch_bounds__(256) void prep_w2(const float* __restrict__ Wu_, const float* __restrict__ Wv_,
                                               const float* __restrict__ lnw, const float* __restrict__ lnb,
                                               const float* __restrict__ bu_, const float* __restrict__ bv_,
                                               short* __restrict__ W1u, short* __restrict__ W2u, short* __restrict__ W3u,
                                               short* __restrict__ W1v, short* __restrict__ W2v, short* __restrict__ W3v,
                                               float* __restrict__ su, float* __restrict__ tu,
                                               float* __restrict__ sv, float* __restrict__ tv) {
    int h = blockIdx.x, z = blockIdx.y, tid = threadIdx.x;
    const float* row = (z ? Wv_ : Wu_) + (size_t)h * H3;
    const float* bias = z ? bv_ : bu_;
    short* W1 = z ? W1v : W1u; short* W2 = z ? W2v : W2u; short* W3 = z ? W3v : W3u;
    float* svec = z ? sv : su; float* tvec = z ? tv : tu;
    for (int j = tid; j < HD; j += 256) {
        W1[h * HD + j] = f2bf(lnw[j] * row[j]);
        W2[h * HD + j] = f2bf(lnw[HD + j] * row[HD + j]);
        W3[h * HD + j] = f2bf(lnw[2 * HD + j] * row[2 * HD + j]);
    }
    float s = 0.f, t = 0.f;
    for (int c = tid; c < H3; c += 256) {
        float w = row[c];
        s += lnw[c] * w;
        t += lnb[c] * w;
    }
    for (int m = 1; m < 64; m <<= 1) { s += __shfl_xor(s, m, 64); t += __shfl_xor(t, m, 64); }
    __shared__ float rs[4], rt[4];
    if ((tid & 63) == 0) { rs[tid >> 6] = s; rt[tid >> 6] = t; }
    __syncthreads();
    if (tid == 0) {
        svec[h] = rs[0] + rs[1] + rs[2] + rs[3];
        tvec[h] = rt[0] + rt[1] + rt[2] + rt[3] + bias[h];
    }
}

// ---------- q/k projection, f32 in -> bf16 out (z-fused) ---------------------
__global__ __launch_bounds__(256) void proj2(const float* __restrict__ Q_, const float* __restrict__ K_,
                                             const float* __restrict__ Wq_, const float* __restrict__ Wk_,
                                             short* __restrict__ qbf, short* __restrict__ kbf) {
    int z = blockIdx.z;
    const float* In = z ? K_ : Q_;
    const float* W = z ? Wk_ : Wq_;
    short* OutB = z ? kbf : qbf;
    __shared__ short a_l[64][72], b_l[64][72];
    int t = threadIdx.x;
    int i0 = blockIdx.y * 64, n0 = blockIdx.x * 64;
    int lane = t & 63, wv = t >> 6, wm = wv >> 1, wn = wv & 1;
    int l15 = lane & 15, lg = lane >> 4;
    f32x4 acc[2][2] = {};
    int sr = t >> 4, sc = (t & 15) * 4;
    for (int kc = 0; kc < QD; kc += 64) {
#pragma unroll
        for (int rep = 0; rep < 4; ++rep) {
            int row = sr + rep * 16;
            float4 av = *(const float4*)&In[(size_t)(i0 + row) * QD + kc + sc];
            float4 bv = *(const float4*)&W[(size_t)(n0 + row) * QD + kc + sc];
            *(uint2*)&a_l[row][sc] = (uint2){pk2(av.x, av.y), pk2(av.z, av.w)};
            *(uint2*)&b_l[row][sc] = (uint2){pk2(bv.x, bv.y), pk2(bv.z, bv.w)};
        }
        __syncthreads();
#pragma unroll
        for (int kk = 0; kk < 2; ++kk) {
            short8 af[2], bf_[2];
#pragma unroll
            for (int mi = 0; mi < 2; ++mi)
                af[mi] = *(const short8*)&a_l[wm * 32 + mi * 16 + l15][kk * 32 + lg * 8];
#pragma unroll
            for (int nj = 0; nj < 2; ++nj)
                bf_[nj] = *(const short8*)&b_l[wn * 32 + nj * 16 + l15][kk * 32 + lg * 8];
#pragma unroll
            for (int mi = 0; mi < 2; ++mi)
#pragma unroll
                for (int nj = 0; nj < 2; ++nj)
                    acc[mi][nj] = __builtin_amdgcn_mfma_f32_16x16x32_bf16(af[mi], bf_[nj], acc[mi][nj], 0, 0, 0);
        }
        __syncthreads();
    }
#pragma unroll
    for (int mi = 0; mi < 2; ++mi)
#pragma unroll
        for (int nj = 0; nj < 2; ++nj)
#pragma unroll
            for (int r = 0; r < 4; ++r) {
                int row = i0 + wm * 32 + mi * 16 + lg * 4 + r;
                int col = n0 + wn * 32 + nj * 16 + l15;
                OutB[(size_t)row * HD + col] = f2bf(acc[mi][nj][r]);
            }
}

// ---------- row sums (z-fused) + out init to bo ------------------------------
__global__ __launch_bounds__(256) void rowstats2(const unsigned* __restrict__ qbf, const unsigned* __restrict__ kbf,
                                                 float* __restrict__ s1q, float* __restrict__ s2q,
                                                 float* __restrict__ s1k, float* __restrict__ s2k,
                                                 float* __restrict__ out, const float* __restrict__ bo) {
    int row = blockIdx.x, z = blockIdx.y, tid = threadIdx.x;
    // init out = bo[0] (re-poisoned to 0xAA before every launch; atomics need it)
    int gid = (z * 512 + row) * 256 + tid;
    if (gid < 2 * QLEN * QLEN) out[gid] = bo[0];
    const unsigned* Xbf = z ? kbf : qbf;
    float* s1 = z ? s1k : s1q;
    float* s2 = z ? s2k : s2q;
    unsigned u = Xbf[row * 256 + tid];
    float a = bf2f((short)(u & 0xffff)), b = bf2f((short)(u >> 16));
    float s = a + b, q = a * a + b * b;
    for (int m = 1; m < 64; m <<= 1) { s += __shfl_xor(s, m, 64); q += __shfl_xor(q, m, 64); }
    __shared__ float rs[4], rq[4];
    if ((tid & 63) == 0) { rs[tid >> 6] = s; rq[tid >> 6] = q; }
    __syncthreads();
    if (tid == 0) {
        s1[row] = rs[0] + rs[1] + rs[2] + rs[3];
        s2[row] = rq[0] + rq[1] + rq[2] + rq[3];
    }
}

// ---------- LN-linear row terms: 4 GEMMs z-fused (Au, Av, BuT, BvT) ----------
__global__ __launch_bounds__(256) void lnlin4(const short* __restrict__ qbf, const short* __restrict__ kbf,
                                              const short* __restrict__ W1u, const short* __restrict__ W1v,
                                              const short* __restrict__ W2u, const short* __restrict__ W2v,
                                              float* __restrict__ Au, float* __restrict__ Av,
                                              float* __restrict__ BuT, float* __restrict__ BvT) {
    int z = blockIdx.z;
    const short* A = (z < 2) ? qbf : kbf;
    const short* W = (z == 0) ? W1u : (z == 1) ? W1v : (z == 2) ? W2u : W2v;
    float* Out = (z == 0) ? Au : (z == 1) ? Av : (z == 2) ? BuT : BvT;
    bool tr = z >= 2;
    __shared__ short a_l[64][72], b_l[64][72];
    int t = threadIdx.x;
    int i0 = blockIdx.y * 64, n0 = blockIdx.x * 64;
    int lane = t & 63, wv = t >> 6, wm = wv >> 1, wn = wv & 1;
    int l15 = lane & 15, lg = lane >> 4;
    f32x4 acc[2][2] = {};
    int sr = t >> 4, sc = (t & 15) * 4;
    for (int kc = 0; kc < HD; kc += 64) {
#pragma unroll
        for (int rep = 0; rep < 4; ++rep) {
            int row = sr + rep * 16;
            *(uint2*)&a_l[row][sc] = *(const uint2*)&A[(size_t)(i0 + row) * HD + kc + sc];
            *(uint2*)&b_l[row][sc] = *(const uint2*)&W[(size_t)(n0 + row) * HD + kc + sc];
        }
        __syncthreads();
#pragma unroll
        for (int kk = 0; kk < 2; ++kk) {
            short8 af[2], bf_[2];
#pragma unroll
            for (int mi = 0; mi < 2; ++mi)
                af[mi] = *(const short8*)&a_l[wm * 32 + mi * 16 + l15][kk * 32 + lg * 8];
#pragma unroll
            for (int nj = 0; nj < 2; ++nj)
                bf_[nj] = *(const short8*)&b_l[wn * 32 + nj * 16 + l15][kk * 32 + lg * 8];
#pragma unroll
            for (int mi = 0; mi < 2; ++mi)
#pragma unroll
                for (int nj = 0; nj < 2; ++nj)
                    acc[mi][nj] = __builtin_amdgcn_mfma_f32_16x16x32_bf16(af[mi], bf_[nj], acc[mi][nj], 0, 0, 0);
        }
        __syncthreads();
    }
#pragma unroll
    for (int mi = 0; mi < 2; ++mi)
#pragma unroll
        for (int nj = 0; nj < 2; ++nj)
#pragma unroll
            for (int r = 0; r < 4; ++r) {
                int row = i0 + wm * 32 + mi * 16 + lg * 4 + r;
                int col = n0 + wn * 32 + nj * 16 + l15;
                if (tr) Out[(size_t)col * HD + row] = acc[mi][nj][r];
                else    Out[(size_t)row * HD + col] = acc[mi][nj][r];
            }
}

// ---------- main: 256 pairs (16q x 16k) x 64-h slice per block ---------------
// q,k tiles LDS-resident (XOR-swizzled); A-frags (p=q*k) built in registers
// (q is wave-uniform per m-frag -> broadcast; cvt_pk_bf16_f32 pack).
// W3 slice reg-staged into LDS per K-chunk (BK=128), double-buffered,
// reused by all 256 pairs -> W3 L2 traffic 4 GB -> 512 MB vs R5.
// mu/ri computed in-block via 4 stats-MFMAs + LDS atomics.
// LDS ~100 KB -> 1 block/CU -> VGPR cap 256, no spill (acc=64).
__global__ __launch_bounds__(512) void main2(const short* __restrict__ qbf,
                                             const short* __restrict__ kbf,
                                             const float* __restrict__ Au,
                                             const float* __restrict__ Av,
                                             const float* __restrict__ BuT,
                                             const float* __restrict__ BvT,
                                             const short* __restrict__ W3u,
                                             const short* __restrict__ W3v,
                                             const float* __restrict__ su,
                                             const float* __restrict__ tu,
                                             const float* __restrict__ sv,
                                             const float* __restrict__ tv,
                                             const float* __restrict__ Wo,
                                             const float* __restrict__ s1q,
                                             const float* __restrict__ s2q,
                                             const float* __restrict__ s1k,
                                             const float* __restrict__ s2k,
                                             float* __restrict__ out) {
    __shared__ short q_l[16 * 512];          // 16 KB, swizzled rows (1024 B)
    __shared__ short k_l[16 * 512];          // 16 KB
    __shared__ short B_l[2][2][64 * 128];    // 64 KB: [buf][uv][h][128], swizzled 256 B rows
    __shared__ float stat_l[512];            // d1[256], d2[256] -> ri[256], ri*mu[256]
    __shared__ float sred[8][64];

    int tid = threadIdx.x;
    int kt = blockIdx.x, qt = blockIdx.y;
    int b = blockIdx.z >> 3, hs = blockIdx.z & 7;
    int qbase = qt * 16, kbase = kt * 16, hbase = hs * 64;
    int lane = tid & 63, wv = tid >> 6;
    int l15 = lane & 15, lg = lane >> 4;
    int wm = wv & 3, wn = wv >> 2;

    // ---- acc init = Au + Bu (C-in of MFMA) ----
    f32x4 accU[4][2], accV[4][2];
#pragma unroll
    for (int mf = 0; mf < 4; ++mf) {
        int qrow = b * QLEN + qbase + wm * 4 + mf;
#pragma unroll
        for (int nf = 0; nf < 2; ++nf) {
            int h = hbase + wn * 32 + nf * 16 + l15;
            float au = Au[(size_t)qrow * HD + h];
            float av = Av[(size_t)qrow * HD + h];
            f32x4 bu4 = *(const f32x4*)&BuT[(size_t)h * 512 + b * QLEN + kbase + lg * 4];
            f32x4 bv4 = *(const f32x4*)&BvT[(size_t)h * 512 + b * QLEN + kbase + lg * 4];
#pragma unroll
            for (int r = 0; r < 4; ++r) {
                accU[mf][nf][r] = au + bu4[r];
                accV[mf][nf][r] = av + bv4[r];
            }
        }
    }

    // ---- stage q,k tiles (swizzled) + zero stats ----
    stat_l[tid] = 0.f;
    for (int i = tid; i < 2048; i += 512) {
        int tile = i >> 10, slot = i & 1023;
        int row = slot >> 6, col16 = slot & 63;
        const short* sp = (tile ? kbf : qbf) +
            (size_t)(b * QLEN + (tile ? kbase : qbase) + row) * HD + col16 * 8;
        uint4 v = *(const uint4*)sp;
        short* dl = tile ? k_l : q_l;
        unsigned off = row * 1024 + ((col16 * 16) ^ ((row & 7) << 4));
        *(uint4*)((char*)dl + off) = v;
    }

    // ---- B chunk staging helpers ----
    uint4 rb[4];
    auto loadB = [&](int kc) {
#pragma unroll
        for (int s = 0; s < 4; ++s) {
            int slot = s * 512 + tid;
            int uvx = slot >> 10, in = slot & 1023;
            int r = in >> 4, c16 = in & 15;
            const short* src = (uvx ? W3v : W3u) + (size_t)(hbase + r) * HD + kc + c16 * 8;
            rb[s] = *(const uint4*)src;
        }
    };
    auto storeB = [&](int buf) {
#pragma unroll
        for (int s = 0; s < 4; ++s) {
            int slot = s * 512 + tid;
            int uvx = slot >> 10, in = slot & 1023;
            int r = in >> 4, c16 = in & 15;
            unsigned off = r * 256 + ((c16 * 16) ^ ((r & 7) << 4));
            *(uint4*)((char*)&B_l[buf][uvx][0] + off) = rb[s];
        }
    };

    loadB(0);  // prologue

    // ---- K loop: 4 chunks of BK=128, single barrier per chunk ----
    for (int c = 0; c < 4; ++c) {
        storeB(c & 1);                 // waits vmcnt on rb automatically
        if (c < 3) loadB((c + 1) * 128);
        __syncthreads();               // buf[c&1] + (c==0: q/k tiles, zeros) visible

        if (c == 0) {
            // ---- pair stats: d1 = q.k, d2 = q^2.k^2 ; wave handles 2 K-slices
            f32x4 d1 = {0.f, 0.f, 0.f, 0.f}, d2 = {0.f, 0.f, 0.f, 0.f};
#pragma unroll
            for (int s = 0; s < 2; ++s) {
                int jb = (wv * 2 + s) * 64 + lg * 16;   // byte col
                uint4 qfu = *(const uint4*)((const char*)q_l + l15 * 1024 + (jb ^ ((l15 & 7) << 4)));
                uint4 kfu = *(const uint4*)((const char*)k_l + l15 * 1024 + (jb ^ ((l15 & 7) << 4)));
                d1 = __builtin_amdgcn_mfma_f32_16x16x32_bf16(
                    *(short8*)&qfu, *(short8*)&kfu, d1, 0, 0, 0);
                uint4 q2u, k2u;
                unsigned* qp = (unsigned*)&qfu; unsigned* kp = (unsigned*)&kfu;
                unsigned* q2p = (unsigned*)&q2u; unsigned* k2p = (unsigned*)&k2u;
#pragma unroll
                for (int i = 0; i < 4; ++i) {
                    float ql = asf(qp[i] << 16), qh = asf(qp[i] & 0xFFFF0000u);
                    float kl = asf(kp[i] << 16), kh = asf(kp[i] & 0xFFFF0000u);
                    q2p[i] = cvtpk(ql * ql, qh * qh);
                    k2p[i] = cvtpk(kl * kl, kh * kh);
                }
                d2 = __builtin_amdgcn_mfma_f32_16x16x32_bf16(
                    *(short8*)&q2u, *(short8*)&k2u, d2, 0, 0, 0);
            }
#pragma unroll
            for (int r = 0; r < 4; ++r) {
                int p = (lg * 4 + r) * 16 + l15;
                atomicAdd(&stat_l[p], d1[r]);
                atomicAdd(&stat_l[256 + p], d2[r]);
            }
        }

        int kc2 = c * 256;   // byte col base in q/k rows
        const char* blu = (const char*)&B_l[c & 1][0][0];
        const char* blv = (const char*)&B_l[c & 1][1][0];
#pragma unroll
        for (int ks = 0; ks < 4; ++ks) {
            int jb = kc2 + ks * 64 + lg * 16;         // q/k byte col
            int bb = ks * 64 + lg * 16;               // B byte col
            uint4 kfu = *(const uint4*)((const char*)k_l + l15 * 1024 + (jb ^ ((l15 & 7) << 4)));
            unsigned* kp = (unsigned*)&kfu;
            float klo[4], khi[4];
#pragma unroll
            for (int i = 0; i < 4; ++i) {
                klo[i] = asf(kp[i] << 16);
                khi[i] = asf(kp[i] & 0xFFFF0000u);
            }
            short8 bu_f[2], bv_f[2];
#pragma unroll
            for (int nf = 0; nf < 2; ++nf) {
                int row = wn * 32 + nf * 16 + l15;
                unsigned off = row * 256 + (bb ^ ((row & 7) << 4));
                bu_f[nf] = *(const short8*)(blu + off);
                bv_f[nf] = *(const short8*)(blv + off);
            }
            short8 af[4];
#pragma unroll
            for (int mf = 0; mf < 4; ++mf) {
                int qrow = wm * 4 + mf;
                uint4 qfu = *(const uint4*)((const char*)q_l + qrow * 1024 + (jb ^ ((qrow & 7) << 4)));
                unsigned* qp = (unsigned*)&qfu;
                uint4 afu;
                unsigned* ap = (unsigned*)&afu;
#pragma unroll
                for (int i = 0; i < 4; ++i) {
                    float ql = asf(qp[i] << 16), qh = asf(qp[i] & 0xFFFF0000u);
                    ap[i] = cvtpk(ql * klo[i], qh * khi[i]);
                }
                af[mf] = *(short8*)&afu;
            }
#pragma unroll
            for (int mf = 0; mf < 4; ++mf)
#pragma unroll
                for (int nf = 0; nf < 2; ++nf) {
                    accU[mf][nf] = __builtin_amdgcn_mfma_f32_16x16x32_bf16(af[mf], bu_f[nf], accU[mf][nf], 0, 0, 0);
                    accV[mf][nf] = __builtin_amdgcn_mfma_f32_16x16x32_bf16(af[mf], bv_f[nf], accV[mf][nf], 0, 0, 0);
                }
        }
    }

    // ---- mu/ri conversion (stats complete since chunk-1 barrier) ----
    if (tid < 256) {
        int qi = tid >> 4, ki = tid & 15;
        float mu = (s1q[b * QLEN + qbase + qi] + s1k[b * QLEN + kbase + ki] + stat_l[tid]) * (1.f / H3);
        float ex2 = (s2q[b * QLEN + qbase + qi] + s2k[b * QLEN + kbase + ki] + stat_l[256 + tid]) * (1.f / H3);
        float ri = rsqrtf(ex2 - mu * mu + EPSF);
        stat_l[tid] = ri;
        stat_l[256 + tid] = ri * mu;
    }
    __syncthreads();

    // ---- fused epilogue: LN-linear + gelu + Wo, h-reduce ----
    float sacc[16];
#pragma unroll
    for (int i = 0; i < 16; ++i) sacc[i] = 0.f;
#pragma unroll
    for (int nf = 0; nf < 2; ++nf) {
        int h = hbase + wn * 32 + nf * 16 + l15;
        float suh = su[h], tuh = tu[h], svh = sv[h], tvh = tv[h], woh = Wo[h];
#pragma unroll
        for (int mf = 0; mf < 4; ++mf) {
            int pbase = (wm * 4 + mf) * 16 + lg * 4;
#pragma unroll
            for (int r = 0; r < 4; ++r) {
                float ri = stat_l[pbase + r];          // broadcast LDS reads
                float rmu = stat_l[256 + pbase + r];
                float u = fmaf(ri, accU[mf][nf][r], tuh) - rmu * suh;
                float vx = fmaf(ri, accV[mf][nf][r], tvh) - rmu * svh;
                float x2 = vx * vx;
                float tt = vx * fmaf(0.0356774081f, x2, 0.7978845608f);
                float e2 = exp2f(tt * 2.885390082f);
                float ge = vx - vx / (e2 + 1.0f);      // v*sigmoid(2t), inf-safe
                sacc[mf * 4 + r] = fmaf(u * ge, woh, sacc[mf * 4 + r]);
            }
        }
    }

    // reduce over the 16 h-lanes (l15)
#pragma unroll
    for (int i = 0; i < 16; ++i) {
        float v = sacc[i];
        v += __shfl_xor(v, 1, 64);
        v += __shfl_xor(v, 2, 64);
        v += __shfl_xor(v, 4, 64);
        v += __shfl_xor(v, 8, 64);
        sacc[i] = v;
    }
    if (l15 == 0) {
#pragma unroll
        for (int mf = 0; mf < 4; ++mf)
#pragma unroll
            for (int r = 0; r < 4; ++r)
                sred[wv][mf * 16 + lg * 4 + r] = sacc[mf * 4 + r];
    }
    __syncthreads();
    if (tid < 256) {
        int wm_ = tid >> 6, within = tid & 63;
        float val = sred[wm_][within] + sred[wm_ + 4][within];
        int qi = wm_ * 4 + (within >> 4), ki = within & 15;
        atomicAdd(&out[(size_t)(b * QLEN + qbase + qi) * QLEN + kbase + ki], val);
    }
}

extern "C" void kernel_launch(void* const* d_in, const int* in_sizes, int n_in,
                              void* d_out, int out_size, void* d_ws, size_t ws_size,
                              hipStream_t stream) {
    const float* Q   = (const float*)d_in[0];
    const float* Kin = (const float*)d_in[1];
    const float* Wq  = (const float*)d_in[2];
    const float* Wk  = (const float*)d_in[3];
    const float* lnw = (const float*)d_in[4];
    const float* lnb = (const float*)d_in[5];
    const float* Wu  = (const float*)d_in[6];
    const float* bu  = (const float*)d_in[7];
    const float* Wv  = (const float*)d_in[8];
    const float* bv  = (const float*)d_in[9];
    const float* Wo  = (const float*)d_in[10];
    const float* bo  = (const float*)d_in[11];
    float* out = (float*)d_out;

    char* ws = (char*)d_ws;
    size_t off = 0;
    auto alloc = [&](size_t bytes) -> void* {
        void* p = ws + off;
        off += (bytes + 255) & ~(size_t)255;
        return p;
    };
    const size_t WB = (size_t)HD * HD * 2;  // 512 KB bf16 matrix
    short* W1u = (short*)alloc(WB); short* W2u = (short*)alloc(WB); short* W3u = (short*)alloc(WB);
    short* W1v = (short*)alloc(WB); short* W2v = (short*)alloc(WB); short* W3v = (short*)alloc(WB);
    short* qbf = (short*)alloc(WB); short* kbf = (short*)alloc(WB);
    float* su = (float*)alloc(HD * 4); float* tu = (float*)alloc(HD * 4);
    float* sv = (float*)alloc(HD * 4); float* tv = (float*)alloc(HD * 4);
    float* s1q = (float*)alloc(512 * 4); float* s2q = (float*)alloc(512 * 4);
    float* s1k = (float*)alloc(512 * 4); float* s2k = (float*)alloc(512 * 4);
    float* Au  = (float*)alloc((size_t)512 * HD * 4);
    float* Av  = (float*)alloc((size_t)512 * HD * 4);
    float* BuT = (float*)alloc((size_t)512 * HD * 4);
    float* BvT = (float*)alloc((size_t)512 * HD * 4);

    prep_w2<<<dim3(HD, 2), 256, 0, stream>>>(Wu, Wv, lnw, lnb, bu, bv,
                                             W1u, W2u, W3u, W1v, W2v, W3v, su, tu, sv, tv);

    proj2<<<dim3(8, 8, 2), 256, 0, stream>>>(Q, Kin, Wq, Wk, qbf, kbf);

    rowstats2<<<dim3(512, 2), 256, 0, stream>>>((const unsigned*)qbf, (const unsigned*)kbf,
                                                s1q, s2q, s1k, s2k, out, bo);

    lnlin4<<<dim3(8, 8, 4), 256, 0, stream>>>(qbf, kbf, W1u, W1v, W2u, W2v, Au, Av, BuT, BvT);

    main2<<<dim3(16, 16, 16), 512, 0, stream>>>(
        qbf, kbf, Au, Av, BuT, BvT, W3u, W3v, su, tu, sv, tv, Wo,
        s1q, s2q, s1k, s2k, out);
}

// Round 7
// 433.151 us; speedup vs baseline: 2.5017x; 1.1749x over previous
//
#include <hip/hip_runtime.h>
#include <hip/hip_bf16.h>

#define QLEN 256
#define QD 1024
#define HD 512
#define H3 1536
#define EPSF 1e-5f

typedef __attribute__((ext_vector_type(8))) short short8;
typedef __attribute__((ext_vector_type(4))) float f32x4;

__device__ inline short f2bf(float f) {
    union { float f; unsigned u; } v; v.f = f;
    unsigned r = v.u + 0x7FFF + ((v.u >> 16) & 1);
    return (short)(r >> 16);
}
__device__ inline float bf2f(short s) {
    union { float f; unsigned u; } v; v.u = ((unsigned)(unsigned short)s) << 16;
    return v.f;
}
__device__ inline unsigned pk2(float a, float b) {
    return ((unsigned)(unsigned short)f2bf(a)) | (((unsigned)(unsigned short)f2bf(b)) << 16);
}
__device__ inline float asf(unsigned u) { union { unsigned u; float f; } v; v.u = u; return v.f; }
// packed bf16 convert (RNE), 1 instruction
__device__ inline unsigned cvtpk(float lo, float hi) {
    unsigned r;
    asm("v_cvt_pk_bf16_f32 %0, %1, %2" : "=v"(r) : "v"(lo), "v"(hi));
    return r;
}

// ---------- weight prep (both U and V via blockIdx.y) ------------------------
__global__ __launch_bounds__(256) void prep_w2(const float* __restrict__ Wu_, const float* __restrict__ Wv_,
                                               const float* __restrict__ lnw, const float* __restrict__ lnb,
                                               const float* __restrict__ bu_, const float* __restrict__ bv_,
                                               short* __restrict__ W1u, short* __restrict__ W2u, short* __restrict__ W3u,
                                               short* __restrict__ W1v, short* __restrict__ W2v, short* __restrict__ W3v,
                                               float* __restrict__ su, float* __restrict__ tu,
                                               float* __restrict__ sv, float* __restrict__ tv) {
    int h = blockIdx.x, z = blockIdx.y, tid = threadIdx.x;
    const float* row = (z ? Wv_ : Wu_) + (size_t)h * H3;
    const float* bias = z ? bv_ : bu_;
    short* W1 = z ? W1v : W1u; short* W2 = z ? W2v : W2u; short* W3 = z ? W3v : W3u;
    float* svec = z ? sv : su; float* tvec = z ? tv : tu;
    for (int j = tid; j < HD; j += 256) {
        W1[h * HD + j] = f2bf(lnw[j] * row[j]);
        W2[h * HD + j] = f2bf(lnw[HD + j] * row[HD + j]);
        W3[h * HD + j] = f2bf(lnw[2 * HD + j] * row[2 * HD + j]);
    }
    float s = 0.f, t = 0.f;
    for (int c = tid; c < H3; c += 256) {
        float w = row[c];
        s += lnw[c] * w;
        t += lnb[c] * w;
    }
    for (int m = 1; m < 64; m <<= 1) { s += __shfl_xor(s, m, 64); t += __shfl_xor(t, m, 64); }
    __shared__ float rs[4], rt[4];
    if ((tid & 63) == 0) { rs[tid >> 6] = s; rt[tid >> 6] = t; }
    __syncthreads();
    if (tid == 0) {
        svec[h] = rs[0] + rs[1] + rs[2] + rs[3];
        tvec[h] = rt[0] + rt[1] + rt[2] + rt[3] + bias[h];
    }
}

// ---------- q/k projection, f32 in -> bf16 out (z-fused) ---------------------
__global__ __launch_bounds__(256) void proj2(const float* __restrict__ Q_, const float* __restrict__ K_,
                                             const float* __restrict__ Wq_, const float* __restrict__ Wk_,
                                             short* __restrict__ qbf, short* __restrict__ kbf) {
    int z = blockIdx.z;
    const float* In = z ? K_ : Q_;
    const float* W = z ? Wk_ : Wq_;
    short* OutB = z ? kbf : qbf;
    __shared__ short a_l[64][72], b_l[64][72];
    int t = threadIdx.x;
    int i0 = blockIdx.y * 64, n0 = blockIdx.x * 64;
    int lane = t & 63, wv = t >> 6, wm = wv >> 1, wn = wv & 1;
    int l15 = lane & 15, lg = lane >> 4;
    f32x4 acc[2][2] = {};
    int sr = t >> 4, sc = (t & 15) * 4;
    for (int kc = 0; kc < QD; kc += 64) {
#pragma unroll
        for (int rep = 0; rep < 4; ++rep) {
            int row = sr + rep * 16;
            float4 av = *(const float4*)&In[(size_t)(i0 + row) * QD + kc + sc];
            float4 bv = *(const float4*)&W[(size_t)(n0 + row) * QD + kc + sc];
            *(uint2*)&a_l[row][sc] = (uint2){pk2(av.x, av.y), pk2(av.z, av.w)};
            *(uint2*)&b_l[row][sc] = (uint2){pk2(bv.x, bv.y), pk2(bv.z, bv.w)};
        }
        __syncthreads();
#pragma unroll
        for (int kk = 0; kk < 2; ++kk) {
            short8 af[2], bf_[2];
#pragma unroll
            for (int mi = 0; mi < 2; ++mi)
                af[mi] = *(const short8*)&a_l[wm * 32 + mi * 16 + l15][kk * 32 + lg * 8];
#pragma unroll
            for (int nj = 0; nj < 2; ++nj)
                bf_[nj] = *(const short8*)&b_l[wn * 32 + nj * 16 + l15][kk * 32 + lg * 8];
#pragma unroll
            for (int mi = 0; mi < 2; ++mi)
#pragma unroll
                for (int nj = 0; nj < 2; ++nj)
                    acc[mi][nj] = __builtin_amdgcn_mfma_f32_16x16x32_bf16(af[mi], bf_[nj], acc[mi][nj], 0, 0, 0);
        }
        __syncthreads();
    }
#pragma unroll
    for (int mi = 0; mi < 2; ++mi)
#pragma unroll
        for (int nj = 0; nj < 2; ++nj)
#pragma unroll
            for (int r = 0; r < 4; ++r) {
                int row = i0 + wm * 32 + mi * 16 + lg * 4 + r;
                int col = n0 + wn * 32 + nj * 16 + l15;
                OutB[(size_t)row * HD + col] = f2bf(acc[mi][nj][r]);
            }
}

// ---------- row sums (z-fused) + out init to bo ------------------------------
__global__ __launch_bounds__(256) void rowstats2(const unsigned* __restrict__ qbf, const unsigned* __restrict__ kbf,
                                                 float* __restrict__ s1q, float* __restrict__ s2q,
                                                 float* __restrict__ s1k, float* __restrict__ s2k,
                                                 float* __restrict__ out, const float* __restrict__ bo) {
    int row = blockIdx.x, z = blockIdx.y, tid = threadIdx.x;
    int gid = (z * 512 + row) * 256 + tid;
    if (gid < 2 * QLEN * QLEN) out[gid] = bo[0];
    const unsigned* Xbf = z ? kbf : qbf;
    float* s1 = z ? s1k : s1q;
    float* s2 = z ? s2k : s2q;
    unsigned u = Xbf[row * 256 + tid];
    float a = bf2f((short)(u & 0xffff)), b = bf2f((short)(u >> 16));
    float s = a + b, q = a * a + b * b;
    for (int m = 1; m < 64; m <<= 1) { s += __shfl_xor(s, m, 64); q += __shfl_xor(q, m, 64); }
    __shared__ float rs[4], rq[4];
    if ((tid & 63) == 0) { rs[tid >> 6] = s; rq[tid >> 6] = q; }
    __syncthreads();
    if (tid == 0) {
        s1[row] = rs[0] + rs[1] + rs[2] + rs[3];
        s2[row] = rq[0] + rq[1] + rq[2] + rq[3];
    }
}

// ---------- LN-linear row terms: 4 GEMMs z-fused (Au, Av, BuT, BvT) ----------
__global__ __launch_bounds__(256) void lnlin4(const short* __restrict__ qbf, const short* __restrict__ kbf,
                                              const short* __restrict__ W1u, const short* __restrict__ W1v,
                                              const short* __restrict__ W2u, const short* __restrict__ W2v,
                                              float* __restrict__ Au, float* __restrict__ Av,
                                              float* __restrict__ BuT, float* __restrict__ BvT) {
    int z = blockIdx.z;
    const short* A = (z < 2) ? qbf : kbf;
    const short* W = (z == 0) ? W1u : (z == 1) ? W1v : (z == 2) ? W2u : W2v;
    float* Out = (z == 0) ? Au : (z == 1) ? Av : (z == 2) ? BuT : BvT;
    bool tr = z >= 2;
    __shared__ short a_l[64][72], b_l[64][72];
    int t = threadIdx.x;
    int i0 = blockIdx.y * 64, n0 = blockIdx.x * 64;
    int lane = t & 63, wv = t >> 6, wm = wv >> 1, wn = wv & 1;
    int l15 = lane & 15, lg = lane >> 4;
    f32x4 acc[2][2] = {};
    int sr = t >> 4, sc = (t & 15) * 4;
    for (int kc = 0; kc < HD; kc += 64) {
#pragma unroll
        for (int rep = 0; rep < 4; ++rep) {
            int row = sr + rep * 16;
            *(uint2*)&a_l[row][sc] = *(const uint2*)&A[(size_t)(i0 + row) * HD + kc + sc];
            *(uint2*)&b_l[row][sc] = *(const uint2*)&W[(size_t)(n0 + row) * HD + kc + sc];
        }
        __syncthreads();
#pragma unroll
        for (int kk = 0; kk < 2; ++kk) {
            short8 af[2], bf_[2];
#pragma unroll
            for (int mi = 0; mi < 2; ++mi)
                af[mi] = *(const short8*)&a_l[wm * 32 + mi * 16 + l15][kk * 32 + lg * 8];
#pragma unroll
            for (int nj = 0; nj < 2; ++nj)
                bf_[nj] = *(const short8*)&b_l[wn * 32 + nj * 16 + l15][kk * 32 + lg * 8];
#pragma unroll
            for (int mi = 0; mi < 2; ++mi)
#pragma unroll
                for (int nj = 0; nj < 2; ++nj)
                    acc[mi][nj] = __builtin_amdgcn_mfma_f32_16x16x32_bf16(af[mi], bf_[nj], acc[mi][nj], 0, 0, 0);
        }
        __syncthreads();
    }
#pragma unroll
    for (int mi = 0; mi < 2; ++mi)
#pragma unroll
        for (int nj = 0; nj < 2; ++nj)
#pragma unroll
            for (int r = 0; r < 4; ++r) {
                int row = i0 + wm * 32 + mi * 16 + lg * 4 + r;
                int col = n0 + wn * 32 + nj * 16 + l15;
                if (tr) Out[(size_t)col * HD + row] = acc[mi][nj][r];
                else    Out[(size_t)row * HD + col] = acc[mi][nj][r];
            }
}

// ---------- main: 256 pairs (16q x 16k) x 128-h slice per block --------------
// 8 waves = 4 wm (pair quads) x 2 wn (h halves); wave = 64 pairs x 64 h.
// A-frag (p=q*k) built in regs; 88 VALU feeds 32 MFMA (was 16 in R6).
// B dbuf BK=64: [2][2][128h][64K] swizzled. LDS ~100 KB -> 1 block/CU,
// VGPR cap 256 (acc=128, live ~200, no spill).
__global__ __launch_bounds__(512) void main2(const short* __restrict__ qbf,
                                             const short* __restrict__ kbf,
                                             const float* __restrict__ Au,
                                             const float* __restrict__ Av,
                                             const float* __restrict__ BuT,
                                             const float* __restrict__ BvT,
                                             const short* __restrict__ W3u,
                                             const short* __restrict__ W3v,
                                             const float* __restrict__ su,
                                             const float* __restrict__ tu,
                                             const float* __restrict__ sv,
                                             const float* __restrict__ tv,
                                             const float* __restrict__ Wo,
                                             const float* __restrict__ s1q,
                                             const float* __restrict__ s2q,
                                             const float* __restrict__ s1k,
                                             const float* __restrict__ s2k,
                                             float* __restrict__ out) {
    __shared__ short q_l[16 * 512];          // 16 KB, swizzled rows (1024 B)
    __shared__ short k_l[16 * 512];          // 16 KB
    __shared__ short B_l[2][2][128 * 64];    // 64 KB: [buf][uv][h][64K], 128-B swizzled rows
    __shared__ float stat_l[512];
    __shared__ float sred[8][64];

    int tid = threadIdx.x;
    int kt = blockIdx.x, qt = blockIdx.y;
    int b = blockIdx.z >> 2, hs = blockIdx.z & 3;
    int qbase = qt * 16, kbase = kt * 16, hbase = hs * 128;
    int lane = tid & 63, wv = tid >> 6;
    int l15 = lane & 15, lg = lane >> 4;
    int wm = wv & 3, wn = wv >> 2;

    // ---- acc init = Au + BuT (C-in of MFMA); C rows = k (lg*4+r), cols = h --
    f32x4 accU[4][4], accV[4][4];
#pragma unroll
    for (int mf = 0; mf < 4; ++mf) {
        int qrow = b * QLEN + qbase + wm * 4 + mf;
#pragma unroll
        for (int nf = 0; nf < 4; ++nf) {
            int h = hbase + wn * 64 + nf * 16 + l15;
            float au = Au[(size_t)qrow * HD + h];
            float av = Av[(size_t)qrow * HD + h];
            f32x4 bu4 = *(const f32x4*)&BuT[(size_t)h * 512 + b * QLEN + kbase + lg * 4];
            f32x4 bv4 = *(const f32x4*)&BvT[(size_t)h * 512 + b * QLEN + kbase + lg * 4];
#pragma unroll
            for (int r = 0; r < 4; ++r) {
                accU[mf][nf][r] = au + bu4[r];
                accV[mf][nf][r] = av + bv4[r];
            }
        }
    }

    // ---- stage q,k tiles (swizzled) + zero stats ----
    stat_l[tid] = 0.f;
    for (int i = tid; i < 2048; i += 512) {
        int tile = i >> 10, slot = i & 1023;
        int row = slot >> 6, col16 = slot & 63;
        const short* sp = (tile ? kbf : qbf) +
            (size_t)(b * QLEN + (tile ? kbase : qbase) + row) * HD + col16 * 8;
        uint4 v = *(const uint4*)sp;
        short* dl = tile ? k_l : q_l;
        unsigned off = row * 1024 + ((col16 * 16) ^ ((row & 7) << 4));
        *(uint4*)((char*)dl + off) = v;
    }

    // ---- B chunk staging: BK=64 -> 32 KB per buf, 4 uint4 per thread --------
    uint4 rb[4];
    auto loadB = [&](int kc) {
#pragma unroll
        for (int s = 0; s < 4; ++s) {
            int idx = s * 512 + tid;
            int uvx = idx >> 10, in = idx & 1023;
            int r = in >> 3, c16 = in & 7;
            const short* src = (uvx ? W3v : W3u) + (size_t)(hbase + r) * HD + kc + c16 * 8;
            rb[s] = *(const uint4*)src;
        }
    };
    auto storeB = [&](int buf) {
#pragma unroll
        for (int s = 0; s < 4; ++s) {
            int idx = s * 512 + tid;
            int uvx = idx >> 10, in = idx & 1023;
            int r = in >> 3, c16 = in & 7;
            unsigned off = r * 128 + ((c16 * 16) ^ ((r & 7) << 4));
            *(uint4*)((char*)&B_l[buf][uvx][0] + off) = rb[s];
        }
    };

    loadB(0);  // prologue

    // ---- K loop: 8 chunks of BK=64, dbuf, one barrier per chunk -------------
    for (int c = 0; c < 8; ++c) {
        storeB(c & 1);
        if (c < 7) loadB((c + 1) * 64);
        __syncthreads();

        if (c == 0) {
            // pair stats: d1 = q.k, d2 = q^2.k^2 (16x16x32 MFMAs on q_l/k_l)
            f32x4 d1 = {0.f, 0.f, 0.f, 0.f}, d2 = {0.f, 0.f, 0.f, 0.f};
#pragma unroll
            for (int s = 0; s < 2; ++s) {
                int jb = (wv * 2 + s) * 64 + lg * 16;
                uint4 qfu = *(const uint4*)((const char*)q_l + l15 * 1024 + (jb ^ ((l15 & 7) << 4)));
                uint4 kfu = *(const uint4*)((const char*)k_l + l15 * 1024 + (jb ^ ((l15 & 7) << 4)));
                d1 = __builtin_amdgcn_mfma_f32_16x16x32_bf16(
                    *(short8*)&qfu, *(short8*)&kfu, d1, 0, 0, 0);
                uint4 q2u, k2u;
                unsigned* qp = (unsigned*)&qfu; unsigned* kp = (unsigned*)&kfu;
                unsigned* q2p = (unsigned*)&q2u; unsigned* k2p = (unsigned*)&k2u;
#pragma unroll
                for (int i = 0; i < 4; ++i) {
                    float ql = asf(qp[i] << 16), qh = asf(qp[i] & 0xFFFF0000u);
                    float kl = asf(kp[i] << 16), kh = asf(kp[i] & 0xFFFF0000u);
                    q2p[i] = cvtpk(ql * ql, qh * qh);
                    k2p[i] = cvtpk(kl * kl, kh * kh);
                }
                d2 = __builtin_amdgcn_mfma_f32_16x16x32_bf16(
                    *(short8*)&q2u, *(short8*)&k2u, d2, 0, 0, 0);
            }
#pragma unroll
            for (int r = 0; r < 4; ++r) {
                int p = (lg * 4 + r) * 16 + l15;
                atomicAdd(&stat_l[p], d1[r]);
                atomicAdd(&stat_l[256 + p], d2[r]);
            }
        }

        const char* blu = (const char*)&B_l[c & 1][0][0];
        const char* blv = (const char*)&B_l[c & 1][1][0];
#pragma unroll
        for (int ksub = 0; ksub < 2; ++ksub) {
            int jb = (c * 2 + ksub) * 64 + lg * 16;   // q/k byte col (K32 slice)
            int bb = ksub * 64 + lg * 16;             // B byte col within chunk
            // k fragment (shared across mf), unpack to f32
            uint4 kfu = *(const uint4*)((const char*)k_l + l15 * 1024 + (jb ^ ((l15 & 7) << 4)));
            unsigned* kp = (unsigned*)&kfu;
            float klo[4], khi[4];
#pragma unroll
            for (int i = 0; i < 4; ++i) {
                klo[i] = asf(kp[i] << 16);
                khi[i] = asf(kp[i] & 0xFFFF0000u);
            }
            // A fragments: p = q*k packed bf16 (q broadcast per mf)
            short8 af[4];
#pragma unroll
            for (int mf = 0; mf < 4; ++mf) {
                int qrow = wm * 4 + mf;
                uint4 qfu = *(const uint4*)((const char*)q_l + qrow * 1024 + (jb ^ ((qrow & 7) << 4)));
                unsigned* qp = (unsigned*)&qfu;
                uint4 afu;
                unsigned* ap = (unsigned*)&afu;
#pragma unroll
                for (int i = 0; i < 4; ++i) {
                    float ql = asf(qp[i] << 16), qh = asf(qp[i] & 0xFFFF0000u);
                    ap[i] = cvtpk(ql * klo[i], qh * khi[i]);
                }
                af[mf] = *(short8*)&afu;
            }
            // B frags per nf, 8 MFMAs each
#pragma unroll
            for (int nf = 0; nf < 4; ++nf) {
                int row = wn * 64 + nf * 16 + l15;
                unsigned off = row * 128 + (bb ^ ((row & 7) << 4));
                short8 bu_f = *(const short8*)(blu + off);
                short8 bv_f = *(const short8*)(blv + off);
#pragma unroll
                for (int mf = 0; mf < 4; ++mf) {
                    accU[mf][nf] = __builtin_amdgcn_mfma_f32_16x16x32_bf16(af[mf], bu_f, accU[mf][nf], 0, 0, 0);
                    accV[mf][nf] = __builtin_amdgcn_mfma_f32_16x16x32_bf16(af[mf], bv_f, accV[mf][nf], 0, 0, 0);
                }
            }
        }
    }

    // ---- mu/ri conversion ----
    if (tid < 256) {
        int qi = tid >> 4, ki = tid & 15;
        float mu = (s1q[b * QLEN + qbase + qi] + s1k[b * QLEN + kbase + ki] + stat_l[tid]) * (1.f / H3);
        float ex2 = (s2q[b * QLEN + qbase + qi] + s2k[b * QLEN + kbase + ki] + stat_l[256 + tid]) * (1.f / H3);
        float ri = rsqrtf(ex2 - mu * mu + EPSF);
        stat_l[tid] = ri;
        stat_l[256 + tid] = ri * mu;
    }
    __syncthreads();

    // ---- fused epilogue: LN-linear + gelu + Wo, h-reduce ----
    float sacc[16];
#pragma unroll
    for (int i = 0; i < 16; ++i) sacc[i] = 0.f;
#pragma unroll
    for (int nf = 0; nf < 4; ++nf) {
        int h = hbase + wn * 64 + nf * 16 + l15;
        float suh = su[h], tuh = tu[h], svh = sv[h], tvh = tv[h], woh = Wo[h];
#pragma unroll
        for (int mf = 0; mf < 4; ++mf) {
            int pbase = (wm * 4 + mf) * 16 + lg * 4;
#pragma unroll
            for (int r = 0; r < 4; ++r) {
                float ri = stat_l[pbase + r];
                float rmu = stat_l[256 + pbase + r];
                float u = fmaf(ri, accU[mf][nf][r], tuh) - rmu * suh;
                float vx = fmaf(ri, accV[mf][nf][r], tvh) - rmu * svh;
                float x2 = vx * vx;
                float tt = vx * fmaf(0.0356774081f, x2, 0.7978845608f);
                float e2 = exp2f(tt * 2.885390082f);
                float ge = vx - vx / (e2 + 1.0f);      // v*sigmoid(2t), inf-safe
                sacc[mf * 4 + r] = fmaf(u * ge, woh, sacc[mf * 4 + r]);
            }
        }
    }

    // reduce over the 16 h-lanes (l15)
#pragma unroll
    for (int i = 0; i < 16; ++i) {
        float v = sacc[i];
        v += __shfl_xor(v, 1, 64);
        v += __shfl_xor(v, 2, 64);
        v += __shfl_xor(v, 4, 64);
        v += __shfl_xor(v, 8, 64);
        sacc[i] = v;
    }
    if (l15 == 0) {
#pragma unroll
        for (int mf = 0; mf < 4; ++mf)
#pragma unroll
            for (int r = 0; r < 4; ++r)
                sred[wv][mf * 16 + lg * 4 + r] = sacc[mf * 4 + r];
    }
    __syncthreads();
    if (tid < 256) {
        int wm_ = tid >> 6, within = tid & 63;
        float val = sred[wm_][within] + sred[wm_ + 4][within];
        int qi = wm_ * 4 + (within >> 4), ki = within & 15;
        atomicAdd(&out[(size_t)(b * QLEN + qbase + qi) * QLEN + kbase + ki], val);
    }
}

extern "C" void kernel_launch(void* const* d_in, const int* in_sizes, int n_in,
                              void* d_out, int out_size, void* d_ws, size_t ws_size,
                              hipStream_t stream) {
    const float* Q   = (const float*)d_in[0];
    const float* Kin = (const float*)d_in[1];
    const float* Wq  = (const float*)d_in[2];
    const float* Wk  = (const float*)d_in[3];
    const float* lnw = (const float*)d_in[4];
    const float* lnb = (const float*)d_in[5];
    const float* Wu  = (const float*)d_in[6];
    const float* bu  = (const float*)d_in[7];
    const float* Wv  = (const float*)d_in[8];
    const float* bv  = (const float*)d_in[9];
    const float* Wo  = (const float*)d_in[10];
    const float* bo  = (const float*)d_in[11];
    float* out = (float*)d_out;

    char* ws = (char*)d_ws;
    size_t off = 0;
    auto alloc = [&](size_t bytes) -> void* {
        void* p = ws + off;
        off += (bytes + 255) & ~(size_t)255;
        return p;
    };
    const size_t WB = (size_t)HD * HD * 2;  // 512 KB bf16 matrix
    short* W1u = (short*)alloc(WB); short* W2u = (short*)alloc(WB); short* W3u = (short*)alloc(WB);
    short* W1v = (short*)alloc(WB); short* W2v = (short*)alloc(WB); short* W3v = (short*)alloc(WB);
    short* qbf = (short*)alloc(WB); short* kbf = (short*)alloc(WB);
    float* su = (float*)alloc(HD * 4); float* tu = (float*)alloc(HD * 4);
    float* sv = (float*)alloc(HD * 4); float* tv = (float*)alloc(HD * 4);
    float* s1q = (float*)alloc(512 * 4); float* s2q = (float*)alloc(512 * 4);
    float* s1k = (float*)alloc(512 * 4); float* s2k = (float*)alloc(512 * 4);
    float* Au  = (float*)alloc((size_t)512 * HD * 4);
    float* Av  = (float*)alloc((size_t)512 * HD * 4);
    float* BuT = (float*)alloc((size_t)512 * HD * 4);
    float* BvT = (float*)alloc((size_t)512 * HD * 4);

    prep_w2<<<dim3(HD, 2), 256, 0, stream>>>(Wu, Wv, lnw, lnb, bu, bv,
                                             W1u, W2u, W3u, W1v, W2v, W3v, su, tu, sv, tv);

    proj2<<<dim3(8, 8, 2), 256, 0, stream>>>(Q, Kin, Wq, Wk, qbf, kbf);

    rowstats2<<<dim3(512, 2), 256, 0, stream>>>((const unsigned*)qbf, (const unsigned*)kbf,
                                                s1q, s2q, s1k, s2k, out, bo);

    lnlin4<<<dim3(8, 8, 4), 256, 0, stream>>>(qbf, kbf, W1u, W1v, W2u, W2v, Au, Av, BuT, BvT);

    main2<<<dim3(16, 16, 8), 512, 0, stream>>>(
        qbf, kbf, Au, Av, BuT, BvT, W3u, W3v, su, tu, sv, tv, Wo,
        s1q, s2q, s1k, s2k, out);
}

// Round 10
// 379.975 us; speedup vs baseline: 2.8518x; 1.1399x over previous
//
#include <hip/hip_runtime.h>
#include <hip/hip_bf16.h>

#define QLEN 256
#define QD 1024
#define HD 512
#define H3 1536
#define EPSF 1e-5f

typedef __attribute__((ext_vector_type(8))) _Float16 half8;
typedef __attribute__((ext_vector_type(4))) float f32x4;

__device__ inline short f2h(float f) { _Float16 h = (_Float16)f; return __builtin_bit_cast(short, h); }
__device__ inline float h2f(short s) { return (float)__builtin_bit_cast(_Float16, s); }
__device__ inline unsigned pkh(float a, float b) {
    return __builtin_bit_cast(unsigned, __builtin_amdgcn_cvt_pkrtz(a, b));
}

// ---------- weight prep: W1/W2 [h][K] f16, W3 in MFMA-frag layout, su/tu -----
// W3p element for (h,j): ht=h>>4, l15=h&15, ks=j>>5, lg=(j>>3)&3, i=j&7
//   -> W3p[((ht*16+ks)*64 + lg*16+l15)*8 + i]  (one coalesced 1KB block per
//      (h-tile,k-slice) = exactly one global_load_dwordx4 per wave in main)
__global__ __launch_bounds__(256) void prep_w2(const float* __restrict__ Wu_, const float* __restrict__ Wv_,
                                               const float* __restrict__ lnw, const float* __restrict__ lnb,
                                               const float* __restrict__ bu_, const float* __restrict__ bv_,
                                               short* __restrict__ W1u, short* __restrict__ W2u, short* __restrict__ W3pu,
                                               short* __restrict__ W1v, short* __restrict__ W2v, short* __restrict__ W3pv,
                                               float* __restrict__ su, float* __restrict__ tu,
                                               float* __restrict__ sv, float* __restrict__ tv) {
    int h = blockIdx.x, z = blockIdx.y, tid = threadIdx.x;
    const float* row = (z ? Wv_ : Wu_) + (size_t)h * H3;
    const float* bias = z ? bv_ : bu_;
    short* W1 = z ? W1v : W1u; short* W2 = z ? W2v : W2u; short* W3p = z ? W3pv : W3pu;
    float* svec = z ? sv : su; float* tvec = z ? tv : tu;
    int ht = h >> 4, l15h = h & 15;
    for (int j = tid; j < HD; j += 256) {
        W1[h * HD + j] = f2h(lnw[j] * row[j]);
        W2[h * HD + j] = f2h(lnw[HD + j] * row[HD + j]);
        float w3 = lnw[2 * HD + j] * row[2 * HD + j];
        int ks = j >> 5, lg2 = (j >> 3) & 3, ii = j & 7;
        W3p[((ht * 16 + ks) * 64 + lg2 * 16 + l15h) * 8 + ii] = f2h(w3);
    }
    float s = 0.f, t = 0.f;
    for (int c = tid; c < H3; c += 256) {
        float w = row[c];
        s += lnw[c] * w;
        t += lnb[c] * w;
    }
    for (int m = 1; m < 64; m <<= 1) { s += __shfl_xor(s, m, 64); t += __shfl_xor(t, m, 64); }
    __shared__ float rs[4], rt[4];
    if ((tid & 63) == 0) { rs[tid >> 6] = s; rt[tid >> 6] = t; }
    __syncthreads();
    if (tid == 0) {
        svec[h] = rs[0] + rs[1] + rs[2] + rs[3];
        tvec[h] = rt[0] + rt[1] + rt[2] + rt[3] + bias[h];
    }
}

// ---------- q/k projection, f32 in -> f16 out (z-fused) ----------------------
__global__ __launch_bounds__(256) void proj2(const float* __restrict__ Q_, const float* __restrict__ K_,
                                             const float* __restrict__ Wq_, const float* __restrict__ Wk_,
                                             short* __restrict__ qh, short* __restrict__ kh) {
    int z = blockIdx.z;
    const float* In = z ? K_ : Q_;
    const float* W = z ? Wk_ : Wq_;
    short* OutB = z ? kh : qh;
    __shared__ short a_l[64][72], b_l[64][72];
    int t = threadIdx.x;
    int i0 = blockIdx.y * 64, n0 = blockIdx.x * 64;
    int lane = t & 63, wv = t >> 6, wm = wv >> 1, wn = wv & 1;
    int l15 = lane & 15, lg = lane >> 4;
    f32x4 acc[2][2] = {};
    int sr = t >> 4, sc = (t & 15) * 4;
    for (int kc = 0; kc < QD; kc += 64) {
#pragma unroll
        for (int rep = 0; rep < 4; ++rep) {
            int row = sr + rep * 16;
            float4 av = *(const float4*)&In[(size_t)(i0 + row) * QD + kc + sc];
            float4 bv = *(const float4*)&W[(size_t)(n0 + row) * QD + kc + sc];
            *(uint2*)&a_l[row][sc] = (uint2){pkh(av.x, av.y), pkh(av.z, av.w)};
            *(uint2*)&b_l[row][sc] = (uint2){pkh(bv.x, bv.y), pkh(bv.z, bv.w)};
        }
        __syncthreads();
#pragma unroll
        for (int kk = 0; kk < 2; ++kk) {
            half8 af[2], bf_[2];
#pragma unroll
            for (int mi = 0; mi < 2; ++mi)
                af[mi] = *(const half8*)&a_l[wm * 32 + mi * 16 + l15][kk * 32 + lg * 8];
#pragma unroll
            for (int nj = 0; nj < 2; ++nj)
                bf_[nj] = *(const half8*)&b_l[wn * 32 + nj * 16 + l15][kk * 32 + lg * 8];
#pragma unroll
            for (int mi = 0; mi < 2; ++mi)
#pragma unroll
                for (int nj = 0; nj < 2; ++nj)
                    acc[mi][nj] = __builtin_amdgcn_mfma_f32_16x16x32_f16(af[mi], bf_[nj], acc[mi][nj], 0, 0, 0);
        }
        __syncthreads();
    }
#pragma unroll
    for (int mi = 0; mi < 2; ++mi)
#pragma unroll
        for (int nj = 0; nj < 2; ++nj)
#pragma unroll
            for (int r = 0; r < 4; ++r) {
                int row = i0 + wm * 32 + mi * 16 + lg * 4 + r;
                int col = n0 + wn * 32 + nj * 16 + l15;
                OutB[(size_t)row * HD + col] = f2h(acc[mi][nj][r]);
            }
}

// ---------- row sums (z-fused) + out init to bo ------------------------------
__global__ __launch_bounds__(256) void rowstats2(const unsigned* __restrict__ qh, const unsigned* __restrict__ kh,
                                                 float* __restrict__ s1q, float* __restrict__ s2q,
                                                 float* __restrict__ s1k, float* __restrict__ s2k,
                                                 float* __restrict__ out, const float* __restrict__ bo) {
    int row = blockIdx.x, z = blockIdx.y, tid = threadIdx.x;
    int gid = (z * 512 + row) * 256 + tid;
    if (gid < 2 * QLEN * QLEN) out[gid] = bo[0];
    const unsigned* Xh = z ? kh : qh;
    float* s1 = z ? s1k : s1q;
    float* s2 = z ? s2k : s2q;
    unsigned u = Xh[row * 256 + tid];
    float a = h2f((short)(u & 0xffff)), b = h2f((short)(u >> 16));
    float s = a + b, q = a * a + b * b;
    for (int m = 1; m < 64; m <<= 1) { s += __shfl_xor(s, m, 64); q += __shfl_xor(q, m, 64); }
    __shared__ float rs[4], rq[4];
    if ((tid & 63) == 0) { rs[tid >> 6] = s; rq[tid >> 6] = q; }
    __syncthreads();
    if (tid == 0) {
        s1[row] = rs[0] + rs[1] + rs[2] + rs[3];
        s2[row] = rq[0] + rq[1] + rq[2] + rq[3];
    }
}

// ---------- LN-linear row terms: 4 GEMMs z-fused (Au, Av, BuT, BvT) ----------
__global__ __launch_bounds__(256) void lnlin4(const short* __restrict__ qh, const short* __restrict__ kh,
                                              const short* __restrict__ W1u, const short* __restrict__ W1v,
                                              const short* __restrict__ W2u, const short* __restrict__ W2v,
                                              float* __restrict__ Au, float* __restrict__ Av,
                                              float* __restrict__ BuT, float* __restrict__ BvT) {
    int z = blockIdx.z;
    const short* A = (z < 2) ? qh : kh;
    const short* W = (z == 0) ? W1u : (z == 1) ? W1v : (z == 2) ? W2u : W2v;
    float* Out = (z == 0) ? Au : (z == 1) ? Av : (z == 2) ? BuT : BvT;
    bool tr = z >= 2;
    __shared__ short a_l[64][72], b_l[64][72];
    int t = threadIdx.x;
    int i0 = blockIdx.y * 64, n0 = blockIdx.x * 64;
    int lane = t & 63, wv = t >> 6, wm = wv >> 1, wn = wv & 1;
    int l15 = lane & 15, lg = lane >> 4;
    f32x4 acc[2][2] = {};
    int sr = t >> 4, sc = (t & 15) * 4;
    for (int kc = 0; kc < HD; kc += 64) {
#pragma unroll
        for (int rep = 0; rep < 4; ++rep) {
            int row = sr + rep * 16;
            *(uint2*)&a_l[row][sc] = *(const uint2*)&A[(size_t)(i0 + row) * HD + kc + sc];
            *(uint2*)&b_l[row][sc] = *(const uint2*)&W[(size_t)(n0 + row) * HD + kc + sc];
        }
        __syncthreads();
#pragma unroll
        for (int kk = 0; kk < 2; ++kk) {
            half8 af[2], bf_[2];
#pragma unroll
            for (int mi = 0; mi < 2; ++mi)
                af[mi] = *(const half8*)&a_l[wm * 32 + mi * 16 + l15][kk * 32 + lg * 8];
#pragma unroll
            for (int nj = 0; nj < 2; ++nj)
                bf_[nj] = *(const half8*)&b_l[wn * 32 + nj * 16 + l15][kk * 32 + lg * 8];
#pragma unroll
            for (int mi = 0; mi < 2; ++mi)
#pragma unroll
                for (int nj = 0; nj < 2; ++nj)
                    acc[mi][nj] = __builtin_amdgcn_mfma_f32_16x16x32_f16(af[mi], bf_[nj], acc[mi][nj], 0, 0, 0);
        }
        __syncthreads();
    }
#pragma unroll
    for (int mi = 0; mi < 2; ++mi)
#pragma unroll
        for (int nj = 0; nj < 2; ++nj)
#pragma unroll
            for (int r = 0; r < 4; ++r) {
                int row = i0 + wm * 32 + mi * 16 + lg * 4 + r;
                int col = n0 + wn * 32 + nj * 16 + l15;
                if (tr) Out[(size_t)col * HD + row] = acc[mi][nj][r];
                else    Out[(size_t)row * HD + col] = acc[mi][nj][r];
            }
}

// ---------- main: 256 pairs x 128 h; barrier-free K loop ---------------------
// q,k f16 tiles LDS-resident (XOR-swizzled). A-frag = q8*k8 (4 v_pk_mul_f16).
// B read DIRECTLY from global in frag-ready layout (coalesced 16B/lane,
// 32KB/chunk shared by 8 waves -> L1/L2 hit). No B staging, no K-loop
// barriers -> MFMA<->load free-running stream. acc-init folded into epilogue.
__global__ __launch_bounds__(512) void main2(const short* __restrict__ qh,
                                             const short* __restrict__ kh,
                                             const float* __restrict__ Au,
                                             const float* __restrict__ Av,
                                             const float* __restrict__ BuT,
                                             const float* __restrict__ BvT,
                                             const short* __restrict__ W3pu,
                                             const short* __restrict__ W3pv,
                                             const float* __restrict__ su,
                                             const float* __restrict__ tu,
                                             const float* __restrict__ sv,
                                             const float* __restrict__ tv,
                                             const float* __restrict__ Wo,
                                             const float* __restrict__ s1q,
                                             const float* __restrict__ s2q,
                                             const float* __restrict__ s1k,
                                             const float* __restrict__ s2k,
                                             float* __restrict__ out) {
    __shared__ short q_l[16 * 512];          // 16 KB, swizzled rows (1024 B)
    __shared__ short k_l[16 * 512];          // 16 KB
    __shared__ float stat_l[512];
    __shared__ float sred[8][64];

    int tid = threadIdx.x;
    int kt = blockIdx.x, qt = blockIdx.y;
    int b = blockIdx.z >> 2, hs = blockIdx.z & 3;
    int qbase = qt * 16, kbase = kt * 16, hbase = hs * 128;
    int lane = tid & 63, wv = tid >> 6;
    int l15 = lane & 15, lg = lane >> 4;
    int wm = wv & 3, wn = wv >> 2;

    // ---- stage q,k tiles (swizzled) + zero stats ----
    stat_l[tid] = 0.f;
    for (int i = tid; i < 2048; i += 512) {
        int tile = i >> 10, slot = i & 1023;
        int row = slot >> 6, col16 = slot & 63;
        const short* sp = (tile ? kh : qh) +
            (size_t)(b * QLEN + (tile ? kbase : qbase) + row) * HD + col16 * 8;
        uint4 v = *(const uint4*)sp;
        short* dl = tile ? k_l : q_l;
        unsigned off = row * 1024 + ((col16 * 16) ^ ((row & 7) << 4));
        *(uint4*)((char*)dl + off) = v;
    }
    __syncthreads();

    // ---- pair stats: d1 = q.k, d2 = q^2.k^2 (each wave: 2 K-slices) ----
    {
        f32x4 d1 = {0.f, 0.f, 0.f, 0.f}, d2 = {0.f, 0.f, 0.f, 0.f};
#pragma unroll
        for (int s = 0; s < 2; ++s) {
            int jb = (wv * 2 + s) * 64 + lg * 16;
            uint4 qfu = *(const uint4*)((const char*)q_l + l15 * 1024 + (jb ^ ((l15 & 7) << 4)));
            uint4 kfu = *(const uint4*)((const char*)k_l + l15 * 1024 + (jb ^ ((l15 & 7) << 4)));
            half8 q8 = __builtin_bit_cast(half8, qfu);
            half8 k8 = __builtin_bit_cast(half8, kfu);
            half8 q2 = q8 * q8, k2 = k8 * k8;
            d1 = __builtin_amdgcn_mfma_f32_16x16x32_f16(q8, k8, d1, 0, 0, 0);
            d2 = __builtin_amdgcn_mfma_f32_16x16x32_f16(q2, k2, d2, 0, 0, 0);
        }
#pragma unroll
        for (int r = 0; r < 4; ++r) {
            int p = (lg * 4 + r) * 16 + l15;
            atomicAdd(&stat_l[p], d1[r]);
            atomicAdd(&stat_l[256 + p], d2[r]);
        }
    }

    // ---- barrier-free K loop: 16 slices of K=32 ----
    f32x4 accU[4][4] = {}, accV[4][4] = {};
    int ht0 = hs * 8 + wn * 4;
#pragma unroll 2
    for (int ks = 0; ks < 16; ++ks) {
        int jb = ks * 64 + lg * 16;
        uint4 kfu = *(const uint4*)((const char*)k_l + l15 * 1024 + (jb ^ ((l15 & 7) << 4)));
        half8 k8 = __builtin_bit_cast(half8, kfu);
        half8 af[4];
#pragma unroll
        for (int mf = 0; mf < 4; ++mf) {
            int qrow = wm * 4 + mf;
            uint4 qfu = *(const uint4*)((const char*)q_l + qrow * 1024 + (jb ^ ((qrow & 7) << 4)));
            af[mf] = __builtin_bit_cast(half8, qfu) * k8;
        }
#pragma unroll
        for (int nf = 0; nf < 4; ++nf) {
            int fo = ((ht0 + nf) * 16 + ks) * 512 + lane * 8;
            half8 bu = *(const half8*)(W3pu + fo);
            half8 bv = *(const half8*)(W3pv + fo);
#pragma unroll
            for (int mf = 0; mf < 4; ++mf) {
                accU[mf][nf] = __builtin_amdgcn_mfma_f32_16x16x32_f16(af[mf], bu, accU[mf][nf], 0, 0, 0);
                accV[mf][nf] = __builtin_amdgcn_mfma_f32_16x16x32_f16(af[mf], bv, accV[mf][nf], 0, 0, 0);
            }
        }
    }

    __syncthreads();   // stats atomics complete
    // ---- mu/ri conversion ----
    if (tid < 256) {
        int qi = tid >> 4, ki = tid & 15;
        float mu = (s1q[b * QLEN + qbase + qi] + s1k[b * QLEN + kbase + ki] + stat_l[tid]) * (1.f / H3);
        float ex2 = (s2q[b * QLEN + qbase + qi] + s2k[b * QLEN + kbase + ki] + stat_l[256 + tid]) * (1.f / H3);
        float ri = rsqrtf(ex2 - mu * mu + EPSF);
        stat_l[tid] = ri;
        stat_l[256 + tid] = ri * mu;
    }
    __syncthreads();

    // ---- fused epilogue: + Au/BuT (acc-init folded), LN-linear, gelu, Wo ----
    float sacc[16];
#pragma unroll
    for (int i = 0; i < 16; ++i) sacc[i] = 0.f;
#pragma unroll
    for (int nf = 0; nf < 4; ++nf) {
        int h = hbase + wn * 64 + nf * 16 + l15;
        float suh = su[h], tuh = tu[h], svh = sv[h], tvh = tv[h], woh = Wo[h];
        f32x4 bu4 = *(const f32x4*)&BuT[(size_t)h * 512 + b * QLEN + kbase + lg * 4];
        f32x4 bv4 = *(const f32x4*)&BvT[(size_t)h * 512 + b * QLEN + kbase + lg * 4];
#pragma unroll
        for (int mf = 0; mf < 4; ++mf) {
            int qrow = b * QLEN + qbase + wm * 4 + mf;
            float au = Au[(size_t)qrow * HD + h];
            float av = Av[(size_t)qrow * HD + h];
            int pbase = (wm * 4 + mf) * 16 + lg * 4;
#pragma unroll
            for (int r = 0; r < 4; ++r) {
                float ri = stat_l[pbase + r];
                float rmu = stat_l[256 + pbase + r];
                float gu = au + bu4[r] + accU[mf][nf][r];
                float gv = av + bv4[r] + accV[mf][nf][r];
                float u = fmaf(ri, gu, tuh) - rmu * suh;
                float vx = fmaf(ri, gv, tvh) - rmu * svh;
                float x2 = vx * vx;
                float tt = vx * fmaf(0.0356774081f, x2, 0.7978845608f);
                float e2 = exp2f(tt * 2.885390082f);
                float ge = vx - vx / (e2 + 1.0f);      // v*sigmoid(2t), inf-safe
                sacc[mf * 4 + r] = fmaf(u * ge, woh, sacc[mf * 4 + r]);
            }
        }
    }

    // reduce over the 16 h-lanes (l15)
#pragma unroll
    for (int i = 0; i < 16; ++i) {
        float v = sacc[i];
        v += __shfl_xor(v, 1, 64);
        v += __shfl_xor(v, 2, 64);
        v += __shfl_xor(v, 4, 64);
        v += __shfl_xor(v, 8, 64);
        sacc[i] = v;
    }
    if (l15 == 0) {
#pragma unroll
        for (int mf = 0; mf < 4; ++mf)
#pragma unroll
            for (int r = 0; r < 4; ++r)
                sred[wv][mf * 16 + lg * 4 + r] = sacc[mf * 4 + r];
    }
    __syncthreads();
    if (tid < 256) {
        int wm_ = tid >> 6, within = tid & 63;
        float val = sred[wm_][within] + sred[wm_ + 4][within];
        int qi = wm_ * 4 + (within >> 4), ki = within & 15;
        atomicAdd(&out[(size_t)(b * QLEN + qbase + qi) * QLEN + kbase + ki], val);
    }
}

extern "C" void kernel_launch(void* const* d_in, const int* in_sizes, int n_in,
                              void* d_out, int out_size, void* d_ws, size_t ws_size,
                              hipStream_t stream) {
    const float* Q   = (const float*)d_in[0];
    const float* Kin = (const float*)d_in[1];
    const float* Wq  = (const float*)d_in[2];
    const float* Wk  = (const float*)d_in[3];
    const float* lnw = (const float*)d_in[4];
    const float* lnb = (const float*)d_in[5];
    const float* Wu  = (const float*)d_in[6];
    const float* bu  = (const float*)d_in[7];
    const float* Wv  = (const float*)d_in[8];
    const float* bv  = (const float*)d_in[9];
    const float* Wo  = (const float*)d_in[10];
    const float* bo  = (const float*)d_in[11];
    float* out = (float*)d_out;

    char* ws = (char*)d_ws;
    size_t off = 0;
    auto alloc = [&](size_t bytes) -> void* {
        void* p = ws + off;
        off += (bytes + 255) & ~(size_t)255;
        return p;
    };
    const size_t WB = (size_t)HD * HD * 2;  // 512 KB f16 matrix
    short* W1u = (short*)alloc(WB); short* W2u = (short*)alloc(WB); short* W3pu = (short*)alloc(WB);
    short* W1v = (short*)alloc(WB); short* W2v = (short*)alloc(WB); short* W3pv = (short*)alloc(WB);
    short* qh = (short*)alloc(WB); short* kh = (short*)alloc(WB);
    float* su = (float*)alloc(HD * 4); float* tu = (float*)alloc(HD * 4);
    float* sv = (float*)alloc(HD * 4); float* tv = (float*)alloc(HD * 4);
    float* s1q = (float*)alloc(512 * 4); float* s2q = (float*)alloc(512 * 4);
    float* s1k = (float*)alloc(512 * 4); float* s2k = (float*)alloc(512 * 4);
    float* Au  = (float*)alloc((size_t)512 * HD * 4);
    float* Av  = (float*)alloc((size_t)512 * HD * 4);
    float* BuT = (float*)alloc((size_t)512 * HD * 4);
    float* BvT = (float*)alloc((size_t)512 * HD * 4);

    prep_w2<<<dim3(HD, 2), 256, 0, stream>>>(Wu, Wv, lnw, lnb, bu, bv,
                                             W1u, W2u, W3pu, W1v, W2v, W3pv, su, tu, sv, tv);

    proj2<<<dim3(8, 8, 2), 256, 0, stream>>>(Q, Kin, Wq, Wk, qh, kh);

    rowstats2<<<dim3(512, 2), 256, 0, stream>>>((const unsigned*)qh, (const unsigned*)kh,
                                                s1q, s2q, s1k, s2k, out, bo);

    lnlin4<<<dim3(8, 8, 4), 256, 0, stream>>>(qh, kh, W1u, W1v, W2u, W2v, Au, Av, BuT, BvT);

    main2<<<dim3(16, 16, 8), 512, 0, stream>>>(
        qh, kh, Au, Av, BuT, BvT, W3pu, W3pv, su, tu, sv, tv, Wo,
        s1q, s2q, s1k, s2k, out);
}

// Round 11
// 369.786 us; speedup vs baseline: 2.9304x; 1.0276x over previous
//
#include <hip/hip_runtime.h>
#include <hip/hip_bf16.h>

#define QLEN 256
#define QD 1024
#define HD 512
#define H3 1536
#define EPSF 1e-5f

typedef __attribute__((ext_vector_type(8))) _Float16 half8;
typedef __attribute__((ext_vector_type(4))) float f32x4;

__device__ inline short f2h(float f) { _Float16 h = (_Float16)f; return __builtin_bit_cast(short, h); }
__device__ inline float h2f(short s) { return (float)__builtin_bit_cast(_Float16, s); }
__device__ inline unsigned pkh(float a, float b) {
    return __builtin_bit_cast(unsigned, __builtin_amdgcn_cvt_pkrtz(a, b));
}

// ---------- weight prep: W1/W2 [h][K] f16, W3 in MFMA-frag layout, su/tu -----
__global__ __launch_bounds__(256) void prep_w2(const float* __restrict__ Wu_, const float* __restrict__ Wv_,
                                               const float* __restrict__ lnw, const float* __restrict__ lnb,
                                               const float* __restrict__ bu_, const float* __restrict__ bv_,
                                               short* __restrict__ W1u, short* __restrict__ W2u, short* __restrict__ W3pu,
                                               short* __restrict__ W1v, short* __restrict__ W2v, short* __restrict__ W3pv,
                                               float* __restrict__ su, float* __restrict__ tu,
                                               float* __restrict__ sv, float* __restrict__ tv) {
    int h = blockIdx.x, z = blockIdx.y, tid = threadIdx.x;
    const float* row = (z ? Wv_ : Wu_) + (size_t)h * H3;
    const float* bias = z ? bv_ : bu_;
    short* W1 = z ? W1v : W1u; short* W2 = z ? W2v : W2u; short* W3p = z ? W3pv : W3pu;
    float* svec = z ? sv : su; float* tvec = z ? tv : tu;
    int ht = h >> 4, l15h = h & 15;
    for (int j = tid; j < HD; j += 256) {
        W1[h * HD + j] = f2h(lnw[j] * row[j]);
        W2[h * HD + j] = f2h(lnw[HD + j] * row[HD + j]);
        float w3 = lnw[2 * HD + j] * row[2 * HD + j];
        int ks = j >> 5, lg2 = (j >> 3) & 3, ii = j & 7;
        W3p[((ht * 16 + ks) * 64 + lg2 * 16 + l15h) * 8 + ii] = f2h(w3);
    }
    float s = 0.f, t = 0.f;
    for (int c = tid; c < H3; c += 256) {
        float w = row[c];
        s += lnw[c] * w;
        t += lnb[c] * w;
    }
    for (int m = 1; m < 64; m <<= 1) { s += __shfl_xor(s, m, 64); t += __shfl_xor(t, m, 64); }
    __shared__ float rs[4], rt[4];
    if ((tid & 63) == 0) { rs[tid >> 6] = s; rt[tid >> 6] = t; }
    __syncthreads();
    if (tid == 0) {
        svec[h] = rs[0] + rs[1] + rs[2] + rs[3];
        tvec[h] = rt[0] + rt[1] + rt[2] + rt[3] + bias[h];
    }
}

// ---------- q/k projection, f32 in -> f16 out (z-fused) ----------------------
__global__ __launch_bounds__(256) void proj2(const float* __restrict__ Q_, const float* __restrict__ K_,
                                             const float* __restrict__ Wq_, const float* __restrict__ Wk_,
                                             short* __restrict__ qh, short* __restrict__ kh) {
    int z = blockIdx.z;
    const float* In = z ? K_ : Q_;
    const float* W = z ? Wk_ : Wq_;
    short* OutB = z ? kh : qh;
    __shared__ short a_l[64][72], b_l[64][72];
    int t = threadIdx.x;
    int i0 = blockIdx.y * 64, n0 = blockIdx.x * 64;
    int lane = t & 63, wv = t >> 6, wm = wv >> 1, wn = wv & 1;
    int l15 = lane & 15, lg = lane >> 4;
    f32x4 acc[2][2] = {};
    int sr = t >> 4, sc = (t & 15) * 4;
    for (int kc = 0; kc < QD; kc += 64) {
#pragma unroll
        for (int rep = 0; rep < 4; ++rep) {
            int row = sr + rep * 16;
            float4 av = *(const float4*)&In[(size_t)(i0 + row) * QD + kc + sc];
            float4 bv = *(const float4*)&W[(size_t)(n0 + row) * QD + kc + sc];
            *(uint2*)&a_l[row][sc] = (uint2){pkh(av.x, av.y), pkh(av.z, av.w)};
            *(uint2*)&b_l[row][sc] = (uint2){pkh(bv.x, bv.y), pkh(bv.z, bv.w)};
        }
        __syncthreads();
#pragma unroll
        for (int kk = 0; kk < 2; ++kk) {
            half8 af[2], bf_[2];
#pragma unroll
            for (int mi = 0; mi < 2; ++mi)
                af[mi] = *(const half8*)&a_l[wm * 32 + mi * 16 + l15][kk * 32 + lg * 8];
#pragma unroll
            for (int nj = 0; nj < 2; ++nj)
                bf_[nj] = *(const half8*)&b_l[wn * 32 + nj * 16 + l15][kk * 32 + lg * 8];
#pragma unroll
            for (int mi = 0; mi < 2; ++mi)
#pragma unroll
                for (int nj = 0; nj < 2; ++nj)
                    acc[mi][nj] = __builtin_amdgcn_mfma_f32_16x16x32_f16(af[mi], bf_[nj], acc[mi][nj], 0, 0, 0);
        }
        __syncthreads();
    }
#pragma unroll
    for (int mi = 0; mi < 2; ++mi)
#pragma unroll
        for (int nj = 0; nj < 2; ++nj)
#pragma unroll
            for (int r = 0; r < 4; ++r) {
                int row = i0 + wm * 32 + mi * 16 + lg * 4 + r;
                int col = n0 + wn * 32 + nj * 16 + l15;
                OutB[(size_t)row * HD + col] = f2h(acc[mi][nj][r]);
            }
}

// ---------- row sums (z-fused) + out init to bo ------------------------------
__global__ __launch_bounds__(256) void rowstats2(const unsigned* __restrict__ qh, const unsigned* __restrict__ kh,
                                                 float* __restrict__ s1q, float* __restrict__ s2q,
                                                 float* __restrict__ s1k, float* __restrict__ s2k,
                                                 float* __restrict__ out, const float* __restrict__ bo) {
    int row = blockIdx.x, z = blockIdx.y, tid = threadIdx.x;
    int gid = (z * 512 + row) * 256 + tid;
    if (gid < 2 * QLEN * QLEN) out[gid] = bo[0];
    const unsigned* Xh = z ? kh : qh;
    float* s1 = z ? s1k : s1q;
    float* s2 = z ? s2k : s2q;
    unsigned u = Xh[row * 256 + tid];
    float a = h2f((short)(u & 0xffff)), b = h2f((short)(u >> 16));
    float s = a + b, q = a * a + b * b;
    for (int m = 1; m < 64; m <<= 1) { s += __shfl_xor(s, m, 64); q += __shfl_xor(q, m, 64); }
    __shared__ float rs[4], rq[4];
    if ((tid & 63) == 0) { rs[tid >> 6] = s; rq[tid >> 6] = q; }
    __syncthreads();
    if (tid == 0) {
        s1[row] = rs[0] + rs[1] + rs[2] + rs[3];
        s2[row] = rq[0] + rq[1] + rq[2] + rq[3];
    }
}

// ---------- LN-linear row terms: 4 GEMMs z-fused (Au, Av, BuT, BvT) ----------
__global__ __launch_bounds__(256) void lnlin4(const short* __restrict__ qh, const short* __restrict__ kh,
                                              const short* __restrict__ W1u, const short* __restrict__ W1v,
                                              const short* __restrict__ W2u, const short* __restrict__ W2v,
                                              float* __restrict__ Au, float* __restrict__ Av,
                                              float* __restrict__ BuT, float* __restrict__ BvT) {
    int z = blockIdx.z;
    const short* A = (z < 2) ? qh : kh;
    const short* W = (z == 0) ? W1u : (z == 1) ? W1v : (z == 2) ? W2u : W2v;
    float* Out = (z == 0) ? Au : (z == 1) ? Av : (z == 2) ? BuT : BvT;
    bool tr = z >= 2;
    __shared__ short a_l[64][72], b_l[64][72];
    int t = threadIdx.x;
    int i0 = blockIdx.y * 64, n0 = blockIdx.x * 64;
    int lane = t & 63, wv = t >> 6, wm = wv >> 1, wn = wv & 1;
    int l15 = lane & 15, lg = lane >> 4;
    f32x4 acc[2][2] = {};
    int sr = t >> 4, sc = (t & 15) * 4;
    for (int kc = 0; kc < HD; kc += 64) {
#pragma unroll
        for (int rep = 0; rep < 4; ++rep) {
            int row = sr + rep * 16;
            *(uint2*)&a_l[row][sc] = *(const uint2*)&A[(size_t)(i0 + row) * HD + kc + sc];
            *(uint2*)&b_l[row][sc] = *(const uint2*)&W[(size_t)(n0 + row) * HD + kc + sc];
        }
        __syncthreads();
#pragma unroll
        for (int kk = 0; kk < 2; ++kk) {
            half8 af[2], bf_[2];
#pragma unroll
            for (int mi = 0; mi < 2; ++mi)
                af[mi] = *(const half8*)&a_l[wm * 32 + mi * 16 + l15][kk * 32 + lg * 8];
#pragma unroll
            for (int nj = 0; nj < 2; ++nj)
                bf_[nj] = *(const half8*)&b_l[wn * 32 + nj * 16 + l15][kk * 32 + lg * 8];
#pragma unroll
            for (int mi = 0; mi < 2; ++mi)
#pragma unroll
                for (int nj = 0; nj < 2; ++nj)
                    acc[mi][nj] = __builtin_amdgcn_mfma_f32_16x16x32_f16(af[mi], bf_[nj], acc[mi][nj], 0, 0, 0);
        }
        __syncthreads();
    }
#pragma unroll
    for (int mi = 0; mi < 2; ++mi)
#pragma unroll
        for (int nj = 0; nj < 2; ++nj)
#pragma unroll
            for (int r = 0; r < 4; ++r) {
                int row = i0 + wm * 32 + mi * 16 + lg * 4 + r;
                int col = n0 + wn * 32 + nj * 16 + l15;
                if (tr) Out[(size_t)col * HD + row] = acc[mi][nj][r];
                else    Out[(size_t)row * HD + col] = acc[mi][nj][r];
            }
}

// ---------- main: 256 pairs x 128 h; software-pipelined barrier-free K loop --
// B double-buffered in REGISTERS (buA/bvA <-> buB/bvB, static names), loads
// for ks+1 issued before MFMAs of ks -> counted vmcnt, latency hidden under
// the 32-MFMA cluster. waves_per_eu(2,2) pins the VGPR budget at 256 so the
// allocator doesn't squeeze to 128 and spill (R3 lesson).
__global__ __launch_bounds__(512)
__attribute__((amdgpu_waves_per_eu(2, 2)))
void main2(const short* __restrict__ qh,
           const short* __restrict__ kh,
           const float* __restrict__ Au,
           const float* __restrict__ Av,
           const float* __restrict__ BuT,
           const float* __restrict__ BvT,
           const short* __restrict__ W3pu,
           const short* __restrict__ W3pv,
           const float* __restrict__ su,
           const float* __restrict__ tu,
           const float* __restrict__ sv,
           const float* __restrict__ tv,
           const float* __restrict__ Wo,
           const float* __restrict__ s1q,
           const float* __restrict__ s2q,
           const float* __restrict__ s1k,
           const float* __restrict__ s2k,
           float* __restrict__ out) {
    __shared__ short q_l[16 * 512];          // 16 KB, swizzled rows (1024 B)
    __shared__ short k_l[16 * 512];          // 16 KB
    __shared__ float stat_l[512];
    __shared__ float sred[8][64];

    int tid = threadIdx.x;
    int kt = blockIdx.x, qt = blockIdx.y;
    int b = blockIdx.z >> 2, hs = blockIdx.z & 3;
    int qbase = qt * 16, kbase = kt * 16, hbase = hs * 128;
    int lane = tid & 63, wv = tid >> 6;
    int l15 = lane & 15, lg = lane >> 4;
    int wm = wv & 3, wn = wv >> 2;

    // ---- stage q,k tiles (swizzled) + zero stats ----
    stat_l[tid] = 0.f;
    for (int i = tid; i < 2048; i += 512) {
        int tile = i >> 10, slot = i & 1023;
        int row = slot >> 6, col16 = slot & 63;
        const short* sp = (tile ? kh : qh) +
            (size_t)(b * QLEN + (tile ? kbase : qbase) + row) * HD + col16 * 8;
        uint4 v = *(const uint4*)sp;
        short* dl = tile ? k_l : q_l;
        unsigned off = row * 1024 + ((col16 * 16) ^ ((row & 7) << 4));
        *(uint4*)((char*)dl + off) = v;
    }
    __syncthreads();

    // ---- pair stats: d1 = q.k, d2 = q^2.k^2 (each wave: 2 K-slices) ----
    {
        f32x4 d1 = {0.f, 0.f, 0.f, 0.f}, d2 = {0.f, 0.f, 0.f, 0.f};
#pragma unroll
        for (int s = 0; s < 2; ++s) {
            int jb = (wv * 2 + s) * 64 + lg * 16;
            uint4 qfu = *(const uint4*)((const char*)q_l + l15 * 1024 + (jb ^ ((l15 & 7) << 4)));
            uint4 kfu = *(const uint4*)((const char*)k_l + l15 * 1024 + (jb ^ ((l15 & 7) << 4)));
            half8 q8 = __builtin_bit_cast(half8, qfu);
            half8 k8 = __builtin_bit_cast(half8, kfu);
            half8 q2 = q8 * q8, k2 = k8 * k8;
            d1 = __builtin_amdgcn_mfma_f32_16x16x32_f16(q8, k8, d1, 0, 0, 0);
            d2 = __builtin_amdgcn_mfma_f32_16x16x32_f16(q2, k2, d2, 0, 0, 0);
        }
#pragma unroll
        for (int r = 0; r < 4; ++r) {
            int p = (lg * 4 + r) * 16 + l15;
            atomicAdd(&stat_l[p], d1[r]);
            atomicAdd(&stat_l[256 + p], d2[r]);
        }
    }

    // ---- software-pipelined K loop: 16 slices of K=32, B dbuf in regs ----
    f32x4 accU[4][4] = {}, accV[4][4] = {};
    int ht0 = hs * 8 + wn * 4;
    const half8* BuG = (const half8*)W3pu;
    const half8* BvG = (const half8*)W3pv;
    int bb0 = ht0 * 16 * 64 + lane;          // half8-unit index for (nf=0, ks=0)

    half8 buA[4], bvA[4], buB[4], bvB[4];
#pragma unroll
    for (int nf = 0; nf < 4; ++nf) {
        buA[nf] = BuG[bb0 + (nf * 16) * 64];
        bvA[nf] = BvG[bb0 + (nf * 16) * 64];
    }

#pragma unroll
    for (int ks2 = 0; ks2 < 8; ++ks2) {
        // ======== even ks: compute with A-buf, prefetch ks+1 into B-buf =====
        {
            int ks = ks2 * 2;
            int jb = ks * 64 + lg * 16;
            uint4 kfu = *(const uint4*)((const char*)k_l + l15 * 1024 + (jb ^ ((l15 & 7) << 4)));
            uint4 qfu[4];
#pragma unroll
            for (int mf = 0; mf < 4; ++mf) {
                int qrow = wm * 4 + mf;
                qfu[mf] = *(const uint4*)((const char*)q_l + qrow * 1024 + (jb ^ ((qrow & 7) << 4)));
            }
#pragma unroll
            for (int nf = 0; nf < 4; ++nf) {
                buB[nf] = BuG[bb0 + (nf * 16 + ks + 1) * 64];
                bvB[nf] = BvG[bb0 + (nf * 16 + ks + 1) * 64];
            }
            half8 k8 = __builtin_bit_cast(half8, kfu);
            half8 af[4];
#pragma unroll
            for (int mf = 0; mf < 4; ++mf)
                af[mf] = __builtin_bit_cast(half8, qfu[mf]) * k8;
#pragma unroll
            for (int nf = 0; nf < 4; ++nf)
#pragma unroll
                for (int mf = 0; mf < 4; ++mf) {
                    accU[mf][nf] = __builtin_amdgcn_mfma_f32_16x16x32_f16(af[mf], buA[nf], accU[mf][nf], 0, 0, 0);
                    accV[mf][nf] = __builtin_amdgcn_mfma_f32_16x16x32_f16(af[mf], bvA[nf], accV[mf][nf], 0, 0, 0);
                }
        }
        // ======== odd ks: compute with B-buf, prefetch ks+2 into A-buf ======
        {
            int ks = ks2 * 2 + 1;
            int jb = ks * 64 + lg * 16;
            uint4 kfu = *(const uint4*)((const char*)k_l + l15 * 1024 + (jb ^ ((l15 & 7) << 4)));
            uint4 qfu[4];
#pragma unroll
            for (int mf = 0; mf < 4; ++mf) {
                int qrow = wm * 4 + mf;
                qfu[mf] = *(const uint4*)((const char*)q_l + qrow * 1024 + (jb ^ ((qrow & 7) << 4)));
            }
            if (ks2 < 7) {
#pragma unroll
                for (int nf = 0; nf < 4; ++nf) {
                    buA[nf] = BuG[bb0 + (nf * 16 + ks + 1) * 64];
                    bvA[nf] = BvG[bb0 + (nf * 16 + ks + 1) * 64];
                }
            }
            half8 k8 = __builtin_bit_cast(half8, kfu);
            half8 af[4];
#pragma unroll
            for (int mf = 0; mf < 4; ++mf)
                af[mf] = __builtin_bit_cast(half8, qfu[mf]) * k8;
#pragma unroll
            for (int nf = 0; nf < 4; ++nf)
#pragma unroll
                for (int mf = 0; mf < 4; ++mf) {
                    accU[mf][nf] = __builtin_amdgcn_mfma_f32_16x16x32_f16(af[mf], buB[nf], accU[mf][nf], 0, 0, 0);
                    accV[mf][nf] = __builtin_amdgcn_mfma_f32_16x16x32_f16(af[mf], bvB[nf], accV[mf][nf], 0, 0, 0);
                }
        }
    }

    __syncthreads();   // stats atomics complete
    // ---- mu/ri conversion ----
    if (tid < 256) {
        int qi = tid >> 4, ki = tid & 15;
        float mu = (s1q[b * QLEN + qbase + qi] + s1k[b * QLEN + kbase + ki] + stat_l[tid]) * (1.f / H3);
        float ex2 = (s2q[b * QLEN + qbase + qi] + s2k[b * QLEN + kbase + ki] + stat_l[256 + tid]) * (1.f / H3);
        float ri = rsqrtf(ex2 - mu * mu + EPSF);
        stat_l[tid] = ri;
        stat_l[256 + tid] = ri * mu;
    }
    __syncthreads();

    // ---- fused epilogue: + Au/BuT (acc-init folded), LN-linear, gelu, Wo ----
    float sacc[16];
#pragma unroll
    for (int i = 0; i < 16; ++i) sacc[i] = 0.f;
#pragma unroll
    for (int nf = 0; nf < 4; ++nf) {
        int h = hbase + wn * 64 + nf * 16 + l15;
        float suh = su[h], tuh = tu[h], svh = sv[h], tvh = tv[h], woh = Wo[h];
        f32x4 bu4 = *(const f32x4*)&BuT[(size_t)h * 512 + b * QLEN + kbase + lg * 4];
        f32x4 bv4 = *(const f32x4*)&BvT[(size_t)h * 512 + b * QLEN + kbase + lg * 4];
#pragma unroll
        for (int mf = 0; mf < 4; ++mf) {
            int qrow = b * QLEN + qbase + wm * 4 + mf;
            float au = Au[(size_t)qrow * HD + h];
            float av = Av[(size_t)qrow * HD + h];
            int pbase = (wm * 4 + mf) * 16 + lg * 4;
#pragma unroll
            for (int r = 0; r < 4; ++r) {
                float ri = stat_l[pbase + r];
                float rmu = stat_l[256 + pbase + r];
                float gu = au + bu4[r] + accU[mf][nf][r];
                float gv = av + bv4[r] + accV[mf][nf][r];
                float u = fmaf(ri, gu, tuh) - rmu * suh;
                float vx = fmaf(ri, gv, tvh) - rmu * svh;
                float x2 = vx * vx;
                float tt = vx * fmaf(0.0356774081f, x2, 0.7978845608f);
                float e2 = exp2f(tt * 2.885390082f);
                float ge = vx - vx / (e2 + 1.0f);      // v*sigmoid(2t), inf-safe
                sacc[mf * 4 + r] = fmaf(u * ge, woh, sacc[mf * 4 + r]);
            }
        }
    }

    // reduce over the 16 h-lanes (l15)
#pragma unroll
    for (int i = 0; i < 16; ++i) {
        float v = sacc[i];
        v += __shfl_xor(v, 1, 64);
        v += __shfl_xor(v, 2, 64);
        v += __shfl_xor(v, 4, 64);
        v += __shfl_xor(v, 8, 64);
        sacc[i] = v;
    }
    if (l15 == 0) {
#pragma unroll
        for (int mf = 0; mf < 4; ++mf)
#pragma unroll
            for (int r = 0; r < 4; ++r)
                sred[wv][mf * 16 + lg * 4 + r] = sacc[mf * 4 + r];
    }
    __syncthreads();
    if (tid < 256) {
        int wm_ = tid >> 6, within = tid & 63;
        float val = sred[wm_][within] + sred[wm_ + 4][within];
        int qi = wm_ * 4 + (within >> 4), ki = within & 15;
        atomicAdd(&out[(size_t)(b * QLEN + qbase + qi) * QLEN + kbase + ki], val);
    }
}

extern "C" void kernel_launch(void* const* d_in, const int* in_sizes, int n_in,
                              void* d_out, int out_size, void* d_ws, size_t ws_size,
                              hipStream_t stream) {
    const float* Q   = (const float*)d_in[0];
    const float* Kin = (const float*)d_in[1];
    const float* Wq  = (const float*)d_in[2];
    const float* Wk  = (const float*)d_in[3];
    const float* lnw = (const float*)d_in[4];
    const float* lnb = (const float*)d_in[5];
    const float* Wu  = (const float*)d_in[6];
    const float* bu  = (const float*)d_in[7];
    const float* Wv  = (const float*)d_in[8];
    const float* bv  = (const float*)d_in[9];
    const float* Wo  = (const float*)d_in[10];
    const float* bo  = (const float*)d_in[11];
    float* out = (float*)d_out;

    char* ws = (char*)d_ws;
    size_t off = 0;
    auto alloc = [&](size_t bytes) -> void* {
        void* p = ws + off;
        off += (bytes + 255) & ~(size_t)255;
        return p;
    };
    const size_t WB = (size_t)HD * HD * 2;  // 512 KB f16 matrix
    short* W1u = (short*)alloc(WB); short* W2u = (short*)alloc(WB); short* W3pu = (short*)alloc(WB);
    short* W1v = (short*)alloc(WB); short* W2v = (short*)alloc(WB); short* W3pv = (short*)alloc(WB);
    short* qh = (short*)alloc(WB); short* kh = (short*)alloc(WB);
    float* su = (float*)alloc(HD * 4); float* tu = (float*)alloc(HD * 4);
    float* sv = (float*)alloc(HD * 4); float* tv = (float*)alloc(HD * 4);
    float* s1q = (float*)alloc(512 * 4); float* s2q = (float*)alloc(512 * 4);
    float* s1k = (float*)alloc(512 * 4); float* s2k = (float*)alloc(512 * 4);
    float* Au  = (float*)alloc((size_t)512 * HD * 4);
    float* Av  = (float*)alloc((size_t)512 * HD * 4);
    float* BuT = (float*)alloc((size_t)512 * HD * 4);
    float* BvT = (float*)alloc((size_t)512 * HD * 4);

    prep_w2<<<dim3(HD, 2), 256, 0, stream>>>(Wu, Wv, lnw, lnb, bu, bv,
                                             W1u, W2u, W3pu, W1v, W2v, W3pv, su, tu, sv, tv);

    proj2<<<dim3(8, 8, 2), 256, 0, stream>>>(Q, Kin, Wq, Wk, qh, kh);

    rowstats2<<<dim3(512, 2), 256, 0, stream>>>((const unsigned*)qh, (const unsigned*)kh,
                                                s1q, s2q, s1k, s2k, out, bo);

    lnlin4<<<dim3(8, 8, 4), 256, 0, stream>>>(qh, kh, W1u, W1v, W2u, W2v, Au, Av, BuT, BvT);

    main2<<<dim3(16, 16, 8), 512, 0, stream>>>(
        qh, kh, Au, Av, BuT, BvT, W3pu, W3pv, su, tu, sv, tv, Wo,
        s1q, s2q, s1k, s2k, out);
}